// Round 1
// baseline (3423.689 us; speedup 1.0000x reference)
//
#include <hip/hip_runtime.h>
#include <math.h>

#define B_  4
#define T_  1024
#define D_  1024
#define NH_ 16
#define DH_ 64
#define SH_ 3072

__device__ __forceinline__ float gelu_f(float x) {
    return 0.5f * x * (1.0f + erff(x * 0.70710678118654752440f));
}
__device__ __forceinline__ float sigm_f(float x) {
    return 1.0f / (1.0f + __expf(-x));
}

// ---------------------------------------------------------------------------
// Generic fp32 GEMM: C[M,N] = act(A[M,K] @ Bm[K,N] + bias) ( += into C if ACCUM)
// 128x64 tile, 256 threads, 8x4 micro-tile per thread, K-chunks of 16.
// ---------------------------------------------------------------------------
template<bool BIAS, bool GELU, bool ACCUM>
__global__ __launch_bounds__(256) void gemm_f32(
    const float* __restrict__ A, const float* __restrict__ Bm,
    const float* __restrict__ bias, float* __restrict__ C,
    int M, int N, int K)
{
    __shared__ __align__(16) float At[16][132];   // [k][m], padded stride 132
    __shared__ __align__(16) float Bt[16][64];    // [k][n]
    const int tid = threadIdx.x;
    const int m0b = blockIdx.y * 128;
    const int n0b = blockIdx.x * 64;

    const int sr  = tid >> 1;          // A-stage row 0..127
    const int skq = (tid & 1) * 8;     // A-stage k offset 0/8
    const int bk  = tid >> 4;          // B-stage k 0..15
    const int bn  = (tid & 15) * 4;    // B-stage n

    const int m0t = (tid & 15) * 8;    // thread micro-tile
    const int n0t = (tid >> 4) * 4;

    float acc[8][4];
#pragma unroll
    for (int i = 0; i < 8; ++i)
#pragma unroll
        for (int j = 0; j < 4; ++j) acc[i][j] = 0.f;

    const float* Ap = A + (size_t)(m0b + sr) * K + skq;
    const float* Bp = Bm + (size_t)bk * N + n0b + bn;

    for (int k0 = 0; k0 < K; k0 += 16) {
        float4 a0 = *(const float4*)(Ap);
        float4 a1 = *(const float4*)(Ap + 4);
        float4 b0 = *(const float4*)(Bp);
        At[skq + 0][sr] = a0.x; At[skq + 1][sr] = a0.y;
        At[skq + 2][sr] = a0.z; At[skq + 3][sr] = a0.w;
        At[skq + 4][sr] = a1.x; At[skq + 5][sr] = a1.y;
        At[skq + 6][sr] = a1.z; At[skq + 7][sr] = a1.w;
        *(float4*)&Bt[bk][bn] = b0;
        __syncthreads();
#pragma unroll
        for (int kk = 0; kk < 16; ++kk) {
            float4 xa0 = *(const float4*)&At[kk][m0t];
            float4 xa1 = *(const float4*)&At[kk][m0t + 4];
            float4 xb  = *(const float4*)&Bt[kk][n0t];
            float am[8] = {xa0.x, xa0.y, xa0.z, xa0.w, xa1.x, xa1.y, xa1.z, xa1.w};
            float bv[4] = {xb.x, xb.y, xb.z, xb.w};
#pragma unroll
            for (int i = 0; i < 8; ++i)
#pragma unroll
                for (int j = 0; j < 4; ++j)
                    acc[i][j] = fmaf(am[i], bv[j], acc[i][j]);
        }
        __syncthreads();
        Ap += 16;
        Bp += (size_t)16 * N;
    }

    float4 bs = make_float4(0.f, 0.f, 0.f, 0.f);
    if (BIAS) bs = *(const float4*)&bias[n0b + n0t];
#pragma unroll
    for (int i = 0; i < 8; ++i) {
        float4 v = make_float4(acc[i][0] + bs.x, acc[i][1] + bs.y,
                               acc[i][2] + bs.z, acc[i][3] + bs.w);
        if (GELU) {
            v.x = gelu_f(v.x); v.y = gelu_f(v.y);
            v.z = gelu_f(v.z); v.w = gelu_f(v.w);
        }
        float* Cp = C + (size_t)(m0b + m0t + i) * N + n0b + n0t;
        if (ACCUM) {
            float4 c0 = *(const float4*)Cp;
            v.x += c0.x; v.y += c0.y; v.z += c0.z; v.w += c0.w;
        }
        *(float4*)Cp = v;
    }
}

// ---------------------------------------------------------------------------
// Causal attention, one block per (q-row, head, batch).
// qkv layout from GEMM1: row (b*T+t), columns s*D + h*64 + d, s in {Q,K,V}.
// Adds the nmda*sigmoid(decay) constant to the output (rows of P sum to 1).
// branch[b,t,h*64+d] = attn output.
// ---------------------------------------------------------------------------
__global__ __launch_bounds__(256) void attn_kernel(
    const float* __restrict__ qkv, const float* __restrict__ nmda,
    const float* __restrict__ nmda_decay, float* __restrict__ branch)
{
    const int t = blockIdx.x, h = blockIdx.y, b = blockIdx.z;
    const int tid = threadIdx.x;
    __shared__ __align__(16) float s_lds[1024];
    __shared__ __align__(16) float q_lds[64];
    __shared__ float red[8];
    __shared__ float o_part[4][64];

    const float* qrow = qkv + (size_t)(b * T_ + t) * (3 * D_) + h * 64;
    if (tid < 16) *(float4*)&q_lds[tid * 4] = *(const float4*)&qrow[tid * 4];
    __syncthreads();

    const int n = t + 1;
    float lmax = -INFINITY;
    for (int k = tid; k < n; k += 256) {
        const float* krow = qkv + (size_t)(b * T_ + k) * (3 * D_) + D_ + h * 64;
        float a = 0.f;
#pragma unroll
        for (int d4 = 0; d4 < 16; ++d4) {
            float4 kv = *(const float4*)&krow[d4 * 4];
            float4 qv = *(const float4*)&q_lds[d4 * 4];
            a += kv.x * qv.x + kv.y * qv.y + kv.z * qv.z + kv.w * qv.w;
        }
        a *= 0.125f;
        s_lds[k] = a;
        lmax = fmaxf(lmax, a);
    }
#pragma unroll
    for (int m = 32; m; m >>= 1) lmax = fmaxf(lmax, __shfl_xor(lmax, m));
    if ((tid & 63) == 0) red[tid >> 6] = lmax;
    __syncthreads();
    const float mx = fmaxf(fmaxf(red[0], red[1]), fmaxf(red[2], red[3]));

    float lsum = 0.f;
    for (int k = tid; k < n; k += 256) {
        float e = __expf(s_lds[k] - mx);
        s_lds[k] = e;
        lsum += e;
    }
#pragma unroll
    for (int m = 32; m; m >>= 1) lsum += __shfl_xor(lsum, m);
    if ((tid & 63) == 0) red[4 + (tid >> 6)] = lsum;
    __syncthreads();
    const float inv = 1.f / (red[4] + red[5] + red[6] + red[7]);

    const int d = tid & 63, sl = tid >> 6;
    float acc = 0.f;
    for (int k = sl; k < n; k += 4) {
        const float* vrow = qkv + (size_t)(b * T_ + k) * (3 * D_) + 2 * D_ + h * 64;
        acc += s_lds[k] * vrow[d];
    }
    o_part[sl][d] = acc;
    __syncthreads();
    if (sl == 0) {
        float o = (o_part[0][d] + o_part[1][d] + o_part[2][d] + o_part[3][d]) * inv;
        float tau = sigm_f(nmda_decay[h * 64 + d]);
        o += nmda[(b * NH_ + h) * 64 + d] * tau;
        branch[(size_t)(b * T_ + t) * D_ + h * 64 + d] = o;
    }
}

// ---------------------------------------------------------------------------
// Causal grouped temporal conv (k=5, pad_left=4) + residual + bias.
// xcf2[b,t,c] = branch[b,t,c] + sum_{i,k} w[c,i,k]*branch[b,t-4+k,g*64+i] + b[c]
// Block: 4 output channels (same group), 128 t. 128 threads, one t each.
// ---------------------------------------------------------------------------
__global__ __launch_bounds__(128) void tconv_kernel(
    const float* __restrict__ branch, const float* __restrict__ w,
    const float* __restrict__ bias, float* __restrict__ xcf2)
{
    const int tid = threadIdx.x;
    const int t0 = blockIdx.x * 128;
    const int c0 = blockIdx.y * 4;      // global out channel base
    const int b  = blockIdx.z;
    const int g  = c0 >> 6;
    __shared__ __align__(16) float xl[132][68];   // [t_local][i], pad 68
    __shared__ __align__(16) float wl[4][5][64];  // [cc][k][i]
    __shared__ float bl[4];

    for (int idx = tid; idx < 132 * 64; idx += 128) {
        int tl = idx >> 6, i = idx & 63;
        int tg = t0 - 4 + tl;
        xl[tl][i] = (tg >= 0) ? branch[(size_t)(b * T_ + tg) * D_ + g * 64 + i] : 0.f;
    }
    for (int idx = tid; idx < 4 * 320; idx += 128) {
        int cc = idx / 320, r = idx - cc * 320;
        int i = r / 5, k = r - i * 5;
        wl[cc][k][i] = w[(size_t)(c0 + cc) * 320 + r];
    }
    if (tid < 4) bl[tid] = bias[c0 + tid];
    __syncthreads();

    const int cl = c0 & 63;
    float4 self = *(const float4*)&xl[tid + 4][cl];
    float a0 = self.x + bl[0], a1 = self.y + bl[1], a2 = self.z + bl[2], a3 = self.w + bl[3];
#pragma unroll
    for (int k = 0; k < 5; ++k) {
        const float* xr = &xl[tid + k][0];
#pragma unroll
        for (int i4 = 0; i4 < 16; ++i4) {
            float4 xv = *(const float4*)&xr[i4 * 4];
            float4 w0 = *(const float4*)&wl[0][k][i4 * 4];
            float4 w1 = *(const float4*)&wl[1][k][i4 * 4];
            float4 w2 = *(const float4*)&wl[2][k][i4 * 4];
            float4 w3 = *(const float4*)&wl[3][k][i4 * 4];
            a0 += xv.x * w0.x + xv.y * w0.y + xv.z * w0.z + xv.w * w0.w;
            a1 += xv.x * w1.x + xv.y * w1.y + xv.z * w1.z + xv.w * w1.w;
            a2 += xv.x * w2.x + xv.y * w2.y + xv.z * w2.z + xv.w * w2.w;
            a3 += xv.x * w3.x + xv.y * w3.y + xv.z * w3.z + xv.w * w3.w;
        }
    }
    *(float4*)&xcf2[(size_t)(b * T_ + t0 + tid) * D_ + c0] = make_float4(a0, a1, a2, a3);
}

// ---------------------------------------------------------------------------
// Grouped 1x1 up-proj (64 -> 128 per group) + bias + exact GELU.
// Block: (t-tile 64, group, b); 256 threads, 4t x 8o micro-tile.
// ---------------------------------------------------------------------------
__global__ __launch_bounds__(256) void ffu_kernel(
    const float* __restrict__ xcf2, const float* __restrict__ w,
    const float* __restrict__ bias, float* __restrict__ hid)
{
    const int tid = threadIdx.x;
    const int t0 = blockIdx.x * 64, g = blockIdx.y, b = blockIdx.z;
    __shared__ __align__(16) float al[64][68];     // [i][t]
    __shared__ __align__(16) float wlds[64][132];  // [i][o]

    for (int idx = tid; idx < 64 * 64; idx += 256) {
        int i = idx & 63, tl = idx >> 6;
        al[i][tl] = xcf2[(size_t)(b * T_ + t0 + tl) * D_ + g * 64 + i];
    }
    for (int idx = tid; idx < 128 * 64; idx += 256) {
        int i = idx & 63, o = idx >> 6;
        wlds[i][o] = w[(size_t)(g * 128 + o) * 64 + i];
    }
    __syncthreads();

    const int ot = (tid & 15) * 8;
    const int tt = (tid >> 4) * 4;
    float acc[4][8];
#pragma unroll
    for (int i = 0; i < 4; ++i)
#pragma unroll
        for (int j = 0; j < 8; ++j) acc[i][j] = 0.f;

#pragma unroll 8
    for (int i = 0; i < 64; ++i) {
        float4 a4 = *(const float4*)&al[i][tt];
        float4 w0 = *(const float4*)&wlds[i][ot];
        float4 w1 = *(const float4*)&wlds[i][ot + 4];
        float av[4] = {a4.x, a4.y, a4.z, a4.w};
        float wv[8] = {w0.x, w0.y, w0.z, w0.w, w1.x, w1.y, w1.z, w1.w};
#pragma unroll
        for (int ti = 0; ti < 4; ++ti)
#pragma unroll
            for (int oi = 0; oi < 8; ++oi)
                acc[ti][oi] = fmaf(av[ti], wv[oi], acc[ti][oi]);
    }

    float4 bb0 = *(const float4*)&bias[g * 128 + ot];
    float4 bb1 = *(const float4*)&bias[g * 128 + ot + 4];
    float bv[8] = {bb0.x, bb0.y, bb0.z, bb0.w, bb1.x, bb1.y, bb1.z, bb1.w};
#pragma unroll
    for (int ti = 0; ti < 4; ++ti) {
        float o_[8];
#pragma unroll
        for (int oi = 0; oi < 8; ++oi) o_[oi] = gelu_f(acc[ti][oi] + bv[oi]);
        float* hp = hid + (size_t)(b * T_ + t0 + tt + ti) * (2 * D_) + g * 128 + ot;
        *(float4*)hp       = make_float4(o_[0], o_[1], o_[2], o_[3]);
        *(float4*)(hp + 4) = make_float4(o_[4], o_[5], o_[6], o_[7]);
    }
}

// ---------------------------------------------------------------------------
// Grouped 1x1 down-proj (128 -> 64) + bias + residual(branch) + per-head
// GroupNorm (+affine) + nmda state update at t = T-1. Writes `normed`.
// Block: (t-tile 32, group, b); 256 threads = 16 c-threads x 16 t-threads.
// ---------------------------------------------------------------------------
__global__ __launch_bounds__(256) void ffd_gn_kernel(
    const float* __restrict__ hid, const float* __restrict__ w,
    const float* __restrict__ bias, const float* __restrict__ branch,
    const float* __restrict__ gn_w, const float* __restrict__ gn_b,
    const float* __restrict__ nmda, const float* __restrict__ nmda_decay,
    float* __restrict__ normed, float* __restrict__ out_nmda)
{
    const int tid = threadIdx.x;
    const int t0 = blockIdx.x * 32, g = blockIdx.y, b = blockIdx.z;
    __shared__ __align__(16) float al[128][36];  // [j][t]
    __shared__ __align__(16) float wl[128][68];  // [j][c]

    for (int idx = tid; idx < 128 * 32; idx += 256) {
        int j = idx & 127, tl = idx >> 7;
        al[j][tl] = hid[(size_t)(b * T_ + t0 + tl) * (2 * D_) + g * 128 + j];
    }
    for (int idx = tid; idx < 64 * 128; idx += 256) {
        int j = idx & 127, c = idx >> 7;
        wl[j][c] = w[(size_t)(g * 64 + c) * 128 + j];
    }
    __syncthreads();

    const int c0 = (tid & 15) * 4;     // local channel base (0..60)
    const int tt = (tid >> 4) * 2;     // local t base (0..30)
    float acc[2][4];
#pragma unroll
    for (int i = 0; i < 2; ++i)
#pragma unroll
        for (int j = 0; j < 4; ++j) acc[i][j] = 0.f;

#pragma unroll 8
    for (int j = 0; j < 128; ++j) {
        float2 a2 = *(const float2*)&al[j][tt];
        float4 w4 = *(const float4*)&wl[j][c0];
        acc[0][0] = fmaf(a2.x, w4.x, acc[0][0]);
        acc[0][1] = fmaf(a2.x, w4.y, acc[0][1]);
        acc[0][2] = fmaf(a2.x, w4.z, acc[0][2]);
        acc[0][3] = fmaf(a2.x, w4.w, acc[0][3]);
        acc[1][0] = fmaf(a2.y, w4.x, acc[1][0]);
        acc[1][1] = fmaf(a2.y, w4.y, acc[1][1]);
        acc[1][2] = fmaf(a2.y, w4.z, acc[1][2]);
        acc[1][3] = fmaf(a2.y, w4.w, acc[1][3]);
    }

    float4 bb = *(const float4*)&bias[g * 64 + c0];
    float4 gw = *(const float4*)&gn_w[g * 64 + c0];
    float4 gb = *(const float4*)&gn_b[g * 64 + c0];

#pragma unroll
    for (int tq = 0; tq < 2; ++tq) {
        const int tg = t0 + tt + tq;
        float4 br = *(const float4*)&branch[(size_t)(b * T_ + tg) * D_ + g * 64 + c0];
        float r0 = br.x + acc[tq][0] + bb.x;
        float r1 = br.y + acc[tq][1] + bb.y;
        float r2 = br.z + acc[tq][2] + bb.z;
        float r3 = br.w + acc[tq][3] + bb.w;
        float sm = r0 + r1 + r2 + r3;
#pragma unroll
        for (int m = 1; m < 16; m <<= 1) sm += __shfl_xor(sm, m);
        float mu = sm * (1.f / 64.f);
        float d0 = r0 - mu, d1 = r1 - mu, d2 = r2 - mu, d3 = r3 - mu;
        float vs = d0 * d0 + d1 * d1 + d2 * d2 + d3 * d3;
#pragma unroll
        for (int m = 1; m < 16; m <<= 1) vs += __shfl_xor(vs, m);
        float is = rsqrtf(vs * (1.f / 64.f) + 1e-5f);
        float n0 = d0 * is * gw.x + gb.x;
        float n1 = d1 * is * gw.y + gb.y;
        float n2 = d2 * is * gw.z + gb.z;
        float n3 = d3 * is * gw.w + gb.w;
        *(float4*)&normed[(size_t)(b * T_ + tg) * D_ + g * 64 + c0] =
            make_float4(n0, n1, n2, n3);
        if (tg == T_ - 1) {
            float nv[4] = {n0, n1, n2, n3};
#pragma unroll
            for (int cc = 0; cc < 4; ++cc) {
                int dloc = c0 + cc;
                int ni = (b * NH_ + g) * 64 + dloc;
                float t2 = sigm_f(nmda_decay[g * 64 + dloc]);
                out_nmda[ni] = t2 * nmda[ni] + (1.f - t2) * nv[cc];
            }
        }
    }
}

// ---------------------------------------------------------------------------
// LayerNorm over D=1024 per row: lns = (x-mu)/sqrt(var+eps)*w + b
// ---------------------------------------------------------------------------
__global__ __launch_bounds__(256) void ln_kernel(
    const float* __restrict__ x, const float* __restrict__ w,
    const float* __restrict__ bo, float* __restrict__ y)
{
    __shared__ float red[8];
    const int row = blockIdx.x, tid = threadIdx.x;
    const float* xr = x + (size_t)row * D_;
    float4 v = *(const float4*)&xr[tid * 4];
    float s = v.x + v.y + v.z + v.w;
#pragma unroll
    for (int m = 32; m; m >>= 1) s += __shfl_xor(s, m);
    if ((tid & 63) == 0) red[tid >> 6] = s;
    __syncthreads();
    float mu = (red[0] + red[1] + red[2] + red[3]) * (1.f / 1024.f);
    float dx = v.x - mu, dy = v.y - mu, dz = v.z - mu, dw = v.w - mu;
    float q = dx * dx + dy * dy + dz * dz + dw * dw;
#pragma unroll
    for (int m = 32; m; m >>= 1) q += __shfl_xor(q, m);
    if ((tid & 63) == 0) red[4 + (tid >> 6)] = q;
    __syncthreads();
    float var = (red[4] + red[5] + red[6] + red[7]) * (1.f / 1024.f);
    float is = rsqrtf(var + 1e-5f);
    float4 wv = *(const float4*)&w[tid * 4];
    float4 bv = *(const float4*)&bo[tid * 4];
    *(float4*)&y[(size_t)row * D_ + tid * 4] =
        make_float4(dx * is * wv.x + bv.x, dy * is * wv.y + bv.y,
                    dz * is * wv.z + bv.z, dw * is * wv.w + bv.w);
}

// ---------------------------------------------------------------------------
extern "C" void kernel_launch(void* const* d_in, const int* in_sizes, int n_in,
                              void* d_out, int out_size, void* d_ws, size_t ws_size,
                              hipStream_t stream)
{
    const float* x       = (const float*)d_in[0];
    const float* nmda    = (const float*)d_in[1];
    const float* qkv_w   = (const float*)d_in[2];
    const float* nmda_d  = (const float*)d_in[3];
    const float* tconv_w = (const float*)d_in[4];
    const float* tconv_b = (const float*)d_in[5];
    const float* ffu_w   = (const float*)d_in[6];
    const float* ffu_b   = (const float*)d_in[7];
    const float* ffd_w   = (const float*)d_in[8];
    const float* ffd_b   = (const float*)d_in[9];
    const float* gn_w    = (const float*)d_in[10];
    const float* gn_b    = (const float*)d_in[11];
    const float* soma_w  = (const float*)d_in[12];
    const float* ln_w    = (const float*)d_in[13];
    const float* ln_b    = (const float*)d_in[14];
    const float* w1      = (const float*)d_in[15];
    const float* b1      = (const float*)d_in[16];
    const float* w2      = (const float*)d_in[17];
    const float* b2      = (const float*)d_in[18];
    (void)in_sizes; (void)n_in; (void)out_size; (void)ws_size;

    float* outp     = (float*)d_out;
    float* soma     = outp;                               // B*T*D
    float* out_nmda = outp + (size_t)B_ * T_ * D_;        // B*NH*DH

    float* ws     = (float*)d_ws;
    float* branch = ws;                                   //  4,194,304 f
    float* xcf2   = ws + (size_t)4194304;                 //  4,194,304 f
    float* normed = ws + (size_t)8388608;                 //  4,194,304 f (later lns)
    float* qkvb   = ws + (size_t)12582912;                // 12,582,912 f (later hid, later h1)
    float* hid = qkvb;   // reuse: qkv dead after attention
    float* lns = normed; // reuse: normed dead after soma GEMM
    float* h1  = qkvb;   // reuse: hid dead after ffd

    // 1. qkv = x @ qkv_w                       (4096,1024)@(1024,3072)
    hipLaunchKernelGGL((gemm_f32<false, false, false>), dim3(48, 32), dim3(256), 0, stream,
                       x, qkv_w, nullptr, qkvb, 4096, 3072, 1024);
    // 2. causal attention + nmda shift -> branch
    hipLaunchKernelGGL(attn_kernel, dim3(T_, NH_, B_), dim3(256), 0, stream,
                       qkvb, nmda, nmda_d, branch);
    // 3. xcf2 = branch + tconv(branch)
    hipLaunchKernelGGL(tconv_kernel, dim3(8, 256, 4), dim3(128), 0, stream,
                       branch, tconv_w, tconv_b, xcf2);
    // 4. hid = gelu(ffu(xcf2))
    hipLaunchKernelGGL(ffu_kernel, dim3(16, NH_, B_), dim3(256), 0, stream,
                       xcf2, ffu_w, ffu_b, hid);
    // 5. normed = GroupNorm(branch + ffd(hid)); nmda update at t=T-1
    hipLaunchKernelGGL(ffd_gn_kernel, dim3(32, NH_, B_), dim3(256), 0, stream,
                       hid, ffd_w, ffd_b, branch, gn_w, gn_b, nmda, nmda_d,
                       normed, out_nmda);
    // 6. soma = normed @ soma_w -> d_out       (4096,1024)@(1024,1024)
    hipLaunchKernelGGL((gemm_f32<false, false, false>), dim3(16, 32), dim3(256), 0, stream,
                       normed, soma_w, nullptr, soma, 4096, 1024, 1024);
    // 7. lns = LayerNorm(soma)
    hipLaunchKernelGGL(ln_kernel, dim3(B_ * T_), dim3(256), 0, stream,
                       soma, ln_w, ln_b, lns);
    // 8. h1 = gelu(lns @ w1 + b1)              (4096,1024)@(1024,3072)
    hipLaunchKernelGGL((gemm_f32<true, true, false>), dim3(48, 32), dim3(256), 0, stream,
                       lns, w1, b1, h1, 4096, 3072, 1024);
    // 9. soma += h1 @ w2 + b2                  (4096,3072)@(3072,1024)
    hipLaunchKernelGGL((gemm_f32<true, false, true>), dim3(16, 32), dim3(256), 0, stream,
                       h1, w2, b2, soma, 4096, 1024, 3072);
}

// Round 3
// 2010.263 us; speedup vs baseline: 1.7031x; 1.7031x over previous
//
#include <hip/hip_runtime.h>
#include <math.h>

#define B_  4
#define T_  1024
#define D_  1024
#define NH_ 16
#define DH_ 64
#define SH_ 3072

__device__ __forceinline__ float gelu_f(float x) {
    return 0.5f * x * (1.0f + erff(x * 0.70710678118654752440f));
}
__device__ __forceinline__ float sigm_f(float x) {
    return 1.0f / (1.0f + __expf(-x));
}

// ---------------------------------------------------------------------------
// Generic fp32 GEMM: C[M,N] = act(A[M,K] @ Bm[K,N] + bias) ( += into C if ACCUM)
// 128x64 tile, 256 threads, 8x4 micro-tile per thread, K-chunks of 16.
// ---------------------------------------------------------------------------
template<bool BIAS, bool GELU, bool ACCUM>
__global__ __launch_bounds__(256) void gemm_f32(
    const float* __restrict__ A, const float* __restrict__ Bm,
    const float* __restrict__ bias, float* __restrict__ C,
    int M, int N, int K)
{
    __shared__ __align__(16) float At[16][132];   // [k][m], padded stride 132
    __shared__ __align__(16) float Bt[16][64];    // [k][n]
    const int tid = threadIdx.x;
    const int m0b = blockIdx.y * 128;
    const int n0b = blockIdx.x * 64;

    const int sr  = tid >> 1;          // A-stage row 0..127
    const int skq = (tid & 1) * 8;     // A-stage k offset 0/8
    const int bk  = tid >> 4;          // B-stage k 0..15
    const int bn  = (tid & 15) * 4;    // B-stage n

    const int m0t = (tid & 15) * 8;    // thread micro-tile
    const int n0t = (tid >> 4) * 4;

    float acc[8][4];
#pragma unroll
    for (int i = 0; i < 8; ++i)
#pragma unroll
        for (int j = 0; j < 4; ++j) acc[i][j] = 0.f;

    const float* Ap = A + (size_t)(m0b + sr) * K + skq;
    const float* Bp = Bm + (size_t)bk * N + n0b + bn;

    for (int k0 = 0; k0 < K; k0 += 16) {
        float4 a0 = *(const float4*)(Ap);
        float4 a1 = *(const float4*)(Ap + 4);
        float4 b0 = *(const float4*)(Bp);
        At[skq + 0][sr] = a0.x; At[skq + 1][sr] = a0.y;
        At[skq + 2][sr] = a0.z; At[skq + 3][sr] = a0.w;
        At[skq + 4][sr] = a1.x; At[skq + 5][sr] = a1.y;
        At[skq + 6][sr] = a1.z; At[skq + 7][sr] = a1.w;
        *(float4*)&Bt[bk][bn] = b0;
        __syncthreads();
#pragma unroll
        for (int kk = 0; kk < 16; ++kk) {
            float4 xa0 = *(const float4*)&At[kk][m0t];
            float4 xa1 = *(const float4*)&At[kk][m0t + 4];
            float4 xb  = *(const float4*)&Bt[kk][n0t];
            float am[8] = {xa0.x, xa0.y, xa0.z, xa0.w, xa1.x, xa1.y, xa1.z, xa1.w};
            float bv[4] = {xb.x, xb.y, xb.z, xb.w};
#pragma unroll
            for (int i = 0; i < 8; ++i)
#pragma unroll
                for (int j = 0; j < 4; ++j)
                    acc[i][j] = fmaf(am[i], bv[j], acc[i][j]);
        }
        __syncthreads();
        Ap += 16;
        Bp += (size_t)16 * N;
    }

    float4 bs = make_float4(0.f, 0.f, 0.f, 0.f);
    if (BIAS) bs = *(const float4*)&bias[n0b + n0t];
#pragma unroll
    for (int i = 0; i < 8; ++i) {
        float4 v = make_float4(acc[i][0] + bs.x, acc[i][1] + bs.y,
                               acc[i][2] + bs.z, acc[i][3] + bs.w);
        if (GELU) {
            v.x = gelu_f(v.x); v.y = gelu_f(v.y);
            v.z = gelu_f(v.z); v.w = gelu_f(v.w);
        }
        float* Cp = C + (size_t)(m0b + m0t + i) * N + n0b + n0t;
        if (ACCUM) {
            float4 c0 = *(const float4*)Cp;
            v.x += c0.x; v.y += c0.y; v.z += c0.z; v.w += c0.w;
        }
        *(float4*)Cp = v;
    }
}

// ---------------------------------------------------------------------------
// Flash attention (fp32). One block = 64 q-rows of one (b,h). 256 thr, 4 waves.
// Thread (w = tid>>6, r = tid&63): owns q-row r fully in regs (64 f),
// computes S cols w*16..w*16+15, accumulates O cols w*16..w*16+15.
// K/V tiles (64 rows) staged in LDS; all K/V reads are wave-uniform
// broadcasts. P staged in LDS stride 65 (2-way max -> free).
// Online softmax state (m,l) replicated per row across waves via LDS reduce.
// Adds nmda*sigmoid(decay) constant after normalize (P rows sum to 1).
// ---------------------------------------------------------------------------
__global__ __launch_bounds__(256, 2) void attn_flash(
    const float* __restrict__ qkv, const float* __restrict__ nmda,
    const float* __restrict__ nmda_decay, float* __restrict__ branch)
{
    const int qt = (int)gridDim.x - 1 - (int)blockIdx.x;  // heavy tiles first
    const int h  = blockIdx.y;
    const int b  = blockIdx.z;
    const int tid = threadIdx.x;
    const int w   = tid >> 6;
    const int r   = tid & 63;
    const int q0  = qt * 64;

    __shared__ __align__(16) float kT[64][68];
    __shared__ __align__(16) float vT[64][68];
    __shared__ float sP[64][65];
    __shared__ float redm[4][64];
    __shared__ float reds[4][64];

    // Q row r -> registers (redundant across the 4 waves, read-once from L2)
    float q[64];
    {
        const float* qrow = qkv + (size_t)(b * T_ + q0 + r) * (3 * D_) + h * 64;
#pragma unroll
        for (int i = 0; i < 16; ++i) {
            float4 v = *(const float4*)(qrow + i * 4);
            q[4 * i + 0] = v.x; q[4 * i + 1] = v.y;
            q[4 * i + 2] = v.z; q[4 * i + 3] = v.w;
        }
    }

    float O[16];
#pragma unroll
    for (int i = 0; i < 16; ++i) O[i] = 0.f;
    float m_run = -INFINITY, l_run = 0.f;

    const int ldrow = tid >> 2;         // staging row 0..63
    const int ldd   = (tid & 3) * 16;   // staging d-chunk

    for (int kt = 0; kt <= qt; ++kt) {
        const int k0 = kt * 64;
        __syncthreads();  // previous iteration done with kT/vT/sP
        {
            const float* krow = qkv + (size_t)(b * T_ + k0 + ldrow) * (3 * D_)
                              + D_ + h * 64 + ldd;
            const float* vrow = krow + D_;
#pragma unroll
            for (int i = 0; i < 4; ++i) {
                *(float4*)&kT[ldrow][ldd + 4 * i] = *(const float4*)(krow + 4 * i);
                *(float4*)&vT[ldrow][ldd + 4 * i] = *(const float4*)(vrow + 4 * i);
            }
        }
        __syncthreads();

        // ---- S = (Q K^T) * scale for this thread's 16 k-columns ----
        float s[16];
#pragma unroll 4
        for (int j = 0; j < 16; ++j) {
            const int kk = w * 16 + j;     // wave-uniform
            float a = 0.f;
#pragma unroll
            for (int d4 = 0; d4 < 16; ++d4) {
                float4 kv = *(const float4*)&kT[kk][d4 * 4];
                a += q[4 * d4 + 0] * kv.x + q[4 * d4 + 1] * kv.y
                   + q[4 * d4 + 2] * kv.z + q[4 * d4 + 3] * kv.w;
            }
            s[j] = a * 0.125f;
        }
        if (kt == qt) {
#pragma unroll
            for (int j = 0; j < 16; ++j)
                if (w * 16 + j > r) s[j] = -INFINITY;
        }

        // ---- online softmax ----
        float lm = s[0];
#pragma unroll
        for (int j = 1; j < 16; ++j) lm = fmaxf(lm, s[j]);
        redm[w][r] = lm;
        __syncthreads();
        const float mt = fmaxf(fmaxf(redm[0][r], redm[1][r]),
                               fmaxf(redm[2][r], redm[3][r]));
        const float m_new = fmaxf(m_run, mt);
        const float c = __expf(m_run - m_new);   // -inf -> 0 first time
        float ls = 0.f;
#pragma unroll
        for (int j = 0; j < 16; ++j) {
            float e = (s[j] == -INFINITY) ? 0.f : __expf(s[j] - m_new);
            sP[r][w * 16 + j] = e;
            ls += e;
        }
        reds[w][r] = ls;
        __syncthreads();
        l_run = l_run * c + (reds[0][r] + reds[1][r] + reds[2][r] + reds[3][r]);
        m_run = m_new;

        // ---- PV accumulate (rescale O by c, then add P.V) ----
#pragma unroll
        for (int i = 0; i < 16; ++i) O[i] *= c;
        const int d0 = w * 16;
#pragma unroll 4
        for (int kk = 0; kk < 64; ++kk) {
            const float p = sP[r][kk];
            float4 v0 = *(const float4*)&vT[kk][d0];
            float4 v1 = *(const float4*)&vT[kk][d0 + 4];
            float4 v2 = *(const float4*)&vT[kk][d0 + 8];
            float4 v3 = *(const float4*)&vT[kk][d0 + 12];
            O[0]  = fmaf(p, v0.x, O[0]);  O[1]  = fmaf(p, v0.y, O[1]);
            O[2]  = fmaf(p, v0.z, O[2]);  O[3]  = fmaf(p, v0.w, O[3]);
            O[4]  = fmaf(p, v1.x, O[4]);  O[5]  = fmaf(p, v1.y, O[5]);
            O[6]  = fmaf(p, v1.z, O[6]);  O[7]  = fmaf(p, v1.w, O[7]);
            O[8]  = fmaf(p, v2.x, O[8]);  O[9]  = fmaf(p, v2.y, O[9]);
            O[10] = fmaf(p, v2.z, O[10]); O[11] = fmaf(p, v2.w, O[11]);
            O[12] = fmaf(p, v3.x, O[12]); O[13] = fmaf(p, v3.y, O[13]);
            O[14] = fmaf(p, v3.z, O[14]); O[15] = fmaf(p, v3.w, O[15]);
        }
    }

    // ---- epilogue: normalize, add nmda shift, store ----
    const float inv = 1.f / l_run;
    const int dd = w * 16;
    const float* nd = nmda_decay + h * 64 + dd;
    const float* nm = nmda + (size_t)(b * NH_ + h) * 64 + dd;
    float* orow = branch + (size_t)(b * T_ + q0 + r) * D_ + h * 64 + dd;
#pragma unroll
    for (int i = 0; i < 16; ++i)
        orow[i] = O[i] * inv + nm[i] * sigm_f(nd[i]);
}

// ---------------------------------------------------------------------------
// Causal grouped temporal conv (k=5, pad_left=4) + residual + bias.
// ---------------------------------------------------------------------------
__global__ __launch_bounds__(128) void tconv_kernel(
    const float* __restrict__ branch, const float* __restrict__ w,
    const float* __restrict__ bias, float* __restrict__ xcf2)
{
    const int tid = threadIdx.x;
    const int t0 = blockIdx.x * 128;
    const int c0 = blockIdx.y * 4;      // global out channel base
    const int b  = blockIdx.z;
    const int g  = c0 >> 6;
    __shared__ __align__(16) float xl[132][68];   // [t_local][i], pad 68
    __shared__ __align__(16) float wl[4][5][64];  // [cc][k][i]
    __shared__ float bl[4];

    for (int idx = tid; idx < 132 * 64; idx += 128) {
        int tl = idx >> 6, i = idx & 63;
        int tg = t0 - 4 + tl;
        xl[tl][i] = (tg >= 0) ? branch[(size_t)(b * T_ + tg) * D_ + g * 64 + i] : 0.f;
    }
    for (int idx = tid; idx < 4 * 320; idx += 128) {
        int cc = idx / 320, r = idx - cc * 320;
        int i = r / 5, k = r - i * 5;
        wl[cc][k][i] = w[(size_t)(c0 + cc) * 320 + r];
    }
    if (tid < 4) bl[tid] = bias[c0 + tid];
    __syncthreads();

    const int cl = c0 & 63;
    float4 self = *(const float4*)&xl[tid + 4][cl];
    float a0 = self.x + bl[0], a1 = self.y + bl[1], a2 = self.z + bl[2], a3 = self.w + bl[3];
#pragma unroll
    for (int k = 0; k < 5; ++k) {
        const float* xr = &xl[tid + k][0];
#pragma unroll
        for (int i4 = 0; i4 < 16; ++i4) {
            float4 xv = *(const float4*)&xr[i4 * 4];
            float4 w0 = *(const float4*)&wl[0][k][i4 * 4];
            float4 w1 = *(const float4*)&wl[1][k][i4 * 4];
            float4 w2 = *(const float4*)&wl[2][k][i4 * 4];
            float4 w3 = *(const float4*)&wl[3][k][i4 * 4];
            a0 += xv.x * w0.x + xv.y * w0.y + xv.z * w0.z + xv.w * w0.w;
            a1 += xv.x * w1.x + xv.y * w1.y + xv.z * w1.z + xv.w * w1.w;
            a2 += xv.x * w2.x + xv.y * w2.y + xv.z * w2.z + xv.w * w2.w;
            a3 += xv.x * w3.x + xv.y * w3.y + xv.z * w3.z + xv.w * w3.w;
        }
    }
    *(float4*)&xcf2[(size_t)(b * T_ + t0 + tid) * D_ + c0] = make_float4(a0, a1, a2, a3);
}

// ---------------------------------------------------------------------------
// Grouped 1x1 up-proj (64 -> 128 per group) + bias + exact GELU.
// ---------------------------------------------------------------------------
__global__ __launch_bounds__(256) void ffu_kernel(
    const float* __restrict__ xcf2, const float* __restrict__ w,
    const float* __restrict__ bias, float* __restrict__ hid)
{
    const int tid = threadIdx.x;
    const int t0 = blockIdx.x * 64, g = blockIdx.y, b = blockIdx.z;
    __shared__ __align__(16) float al[64][68];     // [i][t]
    __shared__ __align__(16) float wlds[64][132];  // [i][o]

    for (int idx = tid; idx < 64 * 64; idx += 256) {
        int i = idx & 63, tl = idx >> 6;
        al[i][tl] = xcf2[(size_t)(b * T_ + t0 + tl) * D_ + g * 64 + i];
    }
    for (int idx = tid; idx < 128 * 64; idx += 256) {
        int i = idx & 63, o = idx >> 6;
        wlds[i][o] = w[(size_t)(g * 128 + o) * 64 + i];
    }
    __syncthreads();

    const int ot = (tid & 15) * 8;
    const int tt = (tid >> 4) * 4;
    float acc[4][8];
#pragma unroll
    for (int i = 0; i < 4; ++i)
#pragma unroll
        for (int j = 0; j < 8; ++j) acc[i][j] = 0.f;

#pragma unroll 8
    for (int i = 0; i < 64; ++i) {
        float4 a4 = *(const float4*)&al[i][tt];
        float4 w0 = *(const float4*)&wlds[i][ot];
        float4 w1 = *(const float4*)&wlds[i][ot + 4];
        float av[4] = {a4.x, a4.y, a4.z, a4.w};
        float wv[8] = {w0.x, w0.y, w0.z, w0.w, w1.x, w1.y, w1.z, w1.w};
#pragma unroll
        for (int ti = 0; ti < 4; ++ti)
#pragma unroll
            for (int oi = 0; oi < 8; ++oi)
                acc[ti][oi] = fmaf(av[ti], wv[oi], acc[ti][oi]);
    }

    float4 bb0 = *(const float4*)&bias[g * 128 + ot];
    float4 bb1 = *(const float4*)&bias[g * 128 + ot + 4];
    float bv[8] = {bb0.x, bb0.y, bb0.z, bb0.w, bb1.x, bb1.y, bb1.z, bb1.w};
#pragma unroll
    for (int ti = 0; ti < 4; ++ti) {
        float o_[8];
#pragma unroll
        for (int oi = 0; oi < 8; ++oi) o_[oi] = gelu_f(acc[ti][oi] + bv[oi]);
        float* hp = hid + (size_t)(b * T_ + t0 + tt + ti) * (2 * D_) + g * 128 + ot;
        *(float4*)hp       = make_float4(o_[0], o_[1], o_[2], o_[3]);
        *(float4*)(hp + 4) = make_float4(o_[4], o_[5], o_[6], o_[7]);
    }
}

// ---------------------------------------------------------------------------
// Grouped 1x1 down-proj (128 -> 64) + bias + residual + per-head GroupNorm
// + nmda state update at t = T-1.
// ---------------------------------------------------------------------------
__global__ __launch_bounds__(256) void ffd_gn_kernel(
    const float* __restrict__ hid, const float* __restrict__ w,
    const float* __restrict__ bias, const float* __restrict__ branch,
    const float* __restrict__ gn_w, const float* __restrict__ gn_b,
    const float* __restrict__ nmda, const float* __restrict__ nmda_decay,
    float* __restrict__ normed, float* __restrict__ out_nmda)
{
    const int tid = threadIdx.x;
    const int t0 = blockIdx.x * 32, g = blockIdx.y, b = blockIdx.z;
    __shared__ __align__(16) float al[128][36];  // [j][t]
    __shared__ __align__(16) float wl[128][68];  // [j][c]

    for (int idx = tid; idx < 128 * 32; idx += 256) {
        int j = idx & 127, tl = idx >> 7;
        al[j][tl] = hid[(size_t)(b * T_ + t0 + tl) * (2 * D_) + g * 128 + j];
    }
    for (int idx = tid; idx < 64 * 128; idx += 256) {
        int j = idx & 127, c = idx >> 7;
        wl[j][c] = w[(size_t)(g * 64 + c) * 128 + j];
    }
    __syncthreads();

    const int c0 = (tid & 15) * 4;     // local channel base
    const int tt = (tid >> 4) * 2;     // local t base
    float acc[2][4];
#pragma unroll
    for (int i = 0; i < 2; ++i)
#pragma unroll
        for (int j = 0; j < 4; ++j) acc[i][j] = 0.f;

#pragma unroll 8
    for (int j = 0; j < 128; ++j) {
        float2 a2 = *(const float2*)&al[j][tt];
        float4 w4 = *(const float4*)&wl[j][c0];
        acc[0][0] = fmaf(a2.x, w4.x, acc[0][0]);
        acc[0][1] = fmaf(a2.x, w4.y, acc[0][1]);
        acc[0][2] = fmaf(a2.x, w4.z, acc[0][2]);
        acc[0][3] = fmaf(a2.x, w4.w, acc[0][3]);
        acc[1][0] = fmaf(a2.y, w4.x, acc[1][0]);
        acc[1][1] = fmaf(a2.y, w4.y, acc[1][1]);
        acc[1][2] = fmaf(a2.y, w4.z, acc[1][2]);
        acc[1][3] = fmaf(a2.y, w4.w, acc[1][3]);
    }

    float4 bb = *(const float4*)&bias[g * 64 + c0];
    float4 gw = *(const float4*)&gn_w[g * 64 + c0];
    float4 gb = *(const float4*)&gn_b[g * 64 + c0];

#pragma unroll
    for (int tq = 0; tq < 2; ++tq) {
        const int tg = t0 + tt + tq;
        float4 br = *(const float4*)&branch[(size_t)(b * T_ + tg) * D_ + g * 64 + c0];
        float r0 = br.x + acc[tq][0] + bb.x;
        float r1 = br.y + acc[tq][1] + bb.y;
        float r2 = br.z + acc[tq][2] + bb.z;
        float r3 = br.w + acc[tq][3] + bb.w;
        float sm = r0 + r1 + r2 + r3;
#pragma unroll
        for (int m = 1; m < 16; m <<= 1) sm += __shfl_xor(sm, m);
        float mu = sm * (1.f / 64.f);
        float d0 = r0 - mu, d1 = r1 - mu, d2 = r2 - mu, d3 = r3 - mu;
        float vs = d0 * d0 + d1 * d1 + d2 * d2 + d3 * d3;
#pragma unroll
        for (int m = 1; m < 16; m <<= 1) vs += __shfl_xor(vs, m);
        float is = rsqrtf(vs * (1.f / 64.f) + 1e-5f);
        float n0 = d0 * is * gw.x + gb.x;
        float n1 = d1 * is * gw.y + gb.y;
        float n2 = d2 * is * gw.z + gb.z;
        float n3 = d3 * is * gw.w + gb.w;
        *(float4*)&normed[(size_t)(b * T_ + tg) * D_ + g * 64 + c0] =
            make_float4(n0, n1, n2, n3);
        if (tg == T_ - 1) {
            float nv[4] = {n0, n1, n2, n3};
#pragma unroll
            for (int cc = 0; cc < 4; ++cc) {
                int dloc = c0 + cc;
                int ni = (b * NH_ + g) * 64 + dloc;
                float t2 = sigm_f(nmda_decay[g * 64 + dloc]);
                out_nmda[ni] = t2 * nmda[ni] + (1.f - t2) * nv[cc];
            }
        }
    }
}

// ---------------------------------------------------------------------------
// LayerNorm over D=1024 per row.
// ---------------------------------------------------------------------------
__global__ __launch_bounds__(256) void ln_kernel(
    const float* __restrict__ x, const float* __restrict__ w,
    const float* __restrict__ bo, float* __restrict__ y)
{
    __shared__ float red[8];
    const int row = blockIdx.x, tid = threadIdx.x;
    const float* xr = x + (size_t)row * D_;
    float4 v = *(const float4*)&xr[tid * 4];
    float s = v.x + v.y + v.z + v.w;
#pragma unroll
    for (int m = 32; m; m >>= 1) s += __shfl_xor(s, m);
    if ((tid & 63) == 0) red[tid >> 6] = s;
    __syncthreads();
    float mu = (red[0] + red[1] + red[2] + red[3]) * (1.f / 1024.f);
    float dx = v.x - mu, dy = v.y - mu, dz = v.z - mu, dw = v.w - mu;
    float q = dx * dx + dy * dy + dz * dz + dw * dw;
#pragma unroll
    for (int m = 32; m; m >>= 1) q += __shfl_xor(q, m);
    if ((tid & 63) == 0) red[4 + (tid >> 6)] = q;
    __syncthreads();
    float var = (red[4] + red[5] + red[6] + red[7]) * (1.f / 1024.f);
    float is = rsqrtf(var + 1e-5f);
    float4 wv = *(const float4*)&w[tid * 4];
    float4 bv = *(const float4*)&bo[tid * 4];
    *(float4*)&y[(size_t)row * D_ + tid * 4] =
        make_float4(dx * is * wv.x + bv.x, dy * is * wv.y + bv.y,
                    dz * is * wv.z + bv.z, dw * is * wv.w + bv.w);
}

// ---------------------------------------------------------------------------
extern "C" void kernel_launch(void* const* d_in, const int* in_sizes, int n_in,
                              void* d_out, int out_size, void* d_ws, size_t ws_size,
                              hipStream_t stream)
{
    const float* x       = (const float*)d_in[0];
    const float* nmda    = (const float*)d_in[1];
    const float* qkv_w   = (const float*)d_in[2];
    const float* nmda_d  = (const float*)d_in[3];
    const float* tconv_w = (const float*)d_in[4];
    const float* tconv_b = (const float*)d_in[5];
    const float* ffu_w   = (const float*)d_in[6];
    const float* ffu_b   = (const float*)d_in[7];
    const float* ffd_w   = (const float*)d_in[8];
    const float* ffd_b   = (const float*)d_in[9];
    const float* gn_w    = (const float*)d_in[10];
    const float* gn_b    = (const float*)d_in[11];
    const float* soma_w  = (const float*)d_in[12];
    const float* ln_w    = (const float*)d_in[13];
    const float* ln_b    = (const float*)d_in[14];
    const float* w1      = (const float*)d_in[15];
    const float* b1      = (const float*)d_in[16];
    const float* w2      = (const float*)d_in[17];
    const float* b2      = (const float*)d_in[18];
    (void)in_sizes; (void)n_in; (void)out_size; (void)ws_size;

    float* outp     = (float*)d_out;
    float* soma     = outp;                               // B*T*D
    float* out_nmda = outp + (size_t)B_ * T_ * D_;        // B*NH*DH

    float* ws     = (float*)d_ws;
    float* branch = ws;                                   //  4,194,304 f
    float* xcf2   = ws + (size_t)4194304;                 //  4,194,304 f
    float* normed = ws + (size_t)8388608;                 //  4,194,304 f
    float* qkvb   = ws + (size_t)12582912;                // 12,582,912 f
    float* hid = qkvb;   // reuse: qkv dead after attention
    float* lns = normed; // reuse: normed dead after soma GEMM
    float* h1  = qkvb;   // reuse: hid dead after ffd

    // 1. qkv = x @ qkv_w
    hipLaunchKernelGGL((gemm_f32<false, false, false>), dim3(48, 32), dim3(256), 0, stream,
                       x, qkv_w, nullptr, qkvb, 4096, 3072, 1024);
    // 2. flash attention + nmda shift -> branch
    hipLaunchKernelGGL(attn_flash, dim3(16, NH_, B_), dim3(256), 0, stream,
                       qkvb, nmda, nmda_d, branch);
    // 3. xcf2 = branch + tconv(branch)
    hipLaunchKernelGGL(tconv_kernel, dim3(8, 256, 4), dim3(128), 0, stream,
                       branch, tconv_w, tconv_b, xcf2);
    // 4. hid = gelu(ffu(xcf2))
    hipLaunchKernelGGL(ffu_kernel, dim3(16, NH_, B_), dim3(256), 0, stream,
                       xcf2, ffu_w, ffu_b, hid);
    // 5. normed = GroupNorm(branch + ffd(hid)); nmda update at t=T-1
    hipLaunchKernelGGL(ffd_gn_kernel, dim3(32, NH_, B_), dim3(256), 0, stream,
                       hid, ffd_w, ffd_b, branch, gn_w, gn_b, nmda, nmda_d,
                       normed, out_nmda);
    // 6. soma = normed @ soma_w -> d_out
    hipLaunchKernelGGL((gemm_f32<false, false, false>), dim3(16, 32), dim3(256), 0, stream,
                       normed, soma_w, nullptr, soma, 4096, 1024, 1024);
    // 7. lns = LayerNorm(soma)
    hipLaunchKernelGGL(ln_kernel, dim3(B_ * T_), dim3(256), 0, stream,
                       soma, ln_w, ln_b, lns);
    // 8. h1 = gelu(lns @ w1 + b1)
    hipLaunchKernelGGL((gemm_f32<true, true, false>), dim3(48, 32), dim3(256), 0, stream,
                       lns, w1, b1, h1, 4096, 3072, 1024);
    // 9. soma += h1 @ w2 + b2
    hipLaunchKernelGGL((gemm_f32<true, false, true>), dim3(16, 32), dim3(256), 0, stream,
                       h1, w2, b2, soma, 4096, 1024, 3072);
}

// Round 6
// 1590.751 us; speedup vs baseline: 2.1522x; 1.2637x over previous
//
#include <hip/hip_runtime.h>
#include <math.h>

#define B_  4
#define T_  1024
#define D_  1024
#define NH_ 16
#define DH_ 64
#define SH_ 3072

typedef unsigned short u16;
typedef __attribute__((ext_vector_type(8))) short bf16x8;
typedef __attribute__((ext_vector_type(4))) float f32x4;
typedef __attribute__((ext_vector_type(4))) unsigned short u16x4;
typedef __attribute__((ext_vector_type(8))) unsigned short u16x8;

__device__ __forceinline__ float gelu_f(float x) {
    return 0.5f * x * (1.0f + erff(x * 0.70710678118654752440f));
}
__device__ __forceinline__ float sigm_f(float x) {
    return 1.0f / (1.0f + __expf(-x));
}
__device__ __forceinline__ u16 f2bf(float f) {
    unsigned u = __builtin_bit_cast(unsigned, f);
    return (u16)((u + 0x7FFFu + ((u >> 16) & 1u)) >> 16);
}

// async global->LDS, 16B per lane; LDS dest must be wave-linear (base+lane*16)
#define GLD16(gsrc, ldst) __builtin_amdgcn_global_load_lds( \
    (__attribute__((address_space(1))) void*)(gsrc),        \
    (__attribute__((address_space(3))) void*)(ldst), 16, 0, 0)

// ---------------------------------------------------------------------------
// fp32 -> bf16 elementwise cast (8 elems/thread)
// ---------------------------------------------------------------------------
__global__ __launch_bounds__(256) void cast_bf16_k(
    const float* __restrict__ in, u16* __restrict__ out, int n8)
{
    int i = blockIdx.x * 256 + threadIdx.x;
    if (i >= n8) return;
    const float4* p = (const float4*)(in + (size_t)i * 8);
    float4 a = p[0], b = p[1];
    u16x8 o;
    o[0] = f2bf(a.x); o[1] = f2bf(a.y); o[2] = f2bf(a.z); o[3] = f2bf(a.w);
    o[4] = f2bf(b.x); o[5] = f2bf(b.y); o[6] = f2bf(b.z); o[7] = f2bf(b.w);
    *(u16x8*)(out + (size_t)i * 8) = o;
}

// ---------------------------------------------------------------------------
// W[K][N] fp32 -> Wt[N][K] bf16 (32x32 LDS tile, 256 threads)
// ---------------------------------------------------------------------------
__global__ __launch_bounds__(256) void transpose_cast_k(
    const float* __restrict__ W, u16* __restrict__ Wt, int K, int N)
{
    __shared__ float t[32][33];
    const int n0 = blockIdx.x * 32, k0 = blockIdx.y * 32;
    const int tid = threadIdx.x;
    {
        int kr = tid >> 3, nc = (tid & 7) * 4;
        float4 v = *(const float4*)(W + (size_t)(k0 + kr) * N + n0 + nc);
        t[kr][nc] = v.x; t[kr][nc + 1] = v.y; t[kr][nc + 2] = v.z; t[kr][nc + 3] = v.w;
    }
    __syncthreads();
    {
        int nr = tid >> 3, kc = (tid & 7) * 4;
        u16x4 o = { f2bf(t[kc][nr]), f2bf(t[kc + 1][nr]),
                    f2bf(t[kc + 2][nr]), f2bf(t[kc + 3][nr]) };
        *(u16x4*)(Wt + (size_t)(n0 + nr) * K + k0 + kc) = o;
    }
}

// ---------------------------------------------------------------------------
// bf16 MFMA GEMM (m97 structure): C[M,N] = act(A[M,K] @ Bt[N,K]^T + bias)
// 128x128 tile, BK=32, 256 thr (4 waves, 2x2), 4x4 16x16x32 frags/wave.
// LDS granule swizzle: granule(m,kg) stored at kg^((m>>1)&3) so frag
// ds_read_b128 is ~2-way bank aliasing (free, m136). global_load_lds dest
// is wave-linear; swizzle applied by permuting the GLOBAL source (rule 21).
// ---------------------------------------------------------------------------
template<bool BIAS, bool GELU, bool ACCUM, bool BF16OUT>
__global__ __launch_bounds__(256) void gemm_mfma(
    const u16* __restrict__ A, const u16* __restrict__ Bt,
    const float* __restrict__ bias, void* __restrict__ Cv,
    int M, int N, int K)
{
    __shared__ u16 As[4096];   // 128 rows x 32 k (8 KB)
    __shared__ u16 Bs[4096];
    const int tid = threadIdx.x;
    const int m0 = blockIdx.y * 128, n0 = blockIdx.x * 128;
    const int w = tid >> 6, l = tid & 63;
    const int mw = (w >> 1) * 64, nw = (w & 1) * 64;
    const int lr = l & 15, kg = l >> 4;
    const int swz = kg ^ ((lr >> 1) & 3);    // frag k-granule after swizzle

    f32x4 acc[4][4];
#pragma unroll
    for (int i = 0; i < 4; ++i)
#pragma unroll
        for (int j = 0; j < 4; ++j) acc[i][j] = (f32x4){0.f, 0.f, 0.f, 0.f};

    // staging: granules G0=tid, G1=256+tid; LDS holds source (m, (G&3)^((m>>1)&3))
    const int mA0 = tid >> 2;
    const int kg0 = (tid & 3) ^ ((mA0 >> 1) & 3);
    const int mA1 = (256 + tid) >> 2;
    const int kg1 = ((256 + tid) & 3) ^ ((mA1 >> 1) & 3);
    const u16* a0 = A + (size_t)(m0 + mA0) * K + kg0 * 8;
    const u16* a1 = A + (size_t)(m0 + mA1) * K + kg1 * 8;
    const u16* b0 = Bt + (size_t)(n0 + mA0) * K + kg0 * 8;
    const u16* b1 = Bt + (size_t)(n0 + mA1) * K + kg1 * 8;
    u16* lA0 = As + tid * 8;  u16* lA1 = As + (256 + tid) * 8;
    u16* lB0 = Bs + tid * 8;  u16* lB1 = Bs + (256 + tid) * 8;

    for (int k0 = 0; k0 < K; k0 += 32) {
        __syncthreads();
        GLD16(a0 + k0, lA0); GLD16(a1 + k0, lA1);
        GLD16(b0 + k0, lB0); GLD16(b1 + k0, lB1);
        __syncthreads();   // compiler drains vmcnt before barrier

        bf16x8 aF[4], bF[4];
#pragma unroll
        for (int mt = 0; mt < 4; ++mt) {
            int row = mw + mt * 16 + lr;
            aF[mt] = *(const bf16x8*)&As[(row * 4 + swz) * 8];
            int rowb = nw + mt * 16 + lr;
            bF[mt] = *(const bf16x8*)&Bs[(rowb * 4 + swz) * 8];
        }
#pragma unroll
        for (int mt = 0; mt < 4; ++mt)
#pragma unroll
            for (int nt = 0; nt < 4; ++nt)
                acc[mt][nt] = __builtin_amdgcn_mfma_f32_16x16x32_bf16(
                    aF[mt], bF[nt], acc[mt][nt], 0, 0, 0);
    }

    // epilogue: lane l reg j -> row=(l>>4)*4+j, col=l&15 (m89/m91 layout)
    const int lq = l >> 4;
#pragma unroll
    for (int mt = 0; mt < 4; ++mt) {
#pragma unroll
        for (int nt = 0; nt < 4; ++nt) {
            int row = m0 + mw + mt * 16 + lq * 4;
            int col = n0 + nw + nt * 16 + lr;
            float bsv = BIAS ? bias[col] : 0.f;
#pragma unroll
            for (int j = 0; j < 4; ++j) {
                float v = acc[mt][nt][j] + bsv;
                if (GELU) v = gelu_f(v);
                size_t idx = (size_t)(row + j) * N + col;
                if (BF16OUT) {
                    ((u16*)Cv)[idx] = f2bf(v);
                } else {
                    float* C = (float*)Cv;
                    if (ACCUM) v += C[idx];
                    C[idx] = v;
                }
            }
        }
    }
}

// ---------------------------------------------------------------------------
// Flash attention (fp32). One block = 64 q-rows of one (b,h). 256 thr, 4 waves.
// LDS 52.5 KB -> 3 blocks/CU. K/V reads are wave-uniform broadcasts.
// ---------------------------------------------------------------------------
__global__ __launch_bounds__(256, 3) void attn_flash(
    const float* __restrict__ qkv, const float* __restrict__ nmda,
    const float* __restrict__ nmda_decay, float* __restrict__ branch)
{
    const int qt = (int)gridDim.x - 1 - (int)blockIdx.x;  // heavy tiles first
    const int h  = blockIdx.y;
    const int b  = blockIdx.z;
    const int tid = threadIdx.x;
    const int w   = tid >> 6;
    const int r   = tid & 63;
    const int q0  = qt * 64;

    __shared__ __align__(16) float kT[64][66];
    __shared__ __align__(16) float vT[64][66];
    __shared__ float sP[64][65];
    __shared__ float redm[4][64];
    __shared__ float reds[4][64];

    float q[64];
    {
        const float* qrow = qkv + (size_t)(b * T_ + q0 + r) * (3 * D_) + h * 64;
#pragma unroll
        for (int i = 0; i < 16; ++i) {
            float4 v = *(const float4*)(qrow + i * 4);
            q[4 * i + 0] = v.x; q[4 * i + 1] = v.y;
            q[4 * i + 2] = v.z; q[4 * i + 3] = v.w;
        }
    }

    float O[16];
#pragma unroll
    for (int i = 0; i < 16; ++i) O[i] = 0.f;
    float m_run = -INFINITY, l_run = 0.f;

    const int ldrow = tid >> 2;
    const int ldd   = (tid & 3) * 16;

    for (int kt = 0; kt <= qt; ++kt) {
        const int k0 = kt * 64;
        __syncthreads();
        {
            const float* krow = qkv + (size_t)(b * T_ + k0 + ldrow) * (3 * D_)
                              + D_ + h * 64 + ldd;
            const float* vrow = krow + D_;
#pragma unroll
            for (int i = 0; i < 4; ++i) {
                *(float4*)&kT[ldrow][ldd + 4 * i] = *(const float4*)(krow + 4 * i);
                *(float4*)&vT[ldrow][ldd + 4 * i] = *(const float4*)(vrow + 4 * i);
            }
        }
        __syncthreads();

        float s[16];
#pragma unroll 4
        for (int j = 0; j < 16; ++j) {
            const int kk = w * 16 + j;
            float a = 0.f;
#pragma unroll
            for (int d4 = 0; d4 < 16; ++d4) {
                float4 kv = *(const float4*)&kT[kk][d4 * 4];
                a += q[4 * d4 + 0] * kv.x + q[4 * d4 + 1] * kv.y
                   + q[4 * d4 + 2] * kv.z + q[4 * d4 + 3] * kv.w;
            }
            s[j] = a * 0.125f;
        }
        if (kt == qt) {
#pragma unroll
            for (int j = 0; j < 16; ++j)
                if (w * 16 + j > r) s[j] = -INFINITY;
        }

        float lm = s[0];
#pragma unroll
        for (int j = 1; j < 16; ++j) lm = fmaxf(lm, s[j]);
        redm[w][r] = lm;
        __syncthreads();
        const float mt = fmaxf(fmaxf(redm[0][r], redm[1][r]),
                               fmaxf(redm[2][r], redm[3][r]));
        const float m_new = fmaxf(m_run, mt);
        const float c = __expf(m_run - m_new);
        float ls = 0.f;
#pragma unroll
        for (int j = 0; j < 16; ++j) {
            float e = (s[j] == -INFINITY) ? 0.f : __expf(s[j] - m_new);
            sP[r][w * 16 + j] = e;
            ls += e;
        }
        reds[w][r] = ls;
        __syncthreads();
        l_run = l_run * c + (reds[0][r] + reds[1][r] + reds[2][r] + reds[3][r]);
        m_run = m_new;

#pragma unroll
        for (int i = 0; i < 16; ++i) O[i] *= c;
        const int d0 = w * 16;
#pragma unroll 4
        for (int kk = 0; kk < 64; ++kk) {
            const float p = sP[r][kk];
            float4 v0 = *(const float4*)&vT[kk][d0];
            float4 v1 = *(const float4*)&vT[kk][d0 + 4];
            float4 v2 = *(const float4*)&vT[kk][d0 + 8];
            float4 v3 = *(const float4*)&vT[kk][d0 + 12];
            O[0]  = fmaf(p, v0.x, O[0]);  O[1]  = fmaf(p, v0.y, O[1]);
            O[2]  = fmaf(p, v0.z, O[2]);  O[3]  = fmaf(p, v0.w, O[3]);
            O[4]  = fmaf(p, v1.x, O[4]);  O[5]  = fmaf(p, v1.y, O[5]);
            O[6]  = fmaf(p, v1.z, O[6]);  O[7]  = fmaf(p, v1.w, O[7]);
            O[8]  = fmaf(p, v2.x, O[8]);  O[9]  = fmaf(p, v2.y, O[9]);
            O[10] = fmaf(p, v2.z, O[10]); O[11] = fmaf(p, v2.w, O[11]);
            O[12] = fmaf(p, v3.x, O[12]); O[13] = fmaf(p, v3.y, O[13]);
            O[14] = fmaf(p, v3.z, O[14]); O[15] = fmaf(p, v3.w, O[15]);
        }
    }

    const float inv = 1.f / l_run;
    const int dd = w * 16;
    const float* nd = nmda_decay + h * 64 + dd;
    const float* nm = nmda + (size_t)(b * NH_ + h) * 64 + dd;
    float* orow = branch + (size_t)(b * T_ + q0 + r) * D_ + h * 64 + dd;
#pragma unroll
    for (int i = 0; i < 16; ++i)
        orow[i] = O[i] * inv + nm[i] * sigm_f(nd[i]);
}

// ---------------------------------------------------------------------------
// Causal grouped temporal conv (k=5, pad_left=4) + residual + bias.
// ---------------------------------------------------------------------------
__global__ __launch_bounds__(128) void tconv_kernel(
    const float* __restrict__ branch, const float* __restrict__ w,
    const float* __restrict__ bias, float* __restrict__ xcf2)
{
    const int tid = threadIdx.x;
    const int t0 = blockIdx.x * 128;
    const int c0 = blockIdx.y * 4;
    const int b  = blockIdx.z;
    const int g  = c0 >> 6;
    __shared__ __align__(16) float xl[132][68];
    __shared__ __align__(16) float wl[4][5][64];
    __shared__ float bl[4];

    for (int idx = tid; idx < 132 * 64; idx += 128) {
        int tl = idx >> 6, i = idx & 63;
        int tg = t0 - 4 + tl;
        xl[tl][i] = (tg >= 0) ? branch[(size_t)(b * T_ + tg) * D_ + g * 64 + i] : 0.f;
    }
    for (int idx = tid; idx < 4 * 320; idx += 128) {
        int cc = idx / 320, r = idx - cc * 320;
        int i = r / 5, k = r - i * 5;
        wl[cc][k][i] = w[(size_t)(c0 + cc) * 320 + r];
    }
    if (tid < 4) bl[tid] = bias[c0 + tid];
    __syncthreads();

    const int cl = c0 & 63;
    float4 self = *(const float4*)&xl[tid + 4][cl];
    float a0 = self.x + bl[0], a1 = self.y + bl[1], a2 = self.z + bl[2], a3 = self.w + bl[3];
#pragma unroll
    for (int k = 0; k < 5; ++k) {
        const float* xr = &xl[tid + k][0];
#pragma unroll
        for (int i4 = 0; i4 < 16; ++i4) {
            float4 xv = *(const float4*)&xr[i4 * 4];
            float4 w0 = *(const float4*)&wl[0][k][i4 * 4];
            float4 w1 = *(const float4*)&wl[1][k][i4 * 4];
            float4 w2 = *(const float4*)&wl[2][k][i4 * 4];
            float4 w3 = *(const float4*)&wl[3][k][i4 * 4];
            a0 += xv.x * w0.x + xv.y * w0.y + xv.z * w0.z + xv.w * w0.w;
            a1 += xv.x * w1.x + xv.y * w1.y + xv.z * w1.z + xv.w * w1.w;
            a2 += xv.x * w2.x + xv.y * w2.y + xv.z * w2.z + xv.w * w2.w;
            a3 += xv.x * w3.x + xv.y * w3.y + xv.z * w3.z + xv.w * w3.w;
        }
    }
    *(float4*)&xcf2[(size_t)(b * T_ + t0 + tid) * D_ + c0] = make_float4(a0, a1, a2, a3);
}

// ---------------------------------------------------------------------------
// Grouped 1x1 up-proj (64 -> 128 per group) + bias + exact GELU.
// ---------------------------------------------------------------------------
__global__ __launch_bounds__(256) void ffu_kernel(
    const float* __restrict__ xcf2, const float* __restrict__ w,
    const float* __restrict__ bias, float* __restrict__ hid)
{
    const int tid = threadIdx.x;
    const int t0 = blockIdx.x * 64, g = blockIdx.y, b = blockIdx.z;
    __shared__ __align__(16) float al[64][68];
    __shared__ __align__(16) float wlds[64][132];

    for (int idx = tid; idx < 64 * 64; idx += 256) {
        int i = idx & 63, tl = idx >> 6;
        al[i][tl] = xcf2[(size_t)(b * T_ + t0 + tl) * D_ + g * 64 + i];
    }
    for (int idx = tid; idx < 128 * 64; idx += 256) {
        int i = idx & 63, o = idx >> 6;
        wlds[i][o] = w[(size_t)(g * 128 + o) * 64 + i];
    }
    __syncthreads();

    const int ot = (tid & 15) * 8;
    const int tt = (tid >> 4) * 4;
    float acc[4][8];
#pragma unroll
    for (int i = 0; i < 4; ++i)
#pragma unroll
        for (int j = 0; j < 8; ++j) acc[i][j] = 0.f;

#pragma unroll 8
    for (int i = 0; i < 64; ++i) {
        float4 a4 = *(const float4*)&al[i][tt];
        float4 w0 = *(const float4*)&wlds[i][ot];
        float4 w1 = *(const float4*)&wlds[i][ot + 4];
        float av[4] = {a4.x, a4.y, a4.z, a4.w};
        float wv[8] = {w0.x, w0.y, w0.z, w0.w, w1.x, w1.y, w1.z, w1.w};
#pragma unroll
        for (int ti = 0; ti < 4; ++ti)
#pragma unroll
            for (int oi = 0; oi < 8; ++oi)
                acc[ti][oi] = fmaf(av[ti], wv[oi], acc[ti][oi]);
    }

    float4 bb0 = *(const float4*)&bias[g * 128 + ot];
    float4 bb1 = *(const float4*)&bias[g * 128 + ot + 4];
    float bv[8] = {bb0.x, bb0.y, bb0.z, bb0.w, bb1.x, bb1.y, bb1.z, bb1.w};
#pragma unroll
    for (int ti = 0; ti < 4; ++ti) {
        float o_[8];
#pragma unroll
        for (int oi = 0; oi < 8; ++oi) o_[oi] = gelu_f(acc[ti][oi] + bv[oi]);
        float* hp = hid + (size_t)(b * T_ + t0 + tt + ti) * (2 * D_) + g * 128 + ot;
        *(float4*)hp       = make_float4(o_[0], o_[1], o_[2], o_[3]);
        *(float4*)(hp + 4) = make_float4(o_[4], o_[5], o_[6], o_[7]);
    }
}

// ---------------------------------------------------------------------------
// Grouped 1x1 down-proj (128 -> 64) + bias + residual + per-head GroupNorm
// + nmda state update at t = T-1.
// ---------------------------------------------------------------------------
__global__ __launch_bounds__(256) void ffd_gn_kernel(
    const float* __restrict__ hid, const float* __restrict__ w,
    const float* __restrict__ bias, const float* __restrict__ branch,
    const float* __restrict__ gn_w, const float* __restrict__ gn_b,
    const float* __restrict__ nmda, const float* __restrict__ nmda_decay,
    float* __restrict__ normed, float* __restrict__ out_nmda)
{
    const int tid = threadIdx.x;
    const int t0 = blockIdx.x * 32, g = blockIdx.y, b = blockIdx.z;
    __shared__ __align__(16) float al[128][36];
    __shared__ __align__(16) float wl[128][68];

    for (int idx = tid; idx < 128 * 32; idx += 256) {
        int j = idx & 127, tl = idx >> 7;
        al[j][tl] = hid[(size_t)(b * T_ + t0 + tl) * (2 * D_) + g * 128 + j];
    }
    for (int idx = tid; idx < 64 * 128; idx += 256) {
        int j = idx & 127, c = idx >> 7;
        wl[j][c] = w[(size_t)(g * 64 + c) * 128 + j];
    }
    __syncthreads();

    const int c0 = (tid & 15) * 4;
    const int tt = (tid >> 4) * 2;
    float acc[2][4];
#pragma unroll
    for (int i = 0; i < 2; ++i)
#pragma unroll
        for (int j = 0; j < 4; ++j) acc[i][j] = 0.f;

#pragma unroll 8
    for (int j = 0; j < 128; ++j) {
        float2 a2 = *(const float2*)&al[j][tt];
        float4 w4 = *(const float4*)&wl[j][c0];
        acc[0][0] = fmaf(a2.x, w4.x, acc[0][0]);
        acc[0][1] = fmaf(a2.x, w4.y, acc[0][1]);
        acc[0][2] = fmaf(a2.x, w4.z, acc[0][2]);
        acc[0][3] = fmaf(a2.x, w4.w, acc[0][3]);
        acc[1][0] = fmaf(a2.y, w4.x, acc[1][0]);
        acc[1][1] = fmaf(a2.y, w4.y, acc[1][1]);
        acc[1][2] = fmaf(a2.y, w4.z, acc[1][2]);
        acc[1][3] = fmaf(a2.y, w4.w, acc[1][3]);
    }

    float4 bb = *(const float4*)&bias[g * 64 + c0];
    float4 gw = *(const float4*)&gn_w[g * 64 + c0];
    float4 gb = *(const float4*)&gn_b[g * 64 + c0];

#pragma unroll
    for (int tq = 0; tq < 2; ++tq) {
        const int tg = t0 + tt + tq;
        float4 br = *(const float4*)&branch[(size_t)(b * T_ + tg) * D_ + g * 64 + c0];
        float r0 = br.x + acc[tq][0] + bb.x;
        float r1 = br.y + acc[tq][1] + bb.y;
        float r2 = br.z + acc[tq][2] + bb.z;
        float r3 = br.w + acc[tq][3] + bb.w;
        float sm = r0 + r1 + r2 + r3;
#pragma unroll
        for (int m = 1; m < 16; m <<= 1) sm += __shfl_xor(sm, m);
        float mu = sm * (1.f / 64.f);
        float d0 = r0 - mu, d1 = r1 - mu, d2 = r2 - mu, d3 = r3 - mu;
        float vs = d0 * d0 + d1 * d1 + d2 * d2 + d3 * d3;
#pragma unroll
        for (int m = 1; m < 16; m <<= 1) vs += __shfl_xor(vs, m);
        float is = rsqrtf(vs * (1.f / 64.f) + 1e-5f);
        float n0 = d0 * is * gw.x + gb.x;
        float n1 = d1 * is * gw.y + gb.y;
        float n2 = d2 * is * gw.z + gb.z;
        float n3 = d3 * is * gw.w + gb.w;
        *(float4*)&normed[(size_t)(b * T_ + tg) * D_ + g * 64 + c0] =
            make_float4(n0, n1, n2, n3);
        if (tg == T_ - 1) {
            float nv[4] = {n0, n1, n2, n3};
#pragma unroll
            for (int cc = 0; cc < 4; ++cc) {
                int dloc = c0 + cc;
                int ni = (b * NH_ + g) * 64 + dloc;
                float t2 = sigm_f(nmda_decay[g * 64 + dloc]);
                out_nmda[ni] = t2 * nmda[ni] + (1.f - t2) * nv[cc];
            }
        }
    }
}

// ---------------------------------------------------------------------------
// LayerNorm over D=1024 per row.
// ---------------------------------------------------------------------------
__global__ __launch_bounds__(256) void ln_kernel(
    const float* __restrict__ x, const float* __restrict__ w,
    const float* __restrict__ bo, float* __restrict__ y)
{
    __shared__ float red[8];
    const int row = blockIdx.x, tid = threadIdx.x;
    const float* xr = x + (size_t)row * D_;
    float4 v = *(const float4*)&xr[tid * 4];
    float s = v.x + v.y + v.z + v.w;
#pragma unroll
    for (int m = 32; m; m >>= 1) s += __shfl_xor(s, m);
    if ((tid & 63) == 0) red[tid >> 6] = s;
    __syncthreads();
    float mu = (red[0] + red[1] + red[2] + red[3]) * (1.f / 1024.f);
    float dx = v.x - mu, dy = v.y - mu, dz = v.z - mu, dw = v.w - mu;
    float q = dx * dx + dy * dy + dz * dz + dw * dw;
#pragma unroll
    for (int m = 32; m; m >>= 1) q += __shfl_xor(q, m);
    if ((tid & 63) == 0) red[4 + (tid >> 6)] = q;
    __syncthreads();
    float var = (red[4] + red[5] + red[6] + red[7]) * (1.f / 1024.f);
    float is = rsqrtf(var + 1e-5f);
    float4 wv = *(const float4*)&w[tid * 4];
    float4 bv = *(const float4*)&bo[tid * 4];
    *(float4*)&y[(size_t)row * D_ + tid * 4] =
        make_float4(dx * is * wv.x + bv.x, dy * is * wv.y + bv.y,
                    dz * is * wv.z + bv.z, dw * is * wv.w + bv.w);
}

// ---------------------------------------------------------------------------
extern "C" void kernel_launch(void* const* d_in, const int* in_sizes, int n_in,
                              void* d_out, int out_size, void* d_ws, size_t ws_size,
                              hipStream_t stream)
{
    const float* x       = (const float*)d_in[0];
    const float* nmda    = (const float*)d_in[1];
    const float* qkv_w   = (const float*)d_in[2];
    const float* nmda_d  = (const float*)d_in[3];
    const float* tconv_w = (const float*)d_in[4];
    const float* tconv_b = (const float*)d_in[5];
    const float* ffu_w   = (const float*)d_in[6];
    const float* ffu_b   = (const float*)d_in[7];
    const float* ffd_w   = (const float*)d_in[8];
    const float* ffd_b   = (const float*)d_in[9];
    const float* gn_w    = (const float*)d_in[10];
    const float* gn_b    = (const float*)d_in[11];
    const float* soma_w  = (const float*)d_in[12];
    const float* ln_w    = (const float*)d_in[13];
    const float* ln_b    = (const float*)d_in[14];
    const float* w1      = (const float*)d_in[15];
    const float* b1      = (const float*)d_in[16];
    const float* w2      = (const float*)d_in[17];
    const float* b2      = (const float*)d_in[18];
    (void)in_sizes; (void)n_in; (void)out_size; (void)ws_size;

    float* outp     = (float*)d_out;
    float* soma     = outp;                               // B*T*D
    float* out_nmda = outp + (size_t)B_ * T_ * D_;        // B*NH*DH

    // ws regions (floats) — total 25,165,824 floats (same as round 1/3)
    float* ws     = (float*)d_ws;
    float* branch = ws;                       // R0: 4M floats
    float* xcf2   = ws + (size_t)4194304;     // R1: 4M
    float* normed = ws + (size_t)8388608;     // R2: 4M
    float* qkvb   = ws + (size_t)12582912;    // R3: 12.58M
    float* hid = qkvb;     // fp32 ff-hidden reuses R3 (qkv dead after attn)
    float* lns = normed;   // fp32 lns reuses R2 (normed dead after its cast)
    u16*   h1bf = (u16*)qkvb;  // bf16 MLP hidden reuses R3 (hid dead after ffd)

    // bf16 scratch aliased into dead regions by lifetime:
    u16* xbf    = (u16*)normed;                  // G1: x_bf   (4,194,304 u16)
    u16* wqkvT  = (u16*)normed + 4194304;        // G1: qkv_w^T (3,145,728 u16)
    u16* normbf = (u16*)xcf2;                    // G2: normed_bf
    u16* somaT  = (u16*)xcf2 + 4194304;          // G2: soma_w^T (1,048,576)
    u16* lnsbf  = (u16*)branch;                  // G3: lns_bf
    u16* w1T    = (u16*)branch + 4194304;        // G3: w1^T (3,145,728)
    u16* w2T    = (u16*)xcf2;                    // G4: w2^T (3,145,728)

    // 0. casts for qkv GEMM
    hipLaunchKernelGGL(cast_bf16_k, dim3(2048), dim3(256), 0, stream, x, xbf, 524288);
    hipLaunchKernelGGL(transpose_cast_k, dim3(96, 32), dim3(256), 0, stream,
                       qkv_w, wqkvT, 1024, 3072);
    // 1. qkv = x @ qkv_w  (bf16 MFMA, fp32 out)
    hipLaunchKernelGGL((gemm_mfma<false, false, false, false>), dim3(24, 32), dim3(256), 0, stream,
                       xbf, wqkvT, nullptr, qkvb, 4096, 3072, 1024);
    // 2. flash attention + nmda shift -> branch
    hipLaunchKernelGGL(attn_flash, dim3(16, NH_, B_), dim3(256), 0, stream,
                       qkvb, nmda, nmda_d, branch);
    // 3. xcf2 = branch + tconv(branch)
    hipLaunchKernelGGL(tconv_kernel, dim3(8, 256, 4), dim3(128), 0, stream,
                       branch, tconv_w, tconv_b, xcf2);
    // 4. hid = gelu(ffu(xcf2))
    hipLaunchKernelGGL(ffu_kernel, dim3(16, NH_, B_), dim3(256), 0, stream,
                       xcf2, ffu_w, ffu_b, hid);
    // 5. normed = GroupNorm(branch + ffd(hid)); nmda update at t=T-1
    hipLaunchKernelGGL(ffd_gn_kernel, dim3(32, NH_, B_), dim3(256), 0, stream,
                       hid, ffd_w, ffd_b, branch, gn_w, gn_b, nmda, nmda_d,
                       normed, out_nmda);
    // 6. soma = normed @ soma_w (bf16 MFMA)
    hipLaunchKernelGGL(cast_bf16_k, dim3(2048), dim3(256), 0, stream, normed, normbf, 524288);
    hipLaunchKernelGGL(transpose_cast_k, dim3(32, 32), dim3(256), 0, stream,
                       soma_w, somaT, 1024, 1024);
    hipLaunchKernelGGL((gemm_mfma<false, false, false, false>), dim3(8, 32), dim3(256), 0, stream,
                       normbf, somaT, nullptr, soma, 4096, 1024, 1024);
    // 7. lns = LayerNorm(soma)
    hipLaunchKernelGGL(ln_kernel, dim3(B_ * T_), dim3(256), 0, stream,
                       soma, ln_w, ln_b, lns);
    // 8. h1 = gelu(lns @ w1 + b1)  (bf16 out)
    hipLaunchKernelGGL(cast_bf16_k, dim3(2048), dim3(256), 0, stream, lns, lnsbf, 524288);
    hipLaunchKernelGGL(transpose_cast_k, dim3(96, 32), dim3(256), 0, stream,
                       w1, w1T, 1024, 3072);
    hipLaunchKernelGGL((gemm_mfma<true, true, false, true>), dim3(24, 32), dim3(256), 0, stream,
                       lnsbf, w1T, b1, h1bf, 4096, 3072, 1024);
    // 9. soma += h1 @ w2 + b2
    hipLaunchKernelGGL(transpose_cast_k, dim3(32, 96), dim3(256), 0, stream,
                       w2, w2T, 3072, 1024);
    hipLaunchKernelGGL((gemm_mfma<true, false, true, false>), dim3(8, 32), dim3(256), 0, stream,
                       h1bf, w2T, b2, soma, 4096, 1024, 3072);
}

// Round 7
// 795.620 us; speedup vs baseline: 4.3032x; 1.9994x over previous
//
#include <hip/hip_runtime.h>
#include <math.h>

#define B_  4
#define T_  1024
#define D_  1024
#define NH_ 16
#define DH_ 64
#define SH_ 3072

typedef unsigned short u16;
typedef __attribute__((ext_vector_type(8))) short bf16x8;
typedef __attribute__((ext_vector_type(4))) float f32x4;
typedef __attribute__((ext_vector_type(4))) unsigned short u16x4;
typedef __attribute__((ext_vector_type(8))) unsigned short u16x8;

__device__ __forceinline__ float gelu_f(float x) {
    return 0.5f * x * (1.0f + erff(x * 0.70710678118654752440f));
}
__device__ __forceinline__ float sigm_f(float x) {
    return 1.0f / (1.0f + __expf(-x));
}
__device__ __forceinline__ u16 f2bf(float f) {
    unsigned u = __builtin_bit_cast(unsigned, f);
    return (u16)((u + 0x7FFFu + ((u >> 16) & 1u)) >> 16);
}
__device__ __forceinline__ bf16x8 pack8(float4 a, float4 b, float sc) {
    u16x8 o;
    o[0] = f2bf(a.x * sc); o[1] = f2bf(a.y * sc);
    o[2] = f2bf(a.z * sc); o[3] = f2bf(a.w * sc);
    o[4] = f2bf(b.x * sc); o[5] = f2bf(b.y * sc);
    o[6] = f2bf(b.z * sc); o[7] = f2bf(b.w * sc);
    return __builtin_bit_cast(bf16x8, o);
}

// async global->LDS, 16B per lane; LDS dest must be wave-linear (base+lane*16)
#define GLD16(gsrc, ldst) __builtin_amdgcn_global_load_lds( \
    (__attribute__((address_space(1))) void*)(gsrc),        \
    (__attribute__((address_space(3))) void*)(ldst), 16, 0, 0)

// ---------------------------------------------------------------------------
// fp32 -> bf16 elementwise cast (8 elems/thread)
// ---------------------------------------------------------------------------
__global__ __launch_bounds__(256) void cast_bf16_k(
    const float* __restrict__ in, u16* __restrict__ out, int n8)
{
    int i = blockIdx.x * 256 + threadIdx.x;
    if (i >= n8) return;
    const float4* p = (const float4*)(in + (size_t)i * 8);
    float4 a = p[0], b = p[1];
    u16x8 o;
    o[0] = f2bf(a.x); o[1] = f2bf(a.y); o[2] = f2bf(a.z); o[3] = f2bf(a.w);
    o[4] = f2bf(b.x); o[5] = f2bf(b.y); o[6] = f2bf(b.z); o[7] = f2bf(b.w);
    *(u16x8*)(out + (size_t)i * 8) = o;
}

// ---------------------------------------------------------------------------
// W[K][N] fp32 -> Wt[N][K] bf16 (32x32 LDS tile, 256 threads)
// ---------------------------------------------------------------------------
__global__ __launch_bounds__(256) void transpose_cast_k(
    const float* __restrict__ W, u16* __restrict__ Wt, int K, int N)
{
    __shared__ float t[32][33];
    const int n0 = blockIdx.x * 32, k0 = blockIdx.y * 32;
    const int tid = threadIdx.x;
    {
        int kr = tid >> 3, nc = (tid & 7) * 4;
        float4 v = *(const float4*)(W + (size_t)(k0 + kr) * N + n0 + nc);
        t[kr][nc] = v.x; t[kr][nc + 1] = v.y; t[kr][nc + 2] = v.z; t[kr][nc + 3] = v.w;
    }
    __syncthreads();
    {
        int nr = tid >> 3, kc = (tid & 7) * 4;
        u16x4 o = { f2bf(t[kc][nr]), f2bf(t[kc + 1][nr]),
                    f2bf(t[kc + 2][nr]), f2bf(t[kc + 3][nr]) };
        *(u16x4*)(Wt + (size_t)(n0 + nr) * K + k0 + kc) = o;
    }
}

// ---------------------------------------------------------------------------
// bf16 MFMA GEMM (m97 structure): C[M,N] = act(A[M,K] @ Bt[N,K]^T + bias)
// 128x128 tile, BK=32, 256 thr (4 waves, 2x2), 4x4 16x16x32 frags/wave.
// ---------------------------------------------------------------------------
template<bool BIAS, bool GELU, bool ACCUM, bool BF16OUT>
__global__ __launch_bounds__(256) void gemm_mfma(
    const u16* __restrict__ A, const u16* __restrict__ Bt,
    const float* __restrict__ bias, void* __restrict__ Cv,
    int M, int N, int K)
{
    __shared__ u16 As[4096];   // 128 rows x 32 k (8 KB)
    __shared__ u16 Bs[4096];
    const int tid = threadIdx.x;
    const int m0 = blockIdx.y * 128, n0 = blockIdx.x * 128;
    const int w = tid >> 6, l = tid & 63;
    const int mw = (w >> 1) * 64, nw = (w & 1) * 64;
    const int lr = l & 15, kg = l >> 4;
    const int swz = kg ^ ((lr >> 1) & 3);    // frag k-granule after swizzle

    f32x4 acc[4][4];
#pragma unroll
    for (int i = 0; i < 4; ++i)
#pragma unroll
        for (int j = 0; j < 4; ++j) acc[i][j] = (f32x4){0.f, 0.f, 0.f, 0.f};

    const int mA0 = tid >> 2;
    const int kg0 = (tid & 3) ^ ((mA0 >> 1) & 3);
    const int mA1 = (256 + tid) >> 2;
    const int kg1 = ((256 + tid) & 3) ^ ((mA1 >> 1) & 3);
    const u16* a0 = A + (size_t)(m0 + mA0) * K + kg0 * 8;
    const u16* a1 = A + (size_t)(m0 + mA1) * K + kg1 * 8;
    const u16* b0 = Bt + (size_t)(n0 + mA0) * K + kg0 * 8;
    const u16* b1 = Bt + (size_t)(n0 + mA1) * K + kg1 * 8;
    u16* lA0 = As + tid * 8;  u16* lA1 = As + (256 + tid) * 8;
    u16* lB0 = Bs + tid * 8;  u16* lB1 = Bs + (256 + tid) * 8;

    for (int k0 = 0; k0 < K; k0 += 32) {
        __syncthreads();
        GLD16(a0 + k0, lA0); GLD16(a1 + k0, lA1);
        GLD16(b0 + k0, lB0); GLD16(b1 + k0, lB1);
        __syncthreads();

        bf16x8 aF[4], bF[4];
#pragma unroll
        for (int mt = 0; mt < 4; ++mt) {
            int row = mw + mt * 16 + lr;
            aF[mt] = *(const bf16x8*)&As[(row * 4 + swz) * 8];
            int rowb = nw + mt * 16 + lr;
            bF[mt] = *(const bf16x8*)&Bs[(rowb * 4 + swz) * 8];
        }
#pragma unroll
        for (int mt = 0; mt < 4; ++mt)
#pragma unroll
            for (int nt = 0; nt < 4; ++nt)
                acc[mt][nt] = __builtin_amdgcn_mfma_f32_16x16x32_bf16(
                    aF[mt], bF[nt], acc[mt][nt], 0, 0, 0);
    }

    const int lq = l >> 4;
#pragma unroll
    for (int mt = 0; mt < 4; ++mt) {
#pragma unroll
        for (int nt = 0; nt < 4; ++nt) {
            int row = m0 + mw + mt * 16 + lq * 4;
            int col = n0 + nw + nt * 16 + lr;
            float bsv = BIAS ? bias[col] : 0.f;
#pragma unroll
            for (int j = 0; j < 4; ++j) {
                float v = acc[mt][nt][j] + bsv;
                if (GELU) v = gelu_f(v);
                size_t idx = (size_t)(row + j) * N + col;
                if (BF16OUT) {
                    ((u16*)Cv)[idx] = f2bf(v);
                } else {
                    float* C = (float*)Cv;
                    if (ACCUM) v += C[idx];
                    C[idx] = v;
                }
            }
        }
    }
}

// ---------------------------------------------------------------------------
// bf16 MFMA flash attention. Block = 64 q-rows of one (b,h), 4 waves, each
// wave owns 16 q-rows. Fragment conventions identical to gemm_mfma (verified
// on HW round 6): A/B row|col = l&15, k-granule = l>>4; C row=(l>>4)*4+j,
// col=l&15.
//   S = (Q*0.125) K^T  : A=Q frags (regs), Bt=K tile [kv][d] in LDS.
//   O += P V           : A=P (per-wave LDS), Bt=V^T tile [d][kv] in LDS.
// All LDS tiles XOR-granule-swizzled (granule g stored at g^(row&7)) so frag
// ds_read_b128 is 2-way (free, m136). P->LDS->A-frag is same-wave (no bar).
// No min-blocks bound (round-6 lesson: (256,3) caused spills, 220MB scratch).
// ---------------------------------------------------------------------------
__global__ __launch_bounds__(256) void attn_mfma(
    const float* __restrict__ qkv, const float* __restrict__ nmda,
    const float* __restrict__ nmda_decay, float* __restrict__ branch)
{
    const int qt = 15 - (int)blockIdx.x;   // heavy q-tiles first
    const int h  = blockIdx.y;
    const int b  = blockIdx.z;
    const int tid = threadIdx.x;
    const int w  = tid >> 6, l = tid & 63;
    const int lr = l & 15, kg = l >> 4;
    const int q0 = qt * 64;

    __shared__ u16 Ks[64 * 64];      // [kv][d]   swizzled, 8 KB
    __shared__ u16 Vt[64 * 64];      // [d][kv]   swizzled, 8 KB
    __shared__ u16 Ps[4][16 * 64];   // per-wave [q][kv] swizzled, 8 KB

    // ---- Q fragments (scale 0.125 folded; exact: pow2 only shifts exponent)
    bf16x8 qf[2];
    {
        const float* qrow = qkv + (size_t)(b * T_ + q0 + w * 16 + lr) * (3 * D_) + h * 64;
#pragma unroll
        for (int ks = 0; ks < 2; ++ks) {
            float4 f0 = *(const float4*)(qrow + ks * 32 + kg * 8);
            float4 f1 = *(const float4*)(qrow + ks * 32 + kg * 8 + 4);
            qf[ks] = pack8(f0, f1, 0.125f);
        }
    }

    // ---- nmda shift per output column (constant over tiles)
    float nshift[4];
#pragma unroll
    for (int nt = 0; nt < 4; ++nt) {
        int d = nt * 16 + lr;
        nshift[nt] = nmda[(size_t)(b * NH_ + h) * 64 + d] * sigm_f(nmda_decay[h * 64 + d]);
    }

    f32x4 O[4];
#pragma unroll
    for (int nt = 0; nt < 4; ++nt) O[nt] = (f32x4){0.f, 0.f, 0.f, 0.f};
    float m_run[4] = {-INFINITY, -INFINITY, -INFINITY, -INFINITY};
    float l_run[4] = {0.f, 0.f, 0.f, 0.f};

    const int srow = tid >> 2;          // staging row 0..63
    const int sq   = tid & 3;

    for (int kt = 0; kt <= qt; ++kt) {
        const int kv0 = kt * 64;
        __syncthreads();   // all waves done reading previous Ks/Vt
        {
            const float* krow = qkv + (size_t)(b * T_ + kv0 + srow) * (3 * D_)
                              + D_ + h * 64;
            const float* vrow = krow + D_;
            // K tile: rows [kv][d], granule swizzle g^(row&7)
#pragma unroll
            for (int g2 = 0; g2 < 2; ++g2) {
                int gk = sq * 2 + g2;
                float4 f0 = *(const float4*)(krow + gk * 8);
                float4 f1 = *(const float4*)(krow + gk * 8 + 4);
                *(bf16x8*)&Ks[srow * 64 + ((gk ^ (srow & 7)) << 3)] = pack8(f0, f1, 1.f);
            }
            // V^T tile: [d][kv], granule swizzle on kv
#pragma unroll
            for (int i4 = 0; i4 < 4; ++i4) {
                float4 f = *(const float4*)(vrow + sq * 16 + i4 * 4);
                float vv[4] = {f.x, f.y, f.z, f.w};
#pragma unroll
                for (int c = 0; c < 4; ++c) {
                    int d = sq * 16 + i4 * 4 + c;
                    Vt[d * 64 + (((srow >> 3) ^ (d & 7)) << 3) + (srow & 7)] = f2bf(vv[c]);
                }
            }
        }
        __syncthreads();

        // ---- S = Q K^T (scaled)
        f32x4 s[4];
#pragma unroll
        for (int nt = 0; nt < 4; ++nt) s[nt] = (f32x4){0.f, 0.f, 0.f, 0.f};
#pragma unroll
        for (int ks = 0; ks < 2; ++ks) {
#pragma unroll
            for (int nt = 0; nt < 4; ++nt) {
                int krow = nt * 16 + lr;
                bf16x8 kf = *(const bf16x8*)&Ks[krow * 64 + (((ks * 4 + kg) ^ (krow & 7)) << 3)];
                s[nt] = __builtin_amdgcn_mfma_f32_16x16x32_bf16(qf[ks], kf, s[nt], 0, 0, 0);
            }
        }

        // ---- causal mask (only the diagonal tile needs it)
        if (kt == qt) {
#pragma unroll
            for (int nt = 0; nt < 4; ++nt) {
                int kvp = nt * 16 + lr;
#pragma unroll
                for (int j = 0; j < 4; ++j) {
                    int qp = w * 16 + kg * 4 + j;
                    if (kvp > qp) s[nt][j] = -INFINITY;
                }
            }
        }

        // ---- online softmax (row spread over 16 lanes sharing kg)
        float c4[4];
#pragma unroll
        for (int j = 0; j < 4; ++j) {
            float mx = fmaxf(fmaxf(s[0][j], s[1][j]), fmaxf(s[2][j], s[3][j]));
#pragma unroll
            for (int msk = 1; msk < 16; msk <<= 1) mx = fmaxf(mx, __shfl_xor(mx, msk));
            float mn = fmaxf(m_run[j], mx);
            c4[j] = __expf(m_run[j] - mn);     // -inf -> 0 first time
            m_run[j] = mn;
            float ls = 0.f;
#pragma unroll
            for (int nt = 0; nt < 4; ++nt) {
                float p = __expf(s[nt][j] - mn);   // -inf -> 0 for masked
                s[nt][j] = p;
                ls += p;
            }
#pragma unroll
            for (int msk = 1; msk < 16; msk <<= 1) ls += __shfl_xor(ls, msk);
            l_run[j] = l_run[j] * c4[j] + ls;
        }

        // ---- P -> per-wave LDS (bf16, swizzled); same-wave RAW, no barrier
#pragma unroll
        for (int nt = 0; nt < 4; ++nt) {
#pragma unroll
            for (int j = 0; j < 4; ++j) {
                int r = kg * 4 + j;
                int c = nt * 16 + lr;
                Ps[w][r * 64 + (((c >> 3) ^ (r & 7)) << 3) + (c & 7)] = f2bf(s[nt][j]);
            }
        }

        // ---- O rescale + PV
#pragma unroll
        for (int nt = 0; nt < 4; ++nt)
#pragma unroll
            for (int j = 0; j < 4; ++j) O[nt][j] *= c4[j];
#pragma unroll
        for (int ks = 0; ks < 2; ++ks) {
            bf16x8 pa = *(const bf16x8*)&Ps[w][lr * 64 + (((ks * 4 + kg) ^ (lr & 7)) << 3)];
#pragma unroll
            for (int nt = 0; nt < 4; ++nt) {
                int vrow = nt * 16 + lr;
                bf16x8 vf = *(const bf16x8*)&Vt[vrow * 64 + (((ks * 4 + kg) ^ (vrow & 7)) << 3)];
                O[nt] = __builtin_amdgcn_mfma_f32_16x16x32_bf16(pa, vf, O[nt], 0, 0, 0);
            }
        }
    }

    // ---- epilogue: normalize + nmda shift, store fp32
#pragma unroll
    for (int j = 0; j < 4; ++j) {
        float inv = 1.f / l_run[j];
        int qrow = q0 + w * 16 + kg * 4 + j;
        float* orow = branch + (size_t)(b * T_ + qrow) * D_ + h * 64;
#pragma unroll
        for (int nt = 0; nt < 4; ++nt)
            orow[nt * 16 + lr] = O[nt][j] * inv + nshift[nt];
    }
}

// ---------------------------------------------------------------------------
// Causal grouped temporal conv (k=5, pad_left=4) + residual + bias.
// ---------------------------------------------------------------------------
__global__ __launch_bounds__(128) void tconv_kernel(
    const float* __restrict__ branch, const float* __restrict__ w,
    const float* __restrict__ bias, float* __restrict__ xcf2)
{
    const int tid = threadIdx.x;
    const int t0 = blockIdx.x * 128;
    const int c0 = blockIdx.y * 4;
    const int b  = blockIdx.z;
    const int g  = c0 >> 6;
    __shared__ __align__(16) float xl[132][68];
    __shared__ __align__(16) float wl[4][5][64];
    __shared__ float bl[4];

    for (int idx = tid; idx < 132 * 64; idx += 128) {
        int tl = idx >> 6, i = idx & 63;
        int tg = t0 - 4 + tl;
        xl[tl][i] = (tg >= 0) ? branch[(size_t)(b * T_ + tg) * D_ + g * 64 + i] : 0.f;
    }
    for (int idx = tid; idx < 4 * 320; idx += 128) {
        int cc = idx / 320, r = idx - cc * 320;
        int i = r / 5, k = r - i * 5;
        wl[cc][k][i] = w[(size_t)(c0 + cc) * 320 + r];
    }
    if (tid < 4) bl[tid] = bias[c0 + tid];
    __syncthreads();

    const int cl = c0 & 63;
    float4 self = *(const float4*)&xl[tid + 4][cl];
    float a0 = self.x + bl[0], a1 = self.y + bl[1], a2 = self.z + bl[2], a3 = self.w + bl[3];
#pragma unroll
    for (int k = 0; k < 5; ++k) {
        const float* xr = &xl[tid + k][0];
#pragma unroll
        for (int i4 = 0; i4 < 16; ++i4) {
            float4 xv = *(const float4*)&xr[i4 * 4];
            float4 w0 = *(const float4*)&wl[0][k][i4 * 4];
            float4 w1 = *(const float4*)&wl[1][k][i4 * 4];
            float4 w2 = *(const float4*)&wl[2][k][i4 * 4];
            float4 w3 = *(const float4*)&wl[3][k][i4 * 4];
            a0 += xv.x * w0.x + xv.y * w0.y + xv.z * w0.z + xv.w * w0.w;
            a1 += xv.x * w1.x + xv.y * w1.y + xv.z * w1.z + xv.w * w1.w;
            a2 += xv.x * w2.x + xv.y * w2.y + xv.z * w2.z + xv.w * w2.w;
            a3 += xv.x * w3.x + xv.y * w3.y + xv.z * w3.z + xv.w * w3.w;
        }
    }
    *(float4*)&xcf2[(size_t)(b * T_ + t0 + tid) * D_ + c0] = make_float4(a0, a1, a2, a3);
}

// ---------------------------------------------------------------------------
// Grouped 1x1 up-proj (64 -> 128 per group) + bias + exact GELU.
// ---------------------------------------------------------------------------
__global__ __launch_bounds__(256) void ffu_kernel(
    const float* __restrict__ xcf2, const float* __restrict__ w,
    const float* __restrict__ bias, float* __restrict__ hid)
{
    const int tid = threadIdx.x;
    const int t0 = blockIdx.x * 64, g = blockIdx.y, b = blockIdx.z;
    __shared__ __align__(16) float al[64][68];
    __shared__ __align__(16) float wlds[64][132];

    for (int idx = tid; idx < 64 * 64; idx += 256) {
        int i = idx & 63, tl = idx >> 6;
        al[i][tl] = xcf2[(size_t)(b * T_ + t0 + tl) * D_ + g * 64 + i];
    }
    for (int idx = tid; idx < 128 * 64; idx += 256) {
        int i = idx & 63, o = idx >> 6;
        wlds[i][o] = w[(size_t)(g * 128 + o) * 64 + i];
    }
    __syncthreads();

    const int ot = (tid & 15) * 8;
    const int tt = (tid >> 4) * 4;
    float acc[4][8];
#pragma unroll
    for (int i = 0; i < 4; ++i)
#pragma unroll
        for (int j = 0; j < 8; ++j) acc[i][j] = 0.f;

#pragma unroll 8
    for (int i = 0; i < 64; ++i) {
        float4 a4 = *(const float4*)&al[i][tt];
        float4 w0 = *(const float4*)&wlds[i][ot];
        float4 w1 = *(const float4*)&wlds[i][ot + 4];
        float av[4] = {a4.x, a4.y, a4.z, a4.w};
        float wv[8] = {w0.x, w0.y, w0.z, w0.w, w1.x, w1.y, w1.z, w1.w};
#pragma unroll
        for (int ti = 0; ti < 4; ++ti)
#pragma unroll
            for (int oi = 0; oi < 8; ++oi)
                acc[ti][oi] = fmaf(av[ti], wv[oi], acc[ti][oi]);
    }

    float4 bb0 = *(const float4*)&bias[g * 128 + ot];
    float4 bb1 = *(const float4*)&bias[g * 128 + ot + 4];
    float bv[8] = {bb0.x, bb0.y, bb0.z, bb0.w, bb1.x, bb1.y, bb1.z, bb1.w};
#pragma unroll
    for (int ti = 0; ti < 4; ++ti) {
        float o_[8];
#pragma unroll
        for (int oi = 0; oi < 8; ++oi) o_[oi] = gelu_f(acc[ti][oi] + bv[oi]);
        float* hp = hid + (size_t)(b * T_ + t0 + tt + ti) * (2 * D_) + g * 128 + ot;
        *(float4*)hp       = make_float4(o_[0], o_[1], o_[2], o_[3]);
        *(float4*)(hp + 4) = make_float4(o_[4], o_[5], o_[6], o_[7]);
    }
}

// ---------------------------------------------------------------------------
// Grouped 1x1 down-proj (128 -> 64) + bias + residual + per-head GroupNorm
// + nmda state update at t = T-1.
// ---------------------------------------------------------------------------
__global__ __launch_bounds__(256) void ffd_gn_kernel(
    const float* __restrict__ hid, const float* __restrict__ w,
    const float* __restrict__ bias, const float* __restrict__ branch,
    const float* __restrict__ gn_w, const float* __restrict__ gn_b,
    const float* __restrict__ nmda, const float* __restrict__ nmda_decay,
    float* __restrict__ normed, float* __restrict__ out_nmda)
{
    const int tid = threadIdx.x;
    const int t0 = blockIdx.x * 32, g = blockIdx.y, b = blockIdx.z;
    __shared__ __align__(16) float al[128][36];
    __shared__ __align__(16) float wl[128][68];

    for (int idx = tid; idx < 128 * 32; idx += 256) {
        int j = idx & 127, tl = idx >> 7;
        al[j][tl] = hid[(size_t)(b * T_ + t0 + tl) * (2 * D_) + g * 128 + j];
    }
    for (int idx = tid; idx < 64 * 128; idx += 256) {
        int j = idx & 127, c = idx >> 7;
        wl[j][c] = w[(size_t)(g * 64 + c) * 128 + j];
    }
    __syncthreads();

    const int c0 = (tid & 15) * 4;
    const int tt = (tid >> 4) * 2;
    float acc[2][4];
#pragma unroll
    for (int i = 0; i < 2; ++i)
#pragma unroll
        for (int j = 0; j < 4; ++j) acc[i][j] = 0.f;

#pragma unroll 8
    for (int j = 0; j < 128; ++j) {
        float2 a2 = *(const float2*)&al[j][tt];
        float4 w4 = *(const float4*)&wl[j][c0];
        acc[0][0] = fmaf(a2.x, w4.x, acc[0][0]);
        acc[0][1] = fmaf(a2.x, w4.y, acc[0][1]);
        acc[0][2] = fmaf(a2.x, w4.z, acc[0][2]);
        acc[0][3] = fmaf(a2.x, w4.w, acc[0][3]);
        acc[1][0] = fmaf(a2.y, w4.x, acc[1][0]);
        acc[1][1] = fmaf(a2.y, w4.y, acc[1][1]);
        acc[1][2] = fmaf(a2.y, w4.z, acc[1][2]);
        acc[1][3] = fmaf(a2.y, w4.w, acc[1][3]);
    }

    float4 bb = *(const float4*)&bias[g * 64 + c0];
    float4 gw = *(const float4*)&gn_w[g * 64 + c0];
    float4 gb = *(const float4*)&gn_b[g * 64 + c0];

#pragma unroll
    for (int tq = 0; tq < 2; ++tq) {
        const int tg = t0 + tt + tq;
        float4 br = *(const float4*)&branch[(size_t)(b * T_ + tg) * D_ + g * 64 + c0];
        float r0 = br.x + acc[tq][0] + bb.x;
        float r1 = br.y + acc[tq][1] + bb.y;
        float r2 = br.z + acc[tq][2] + bb.z;
        float r3 = br.w + acc[tq][3] + bb.w;
        float sm = r0 + r1 + r2 + r3;
#pragma unroll
        for (int m = 1; m < 16; m <<= 1) sm += __shfl_xor(sm, m);
        float mu = sm * (1.f / 64.f);
        float d0 = r0 - mu, d1 = r1 - mu, d2 = r2 - mu, d3 = r3 - mu;
        float vs = d0 * d0 + d1 * d1 + d2 * d2 + d3 * d3;
#pragma unroll
        for (int m = 1; m < 16; m <<= 1) vs += __shfl_xor(vs, m);
        float is = rsqrtf(vs * (1.f / 64.f) + 1e-5f);
        float n0 = d0 * is * gw.x + gb.x;
        float n1 = d1 * is * gw.y + gb.y;
        float n2 = d2 * is * gw.z + gb.z;
        float n3 = d3 * is * gw.w + gb.w;
        *(float4*)&normed[(size_t)(b * T_ + tg) * D_ + g * 64 + c0] =
            make_float4(n0, n1, n2, n3);
        if (tg == T_ - 1) {
            float nv[4] = {n0, n1, n2, n3};
#pragma unroll
            for (int cc = 0; cc < 4; ++cc) {
                int dloc = c0 + cc;
                int ni = (b * NH_ + g) * 64 + dloc;
                float t2 = sigm_f(nmda_decay[g * 64 + dloc]);
                out_nmda[ni] = t2 * nmda[ni] + (1.f - t2) * nv[cc];
            }
        }
    }
}

// ---------------------------------------------------------------------------
// LayerNorm over D=1024 per row.
// ---------------------------------------------------------------------------
__global__ __launch_bounds__(256) void ln_kernel(
    const float* __restrict__ x, const float* __restrict__ w,
    const float* __restrict__ bo, float* __restrict__ y)
{
    __shared__ float red[8];
    const int row = blockIdx.x, tid = threadIdx.x;
    const float* xr = x + (size_t)row * D_;
    float4 v = *(const float4*)&xr[tid * 4];
    float s = v.x + v.y + v.z + v.w;
#pragma unroll
    for (int m = 32; m; m >>= 1) s += __shfl_xor(s, m);
    if ((tid & 63) == 0) red[tid >> 6] = s;
    __syncthreads();
    float mu = (red[0] + red[1] + red[2] + red[3]) * (1.f / 1024.f);
    float dx = v.x - mu, dy = v.y - mu, dz = v.z - mu, dw = v.w - mu;
    float q = dx * dx + dy * dy + dz * dz + dw * dw;
#pragma unroll
    for (int m = 32; m; m >>= 1) q += __shfl_xor(q, m);
    if ((tid & 63) == 0) red[4 + (tid >> 6)] = q;
    __syncthreads();
    float var = (red[4] + red[5] + red[6] + red[7]) * (1.f / 1024.f);
    float is = rsqrtf(var + 1e-5f);
    float4 wv = *(const float4*)&w[tid * 4];
    float4 bv = *(const float4*)&bo[tid * 4];
    *(float4*)&y[(size_t)row * D_ + tid * 4] =
        make_float4(dx * is * wv.x + bv.x, dy * is * wv.y + bv.y,
                    dz * is * wv.z + bv.z, dw * is * wv.w + bv.w);
}

// ---------------------------------------------------------------------------
extern "C" void kernel_launch(void* const* d_in, const int* in_sizes, int n_in,
                              void* d_out, int out_size, void* d_ws, size_t ws_size,
                              hipStream_t stream)
{
    const float* x       = (const float*)d_in[0];
    const float* nmda    = (const float*)d_in[1];
    const float* qkv_w   = (const float*)d_in[2];
    const float* nmda_d  = (const float*)d_in[3];
    const float* tconv_w = (const float*)d_in[4];
    const float* tconv_b = (const float*)d_in[5];
    const float* ffu_w   = (const float*)d_in[6];
    const float* ffu_b   = (const float*)d_in[7];
    const float* ffd_w   = (const float*)d_in[8];
    const float* ffd_b   = (const float*)d_in[9];
    const float* gn_w    = (const float*)d_in[10];
    const float* gn_b    = (const float*)d_in[11];
    const float* soma_w  = (const float*)d_in[12];
    const float* ln_w    = (const float*)d_in[13];
    const float* ln_b    = (const float*)d_in[14];
    const float* w1      = (const float*)d_in[15];
    const float* b1      = (const float*)d_in[16];
    const float* w2      = (const float*)d_in[17];
    const float* b2      = (const float*)d_in[18];
    (void)in_sizes; (void)n_in; (void)out_size; (void)ws_size;

    float* outp     = (float*)d_out;
    float* soma     = outp;                               // B*T*D
    float* out_nmda = outp + (size_t)B_ * T_ * D_;        // B*NH*DH

    // ws regions (floats) — total 25,165,824 floats
    float* ws     = (float*)d_ws;
    float* branch = ws;                       // R0: 4M floats
    float* xcf2   = ws + (size_t)4194304;     // R1: 4M
    float* normed = ws + (size_t)8388608;     // R2: 4M
    float* qkvb   = ws + (size_t)12582912;    // R3: 12.58M
    float* hid = qkvb;     // fp32 ff-hidden reuses R3 (qkv dead after attn)
    float* lns = normed;   // fp32 lns reuses R2 (normed dead after its cast)
    u16*   h1bf = (u16*)qkvb;  // bf16 MLP hidden reuses R3 (hid dead after ffd)

    // bf16 scratch aliased into dead regions by lifetime:
    u16* xbf    = (u16*)normed;                  // G1: x_bf   (4,194,304 u16)
    u16* wqkvT  = (u16*)normed + 4194304;        // G1: qkv_w^T (3,145,728 u16)
    u16* normbf = (u16*)xcf2;                    // G2: normed_bf
    u16* somaT  = (u16*)xcf2 + 4194304;          // G2: soma_w^T (1,048,576)
    u16* lnsbf  = (u16*)branch;                  // G3: lns_bf
    u16* w1T    = (u16*)branch + 4194304;        // G3: w1^T (3,145,728)
    u16* w2T    = (u16*)xcf2;                    // G4: w2^T (3,145,728)

    // 0. casts for qkv GEMM
    hipLaunchKernelGGL(cast_bf16_k, dim3(2048), dim3(256), 0, stream, x, xbf, 524288);
    hipLaunchKernelGGL(transpose_cast_k, dim3(96, 32), dim3(256), 0, stream,
                       qkv_w, wqkvT, 1024, 3072);
    // 1. qkv = x @ qkv_w  (bf16 MFMA, fp32 out)
    hipLaunchKernelGGL((gemm_mfma<false, false, false, false>), dim3(24, 32), dim3(256), 0, stream,
                       xbf, wqkvT, nullptr, qkvb, 4096, 3072, 1024);
    // 2. bf16 MFMA flash attention + nmda shift -> branch
    hipLaunchKernelGGL(attn_mfma, dim3(16, NH_, B_), dim3(256), 0, stream,
                       qkvb, nmda, nmda_d, branch);
    // 3. xcf2 = branch + tconv(branch)
    hipLaunchKernelGGL(tconv_kernel, dim3(8, 256, 4), dim3(128), 0, stream,
                       branch, tconv_w, tconv_b, xcf2);
    // 4. hid = gelu(ffu(xcf2))
    hipLaunchKernelGGL(ffu_kernel, dim3(16, NH_, B_), dim3(256), 0, stream,
                       xcf2, ffu_w, ffu_b, hid);
    // 5. normed = GroupNorm(branch + ffd(hid)); nmda update at t=T-1
    hipLaunchKernelGGL(ffd_gn_kernel, dim3(32, NH_, B_), dim3(256), 0, stream,
                       hid, ffd_w, ffd_b, branch, gn_w, gn_b, nmda, nmda_d,
                       normed, out_nmda);
    // 6. soma = normed @ soma_w (bf16 MFMA)
    hipLaunchKernelGGL(cast_bf16_k, dim3(2048), dim3(256), 0, stream, normed, normbf, 524288);
    hipLaunchKernelGGL(transpose_cast_k, dim3(32, 32), dim3(256), 0, stream,
                       soma_w, somaT, 1024, 1024);
    hipLaunchKernelGGL((gemm_mfma<false, false, false, false>), dim3(8, 32), dim3(256), 0, stream,
                       normbf, somaT, nullptr, soma, 4096, 1024, 1024);
    // 7. lns = LayerNorm(soma)
    hipLaunchKernelGGL(ln_kernel, dim3(B_ * T_), dim3(256), 0, stream,
                       soma, ln_w, ln_b, lns);
    // 8. h1 = gelu(lns @ w1 + b1)  (bf16 out)
    hipLaunchKernelGGL(cast_bf16_k, dim3(2048), dim3(256), 0, stream, lns, lnsbf, 524288);
    hipLaunchKernelGGL(transpose_cast_k, dim3(96, 32), dim3(256), 0, stream,
                       w1, w1T, 1024, 3072);
    hipLaunchKernelGGL((gemm_mfma<true, true, false, true>), dim3(24, 32), dim3(256), 0, stream,
                       lnsbf, w1T, b1, h1bf, 4096, 3072, 1024);
    // 9. soma += h1 @ w2 + b2
    hipLaunchKernelGGL(transpose_cast_k, dim3(32, 96), dim3(256), 0, stream,
                       w2, w2T, 3072, 1024);
    hipLaunchKernelGGL((gemm_mfma<true, false, true, false>), dim3(8, 32), dim3(256), 0, stream,
                       h1bf, w2T, b2, soma, 4096, 1024, 3072);
}

// Round 8
// 580.864 us; speedup vs baseline: 5.8941x; 1.3697x over previous
//
#include <hip/hip_runtime.h>
#include <math.h>

#define B_  4
#define T_  1024
#define D_  1024
#define NH_ 16
#define DH_ 64
#define SH_ 3072

typedef unsigned short u16;
typedef __attribute__((ext_vector_type(8))) short bf16x8;
typedef __attribute__((ext_vector_type(4))) float f32x4;
typedef __attribute__((ext_vector_type(4))) unsigned short u16x4;
typedef __attribute__((ext_vector_type(8))) unsigned short u16x8;

__device__ __forceinline__ float gelu_f(float x) {
    return 0.5f * x * (1.0f + erff(x * 0.70710678118654752440f));
}
__device__ __forceinline__ float sigm_f(float x) {
    return 1.0f / (1.0f + __expf(-x));
}
__device__ __forceinline__ u16 f2bf(float f) {
    unsigned u = __builtin_bit_cast(unsigned, f);
    return (u16)((u + 0x7FFFu + ((u >> 16) & 1u)) >> 16);
}
__device__ __forceinline__ bf16x8 pack8(float4 a, float4 b, float sc) {
    u16x8 o;
    o[0] = f2bf(a.x * sc); o[1] = f2bf(a.y * sc);
    o[2] = f2bf(a.z * sc); o[3] = f2bf(a.w * sc);
    o[4] = f2bf(b.x * sc); o[5] = f2bf(b.y * sc);
    o[6] = f2bf(b.z * sc); o[7] = f2bf(b.w * sc);
    return __builtin_bit_cast(bf16x8, o);
}

// async global->LDS, 16B per lane; LDS dest must be wave-linear (base+lane*16)
#define GLD16(gsrc, ldst) __builtin_amdgcn_global_load_lds( \
    (__attribute__((address_space(1))) void*)(gsrc),        \
    (__attribute__((address_space(3))) void*)(ldst), 16, 0, 0)

// ---------------------------------------------------------------------------
// fp32 -> bf16 elementwise cast (8 elems/thread)
// ---------------------------------------------------------------------------
__global__ __launch_bounds__(256) void cast_bf16_k(
    const float* __restrict__ in, u16* __restrict__ out, int n8)
{
    int i = blockIdx.x * 256 + threadIdx.x;
    if (i >= n8) return;
    const float4* p = (const float4*)(in + (size_t)i * 8);
    float4 a = p[0], b = p[1];
    u16x8 o;
    o[0] = f2bf(a.x); o[1] = f2bf(a.y); o[2] = f2bf(a.z); o[3] = f2bf(a.w);
    o[4] = f2bf(b.x); o[5] = f2bf(b.y); o[6] = f2bf(b.z); o[7] = f2bf(b.w);
    *(u16x8*)(out + (size_t)i * 8) = o;
}

// ---------------------------------------------------------------------------
// W[K][N] fp32 -> Wt[N][K] bf16 (32x32 LDS tile, 256 threads)
// ---------------------------------------------------------------------------
__global__ __launch_bounds__(256) void transpose_cast_k(
    const float* __restrict__ W, u16* __restrict__ Wt, int K, int N)
{
    __shared__ float t[32][33];
    const int n0 = blockIdx.x * 32, k0 = blockIdx.y * 32;
    const int tid = threadIdx.x;
    {
        int kr = tid >> 3, nc = (tid & 7) * 4;
        float4 v = *(const float4*)(W + (size_t)(k0 + kr) * N + n0 + nc);
        t[kr][nc] = v.x; t[kr][nc + 1] = v.y; t[kr][nc + 2] = v.z; t[kr][nc + 3] = v.w;
    }
    __syncthreads();
    {
        int nr = tid >> 3, kc = (tid & 7) * 4;
        u16x4 o = { f2bf(t[kc][nr]), f2bf(t[kc + 1][nr]),
                    f2bf(t[kc + 2][nr]), f2bf(t[kc + 3][nr]) };
        *(u16x4*)(Wt + (size_t)(n0 + nr) * K + k0 + kc) = o;
    }
}

// ---------------------------------------------------------------------------
// bf16 MFMA GEMM (m97 structure): C[M,N] = act(A[M,K] @ Bt[N,K]^T + bias)
// 128x128 tile, BK=32, 256 thr (4 waves, 2x2), 4x4 16x16x32 frags/wave.
// ---------------------------------------------------------------------------
template<bool BIAS, bool GELU, bool ACCUM, bool BF16OUT>
__global__ __launch_bounds__(256) void gemm_mfma(
    const u16* __restrict__ A, const u16* __restrict__ Bt,
    const float* __restrict__ bias, void* __restrict__ Cv,
    int M, int N, int K)
{
    __shared__ u16 As[4096];   // 128 rows x 32 k (8 KB)
    __shared__ u16 Bs[4096];
    const int tid = threadIdx.x;
    const int m0 = blockIdx.y * 128, n0 = blockIdx.x * 128;
    const int w = tid >> 6, l = tid & 63;
    const int mw = (w >> 1) * 64, nw = (w & 1) * 64;
    const int lr = l & 15, kg = l >> 4;
    const int swz = kg ^ ((lr >> 1) & 3);    // frag k-granule after swizzle

    f32x4 acc[4][4];
#pragma unroll
    for (int i = 0; i < 4; ++i)
#pragma unroll
        for (int j = 0; j < 4; ++j) acc[i][j] = (f32x4){0.f, 0.f, 0.f, 0.f};

    const int mA0 = tid >> 2;
    const int kg0 = (tid & 3) ^ ((mA0 >> 1) & 3);
    const int mA1 = (256 + tid) >> 2;
    const int kg1 = ((256 + tid) & 3) ^ ((mA1 >> 1) & 3);
    const u16* a0 = A + (size_t)(m0 + mA0) * K + kg0 * 8;
    const u16* a1 = A + (size_t)(m0 + mA1) * K + kg1 * 8;
    const u16* b0 = Bt + (size_t)(n0 + mA0) * K + kg0 * 8;
    const u16* b1 = Bt + (size_t)(n0 + mA1) * K + kg1 * 8;
    u16* lA0 = As + tid * 8;  u16* lA1 = As + (256 + tid) * 8;
    u16* lB0 = Bs + tid * 8;  u16* lB1 = Bs + (256 + tid) * 8;

    for (int k0 = 0; k0 < K; k0 += 32) {
        __syncthreads();
        GLD16(a0 + k0, lA0); GLD16(a1 + k0, lA1);
        GLD16(b0 + k0, lB0); GLD16(b1 + k0, lB1);
        __syncthreads();

        bf16x8 aF[4], bF[4];
#pragma unroll
        for (int mt = 0; mt < 4; ++mt) {
            int row = mw + mt * 16 + lr;
            aF[mt] = *(const bf16x8*)&As[(row * 4 + swz) * 8];
            int rowb = nw + mt * 16 + lr;
            bF[mt] = *(const bf16x8*)&Bs[(rowb * 4 + swz) * 8];
        }
#pragma unroll
        for (int mt = 0; mt < 4; ++mt)
#pragma unroll
            for (int nt = 0; nt < 4; ++nt)
                acc[mt][nt] = __builtin_amdgcn_mfma_f32_16x16x32_bf16(
                    aF[mt], bF[nt], acc[mt][nt], 0, 0, 0);
    }

    const int lq = l >> 4;
#pragma unroll
    for (int mt = 0; mt < 4; ++mt) {
#pragma unroll
        for (int nt = 0; nt < 4; ++nt) {
            int row = m0 + mw + mt * 16 + lq * 4;
            int col = n0 + nw + nt * 16 + lr;
            float bsv = BIAS ? bias[col] : 0.f;
#pragma unroll
            for (int j = 0; j < 4; ++j) {
                float v = acc[mt][nt][j] + bsv;
                if (GELU) v = gelu_f(v);
                size_t idx = (size_t)(row + j) * N + col;
                if (BF16OUT) {
                    ((u16*)Cv)[idx] = f2bf(v);
                } else {
                    float* C = (float*)Cv;
                    if (ACCUM) v += C[idx];
                    C[idx] = v;
                }
            }
        }
    }
}

// ---------------------------------------------------------------------------
// bf16 MFMA flash attention (unchanged from round 7 — verified).
// ---------------------------------------------------------------------------
__global__ __launch_bounds__(256) void attn_mfma(
    const float* __restrict__ qkv, const float* __restrict__ nmda,
    const float* __restrict__ nmda_decay, float* __restrict__ branch)
{
    const int qt = 15 - (int)blockIdx.x;   // heavy q-tiles first
    const int h  = blockIdx.y;
    const int b  = blockIdx.z;
    const int tid = threadIdx.x;
    const int w  = tid >> 6, l = tid & 63;
    const int lr = l & 15, kg = l >> 4;
    const int q0 = qt * 64;

    __shared__ u16 Ks[64 * 64];      // [kv][d]   swizzled, 8 KB
    __shared__ u16 Vt[64 * 64];      // [d][kv]   swizzled, 8 KB
    __shared__ u16 Ps[4][16 * 64];   // per-wave [q][kv] swizzled, 8 KB

    bf16x8 qf[2];
    {
        const float* qrow = qkv + (size_t)(b * T_ + q0 + w * 16 + lr) * (3 * D_) + h * 64;
#pragma unroll
        for (int ks = 0; ks < 2; ++ks) {
            float4 f0 = *(const float4*)(qrow + ks * 32 + kg * 8);
            float4 f1 = *(const float4*)(qrow + ks * 32 + kg * 8 + 4);
            qf[ks] = pack8(f0, f1, 0.125f);
        }
    }

    float nshift[4];
#pragma unroll
    for (int nt = 0; nt < 4; ++nt) {
        int d = nt * 16 + lr;
        nshift[nt] = nmda[(size_t)(b * NH_ + h) * 64 + d] * sigm_f(nmda_decay[h * 64 + d]);
    }

    f32x4 O[4];
#pragma unroll
    for (int nt = 0; nt < 4; ++nt) O[nt] = (f32x4){0.f, 0.f, 0.f, 0.f};
    float m_run[4] = {-INFINITY, -INFINITY, -INFINITY, -INFINITY};
    float l_run[4] = {0.f, 0.f, 0.f, 0.f};

    const int srow = tid >> 2;
    const int sq   = tid & 3;

    for (int kt = 0; kt <= qt; ++kt) {
        const int kv0 = kt * 64;
        __syncthreads();
        {
            const float* krow = qkv + (size_t)(b * T_ + kv0 + srow) * (3 * D_)
                              + D_ + h * 64;
            const float* vrow = krow + D_;
#pragma unroll
            for (int g2 = 0; g2 < 2; ++g2) {
                int gk = sq * 2 + g2;
                float4 f0 = *(const float4*)(krow + gk * 8);
                float4 f1 = *(const float4*)(krow + gk * 8 + 4);
                *(bf16x8*)&Ks[srow * 64 + ((gk ^ (srow & 7)) << 3)] = pack8(f0, f1, 1.f);
            }
#pragma unroll
            for (int i4 = 0; i4 < 4; ++i4) {
                float4 f = *(const float4*)(vrow + sq * 16 + i4 * 4);
                float vv[4] = {f.x, f.y, f.z, f.w};
#pragma unroll
                for (int c = 0; c < 4; ++c) {
                    int d = sq * 16 + i4 * 4 + c;
                    Vt[d * 64 + (((srow >> 3) ^ (d & 7)) << 3) + (srow & 7)] = f2bf(vv[c]);
                }
            }
        }
        __syncthreads();

        f32x4 s[4];
#pragma unroll
        for (int nt = 0; nt < 4; ++nt) s[nt] = (f32x4){0.f, 0.f, 0.f, 0.f};
#pragma unroll
        for (int ks = 0; ks < 2; ++ks) {
#pragma unroll
            for (int nt = 0; nt < 4; ++nt) {
                int krow = nt * 16 + lr;
                bf16x8 kf = *(const bf16x8*)&Ks[krow * 64 + (((ks * 4 + kg) ^ (krow & 7)) << 3)];
                s[nt] = __builtin_amdgcn_mfma_f32_16x16x32_bf16(qf[ks], kf, s[nt], 0, 0, 0);
            }
        }

        if (kt == qt) {
#pragma unroll
            for (int nt = 0; nt < 4; ++nt) {
                int kvp = nt * 16 + lr;
#pragma unroll
                for (int j = 0; j < 4; ++j) {
                    int qp = w * 16 + kg * 4 + j;
                    if (kvp > qp) s[nt][j] = -INFINITY;
                }
            }
        }

        float c4[4];
#pragma unroll
        for (int j = 0; j < 4; ++j) {
            float mx = fmaxf(fmaxf(s[0][j], s[1][j]), fmaxf(s[2][j], s[3][j]));
#pragma unroll
            for (int msk = 1; msk < 16; msk <<= 1) mx = fmaxf(mx, __shfl_xor(mx, msk));
            float mn = fmaxf(m_run[j], mx);
            c4[j] = __expf(m_run[j] - mn);
            m_run[j] = mn;
            float ls = 0.f;
#pragma unroll
            for (int nt = 0; nt < 4; ++nt) {
                float p = __expf(s[nt][j] - mn);
                s[nt][j] = p;
                ls += p;
            }
#pragma unroll
            for (int msk = 1; msk < 16; msk <<= 1) ls += __shfl_xor(ls, msk);
            l_run[j] = l_run[j] * c4[j] + ls;
        }

#pragma unroll
        for (int nt = 0; nt < 4; ++nt) {
#pragma unroll
            for (int j = 0; j < 4; ++j) {
                int r = kg * 4 + j;
                int c = nt * 16 + lr;
                Ps[w][r * 64 + (((c >> 3) ^ (r & 7)) << 3) + (c & 7)] = f2bf(s[nt][j]);
            }
        }

#pragma unroll
        for (int nt = 0; nt < 4; ++nt)
#pragma unroll
            for (int j = 0; j < 4; ++j) O[nt][j] *= c4[j];
#pragma unroll
        for (int ks = 0; ks < 2; ++ks) {
            bf16x8 pa = *(const bf16x8*)&Ps[w][lr * 64 + (((ks * 4 + kg) ^ (lr & 7)) << 3)];
#pragma unroll
            for (int nt = 0; nt < 4; ++nt) {
                int vrow = nt * 16 + lr;
                bf16x8 vf = *(const bf16x8*)&Vt[vrow * 64 + (((ks * 4 + kg) ^ (vrow & 7)) << 3)];
                O[nt] = __builtin_amdgcn_mfma_f32_16x16x32_bf16(pa, vf, O[nt], 0, 0, 0);
            }
        }
    }

#pragma unroll
    for (int j = 0; j < 4; ++j) {
        float inv = 1.f / l_run[j];
        int qrow = q0 + w * 16 + kg * 4 + j;
        float* orow = branch + (size_t)(b * T_ + qrow) * D_ + h * 64;
#pragma unroll
        for (int nt = 0; nt < 4; ++nt)
            orow[nt * 16 + lr] = O[nt][j] * inv + nshift[nt];
    }
}

// ---------------------------------------------------------------------------
// Causal grouped temporal conv (k=5, pad_left=4) + residual + bias.
// Re-tiled (round 8): 16 output channels/block, 256 threads, float4 staging.
// 4x less x-tile staging redundancy vs the 4-channel version. Weight reads in
// compute are wave-uniform float4 broadcasts (conflict-free); x reads are at
// the 8-way structural floor (64 lanes x 16B over 32 banks, stride 68).
// ---------------------------------------------------------------------------
__global__ __launch_bounds__(256) void tconv_kernel(
    const float* __restrict__ branch, const float* __restrict__ w,
    const float* __restrict__ bias, float* __restrict__ xcf2)
{
    const int tid = threadIdx.x;
    const int t0 = blockIdx.x * 128;
    const int c0 = blockIdx.y * 16;     // global out-channel base (16/block)
    const int b  = blockIdx.z;
    const int g  = c0 >> 6;
    __shared__ __align__(16) float xl[132][68];   // 35.9 KB
    __shared__ __align__(16) float wl[16][5][64]; // 20.5 KB, [cc][k][i]
    __shared__ float bl[16];

    // x tile, vectorized: 132 rows x 16 quads
    for (int idx = tid; idx < 132 * 16; idx += 256) {
        int tl = idx >> 4, q = (idx & 15) * 4;
        int tg = t0 - 4 + tl;
        float4 v = (tg >= 0)
            ? *(const float4*)&branch[(size_t)(b * T_ + tg) * D_ + g * 64 + q]
            : make_float4(0.f, 0.f, 0.f, 0.f);
        *(float4*)&xl[tl][q] = v;
    }
    // weights: coalesced scalar reads, transposed into [cc][k][i]
    for (int idx = tid; idx < 16 * 320; idx += 256) {
        int cc = idx / 320, r = idx - cc * 320;
        int i = r / 5, k = r - i * 5;
        wl[cc][k][i] = w[(size_t)(c0 + cc) * 320 + r];
    }
    if (tid < 16) bl[tid] = bias[c0 + tid];
    __syncthreads();

    const int t  = tid & 127;           // local time
    const int h8 = (tid >> 7) * 8;      // channel octet 0 or 8
    const int cl = (c0 & 63) + h8;      // in-group channel base

    float acc[8];
    {
        float4 s0 = *(const float4*)&xl[t + 4][cl];
        float4 s1 = *(const float4*)&xl[t + 4][cl + 4];
        acc[0] = s0.x + bl[h8 + 0]; acc[1] = s0.y + bl[h8 + 1];
        acc[2] = s0.z + bl[h8 + 2]; acc[3] = s0.w + bl[h8 + 3];
        acc[4] = s1.x + bl[h8 + 4]; acc[5] = s1.y + bl[h8 + 5];
        acc[6] = s1.z + bl[h8 + 6]; acc[7] = s1.w + bl[h8 + 7];
    }
#pragma unroll
    for (int k = 0; k < 5; ++k) {
        const float* xr = &xl[t + k][0];
#pragma unroll 4
        for (int i4 = 0; i4 < 16; ++i4) {
            float4 xv = *(const float4*)&xr[i4 * 4];
#pragma unroll
            for (int cc = 0; cc < 8; ++cc) {
                float4 w4 = *(const float4*)&wl[h8 + cc][k][i4 * 4];
                acc[cc] += xv.x * w4.x + xv.y * w4.y + xv.z * w4.z + xv.w * w4.w;
            }
        }
    }
    float* op = &xcf2[(size_t)(b * T_ + t0 + t) * D_ + c0 + h8];
    *(float4*)op       = make_float4(acc[0], acc[1], acc[2], acc[3]);
    *(float4*)(op + 4) = make_float4(acc[4], acc[5], acc[6], acc[7]);
}

// ---------------------------------------------------------------------------
// Grouped 1x1 up-proj (64 -> 128 per group) + bias + exact GELU.
// ---------------------------------------------------------------------------
__global__ __launch_bounds__(256) void ffu_kernel(
    const float* __restrict__ xcf2, const float* __restrict__ w,
    const float* __restrict__ bias, float* __restrict__ hid)
{
    const int tid = threadIdx.x;
    const int t0 = blockIdx.x * 64, g = blockIdx.y, b = blockIdx.z;
    __shared__ __align__(16) float al[64][68];
    __shared__ __align__(16) float wlds[64][132];

    for (int idx = tid; idx < 64 * 64; idx += 256) {
        int i = idx & 63, tl = idx >> 6;
        al[i][tl] = xcf2[(size_t)(b * T_ + t0 + tl) * D_ + g * 64 + i];
    }
    for (int idx = tid; idx < 128 * 64; idx += 256) {
        int i = idx & 63, o = idx >> 6;
        wlds[i][o] = w[(size_t)(g * 128 + o) * 64 + i];
    }
    __syncthreads();

    const int ot = (tid & 15) * 8;
    const int tt = (tid >> 4) * 4;
    float acc[4][8];
#pragma unroll
    for (int i = 0; i < 4; ++i)
#pragma unroll
        for (int j = 0; j < 8; ++j) acc[i][j] = 0.f;

#pragma unroll 8
    for (int i = 0; i < 64; ++i) {
        float4 a4 = *(const float4*)&al[i][tt];
        float4 w0 = *(const float4*)&wlds[i][ot];
        float4 w1 = *(const float4*)&wlds[i][ot + 4];
        float av[4] = {a4.x, a4.y, a4.z, a4.w};
        float wv[8] = {w0.x, w0.y, w0.z, w0.w, w1.x, w1.y, w1.z, w1.w};
#pragma unroll
        for (int ti = 0; ti < 4; ++ti)
#pragma unroll
            for (int oi = 0; oi < 8; ++oi)
                acc[ti][oi] = fmaf(av[ti], wv[oi], acc[ti][oi]);
    }

    float4 bb0 = *(const float4*)&bias[g * 128 + ot];
    float4 bb1 = *(const float4*)&bias[g * 128 + ot + 4];
    float bv[8] = {bb0.x, bb0.y, bb0.z, bb0.w, bb1.x, bb1.y, bb1.z, bb1.w};
#pragma unroll
    for (int ti = 0; ti < 4; ++ti) {
        float o_[8];
#pragma unroll
        for (int oi = 0; oi < 8; ++oi) o_[oi] = gelu_f(acc[ti][oi] + bv[oi]);
        float* hp = hid + (size_t)(b * T_ + t0 + tt + ti) * (2 * D_) + g * 128 + ot;
        *(float4*)hp       = make_float4(o_[0], o_[1], o_[2], o_[3]);
        *(float4*)(hp + 4) = make_float4(o_[4], o_[5], o_[6], o_[7]);
    }
}

// ---------------------------------------------------------------------------
// Grouped 1x1 down-proj (128 -> 64) + bias + residual + per-head GroupNorm
// + nmda state update at t = T-1.
// ---------------------------------------------------------------------------
__global__ __launch_bounds__(256) void ffd_gn_kernel(
    const float* __restrict__ hid, const float* __restrict__ w,
    const float* __restrict__ bias, const float* __restrict__ branch,
    const float* __restrict__ gn_w, const float* __restrict__ gn_b,
    const float* __restrict__ nmda, const float* __restrict__ nmda_decay,
    float* __restrict__ normed, float* __restrict__ out_nmda)
{
    const int tid = threadIdx.x;
    const int t0 = blockIdx.x * 32, g = blockIdx.y, b = blockIdx.z;
    __shared__ __align__(16) float al[128][36];
    __shared__ __align__(16) float wl[128][68];

    for (int idx = tid; idx < 128 * 32; idx += 256) {
        int j = idx & 127, tl = idx >> 7;
        al[j][tl] = hid[(size_t)(b * T_ + t0 + tl) * (2 * D_) + g * 128 + j];
    }
    for (int idx = tid; idx < 64 * 128; idx += 256) {
        int j = idx & 127, c = idx >> 7;
        wl[j][c] = w[(size_t)(g * 64 + c) * 128 + j];
    }
    __syncthreads();

    const int c0 = (tid & 15) * 4;
    const int tt = (tid >> 4) * 2;
    float acc[2][4];
#pragma unroll
    for (int i = 0; i < 2; ++i)
#pragma unroll
        for (int j = 0; j < 4; ++j) acc[i][j] = 0.f;

#pragma unroll 8
    for (int j = 0; j < 128; ++j) {
        float2 a2 = *(const float2*)&al[j][tt];
        float4 w4 = *(const float4*)&wl[j][c0];
        acc[0][0] = fmaf(a2.x, w4.x, acc[0][0]);
        acc[0][1] = fmaf(a2.x, w4.y, acc[0][1]);
        acc[0][2] = fmaf(a2.x, w4.z, acc[0][2]);
        acc[0][3] = fmaf(a2.x, w4.w, acc[0][3]);
        acc[1][0] = fmaf(a2.y, w4.x, acc[1][0]);
        acc[1][1] = fmaf(a2.y, w4.y, acc[1][1]);
        acc[1][2] = fmaf(a2.y, w4.z, acc[1][2]);
        acc[1][3] = fmaf(a2.y, w4.w, acc[1][3]);
    }

    float4 bb = *(const float4*)&bias[g * 64 + c0];
    float4 gw = *(const float4*)&gn_w[g * 64 + c0];
    float4 gb = *(const float4*)&gn_b[g * 64 + c0];

#pragma unroll
    for (int tq = 0; tq < 2; ++tq) {
        const int tg = t0 + tt + tq;
        float4 br = *(const float4*)&branch[(size_t)(b * T_ + tg) * D_ + g * 64 + c0];
        float r0 = br.x + acc[tq][0] + bb.x;
        float r1 = br.y + acc[tq][1] + bb.y;
        float r2 = br.z + acc[tq][2] + bb.z;
        float r3 = br.w + acc[tq][3] + bb.w;
        float sm = r0 + r1 + r2 + r3;
#pragma unroll
        for (int m = 1; m < 16; m <<= 1) sm += __shfl_xor(sm, m);
        float mu = sm * (1.f / 64.f);
        float d0 = r0 - mu, d1 = r1 - mu, d2 = r2 - mu, d3 = r3 - mu;
        float vs = d0 * d0 + d1 * d1 + d2 * d2 + d3 * d3;
#pragma unroll
        for (int m = 1; m < 16; m <<= 1) vs += __shfl_xor(vs, m);
        float is = rsqrtf(vs * (1.f / 64.f) + 1e-5f);
        float n0 = d0 * is * gw.x + gb.x;
        float n1 = d1 * is * gw.y + gb.y;
        float n2 = d2 * is * gw.z + gb.z;
        float n3 = d3 * is * gw.w + gb.w;
        *(float4*)&normed[(size_t)(b * T_ + tg) * D_ + g * 64 + c0] =
            make_float4(n0, n1, n2, n3);
        if (tg == T_ - 1) {
            float nv[4] = {n0, n1, n2, n3};
#pragma unroll
            for (int cc = 0; cc < 4; ++cc) {
                int dloc = c0 + cc;
                int ni = (b * NH_ + g) * 64 + dloc;
                float t2 = sigm_f(nmda_decay[g * 64 + dloc]);
                out_nmda[ni] = t2 * nmda[ni] + (1.f - t2) * nv[cc];
            }
        }
    }
}

// ---------------------------------------------------------------------------
// LayerNorm over D=1024 per row.
// ---------------------------------------------------------------------------
__global__ __launch_bounds__(256) void ln_kernel(
    const float* __restrict__ x, const float* __restrict__ w,
    const float* __restrict__ bo, float* __restrict__ y)
{
    __shared__ float red[8];
    const int row = blockIdx.x, tid = threadIdx.x;
    const float* xr = x + (size_t)row * D_;
    float4 v = *(const float4*)&xr[tid * 4];
    float s = v.x + v.y + v.z + v.w;
#pragma unroll
    for (int m = 32; m; m >>= 1) s += __shfl_xor(s, m);
    if ((tid & 63) == 0) red[tid >> 6] = s;
    __syncthreads();
    float mu = (red[0] + red[1] + red[2] + red[3]) * (1.f / 1024.f);
    float dx = v.x - mu, dy = v.y - mu, dz = v.z - mu, dw = v.w - mu;
    float q = dx * dx + dy * dy + dz * dz + dw * dw;
#pragma unroll
    for (int m = 32; m; m >>= 1) q += __shfl_xor(q, m);
    if ((tid & 63) == 0) red[4 + (tid >> 6)] = q;
    __syncthreads();
    float var = (red[4] + red[5] + red[6] + red[7]) * (1.f / 1024.f);
    float is = rsqrtf(var + 1e-5f);
    float4 wv = *(const float4*)&w[tid * 4];
    float4 bv = *(const float4*)&bo[tid * 4];
    *(float4*)&y[(size_t)row * D_ + tid * 4] =
        make_float4(dx * is * wv.x + bv.x, dy * is * wv.y + bv.y,
                    dz * is * wv.z + bv.z, dw * is * wv.w + bv.w);
}

// ---------------------------------------------------------------------------
extern "C" void kernel_launch(void* const* d_in, const int* in_sizes, int n_in,
                              void* d_out, int out_size, void* d_ws, size_t ws_size,
                              hipStream_t stream)
{
    const float* x       = (const float*)d_in[0];
    const float* nmda    = (const float*)d_in[1];
    const float* qkv_w   = (const float*)d_in[2];
    const float* nmda_d  = (const float*)d_in[3];
    const float* tconv_w = (const float*)d_in[4];
    const float* tconv_b = (const float*)d_in[5];
    const float* ffu_w   = (const float*)d_in[6];
    const float* ffu_b   = (const float*)d_in[7];
    const float* ffd_w   = (const float*)d_in[8];
    const float* ffd_b   = (const float*)d_in[9];
    const float* gn_w    = (const float*)d_in[10];
    const float* gn_b    = (const float*)d_in[11];
    const float* soma_w  = (const float*)d_in[12];
    const float* ln_w    = (const float*)d_in[13];
    const float* ln_b    = (const float*)d_in[14];
    const float* w1      = (const float*)d_in[15];
    const float* b1      = (const float*)d_in[16];
    const float* w2      = (const float*)d_in[17];
    const float* b2      = (const float*)d_in[18];
    (void)in_sizes; (void)n_in; (void)out_size; (void)ws_size;

    float* outp     = (float*)d_out;
    float* soma     = outp;                               // B*T*D
    float* out_nmda = outp + (size_t)B_ * T_ * D_;        // B*NH*DH

    // ws regions (floats) — total 25,165,824 floats
    float* ws     = (float*)d_ws;
    float* branch = ws;                       // R0: 4M floats
    float* xcf2   = ws + (size_t)4194304;     // R1: 4M
    float* normed = ws + (size_t)8388608;     // R2: 4M
    float* qkvb   = ws + (size_t)12582912;    // R3: 12.58M
    float* hid = qkvb;     // fp32 ff-hidden reuses R3 (qkv dead after attn)
    float* lns = normed;   // fp32 lns reuses R2 (normed dead after its cast)
    u16*   h1bf = (u16*)qkvb;  // bf16 MLP hidden reuses R3 (hid dead after ffd)

    // bf16 scratch aliased into dead regions by lifetime:
    u16* xbf    = (u16*)normed;                  // G1: x_bf   (4,194,304 u16)
    u16* wqkvT  = (u16*)normed + 4194304;        // G1: qkv_w^T (3,145,728 u16)
    u16* normbf = (u16*)xcf2;                    // G2: normed_bf
    u16* somaT  = (u16*)xcf2 + 4194304;          // G2: soma_w^T (1,048,576)
    u16* lnsbf  = (u16*)branch;                  // G3: lns_bf
    u16* w1T    = (u16*)branch + 4194304;        // G3: w1^T (3,145,728)
    u16* w2T    = (u16*)xcf2;                    // G4: w2^T (3,145,728)

    // 0. casts for qkv GEMM
    hipLaunchKernelGGL(cast_bf16_k, dim3(2048), dim3(256), 0, stream, x, xbf, 524288);
    hipLaunchKernelGGL(transpose_cast_k, dim3(96, 32), dim3(256), 0, stream,
                       qkv_w, wqkvT, 1024, 3072);
    // 1. qkv = x @ qkv_w  (bf16 MFMA, fp32 out)
    hipLaunchKernelGGL((gemm_mfma<false, false, false, false>), dim3(24, 32), dim3(256), 0, stream,
                       xbf, wqkvT, nullptr, qkvb, 4096, 3072, 1024);
    // 2. bf16 MFMA flash attention + nmda shift -> branch
    hipLaunchKernelGGL(attn_mfma, dim3(16, NH_, B_), dim3(256), 0, stream,
                       qkvb, nmda, nmda_d, branch);
    // 3. xcf2 = branch + tconv(branch)   (re-tiled: 16 ch/block)
    hipLaunchKernelGGL(tconv_kernel, dim3(8, 64, 4), dim3(256), 0, stream,
                       branch, tconv_w, tconv_b, xcf2);
    // 4. hid = gelu(ffu(xcf2))
    hipLaunchKernelGGL(ffu_kernel, dim3(16, NH_, B_), dim3(256), 0, stream,
                       xcf2, ffu_w, ffu_b, hid);
    // 5. normed = GroupNorm(branch + ffd(hid)); nmda update at t=T-1
    hipLaunchKernelGGL(ffd_gn_kernel, dim3(32, NH_, B_), dim3(256), 0, stream,
                       hid, ffd_w, ffd_b, branch, gn_w, gn_b, nmda, nmda_d,
                       normed, out_nmda);
    // 6. soma = normed @ soma_w (bf16 MFMA)
    hipLaunchKernelGGL(cast_bf16_k, dim3(2048), dim3(256), 0, stream, normed, normbf, 524288);
    hipLaunchKernelGGL(transpose_cast_k, dim3(32, 32), dim3(256), 0, stream,
                       soma_w, somaT, 1024, 1024);
    hipLaunchKernelGGL((gemm_mfma<false, false, false, false>), dim3(8, 32), dim3(256), 0, stream,
                       normbf, somaT, nullptr, soma, 4096, 1024, 1024);
    // 7. lns = LayerNorm(soma)
    hipLaunchKernelGGL(ln_kernel, dim3(B_ * T_), dim3(256), 0, stream,
                       soma, ln_w, ln_b, lns);
    // 8. h1 = gelu(lns @ w1 + b1)  (bf16 out)
    hipLaunchKernelGGL(cast_bf16_k, dim3(2048), dim3(256), 0, stream, lns, lnsbf, 524288);
    hipLaunchKernelGGL(transpose_cast_k, dim3(96, 32), dim3(256), 0, stream,
                       w1, w1T, 1024, 3072);
    hipLaunchKernelGGL((gemm_mfma<true, true, false, true>), dim3(24, 32), dim3(256), 0, stream,
                       lnsbf, w1T, b1, h1bf, 4096, 3072, 1024);
    // 9. soma += h1 @ w2 + b2
    hipLaunchKernelGGL(transpose_cast_k, dim3(32, 96), dim3(256), 0, stream,
                       w2, w2T, 3072, 1024);
    hipLaunchKernelGGL((gemm_mfma<true, false, true, false>), dim3(8, 32), dim3(256), 0, stream,
                       h1bf, w2T, b2, soma, 4096, 1024, 3072);
}

// Round 11
// 548.363 us; speedup vs baseline: 6.2435x; 1.0593x over previous
//
#include <hip/hip_runtime.h>
#include <math.h>

#define B_  4
#define T_  1024
#define D_  1024
#define NH_ 16
#define DH_ 64
#define SH_ 3072

typedef unsigned short u16;
typedef __attribute__((ext_vector_type(8))) short bf16x8;
typedef __attribute__((ext_vector_type(4))) float f32x4;
typedef __attribute__((ext_vector_type(4))) unsigned short u16x4;
typedef __attribute__((ext_vector_type(8))) unsigned short u16x8;

__device__ __forceinline__ float gelu_f(float x) {
    return 0.5f * x * (1.0f + erff(x * 0.70710678118654752440f));
}
__device__ __forceinline__ float sigm_f(float x) {
    return 1.0f / (1.0f + __expf(-x));
}
__device__ __forceinline__ u16 f2bf(float f) {
    unsigned u = __builtin_bit_cast(unsigned, f);
    return (u16)((u + 0x7FFFu + ((u >> 16) & 1u)) >> 16);
}

// async global->LDS, 16B per lane; LDS dest must be wave-linear (base+lane*16)
#define GLD16(gsrc, ldst) __builtin_amdgcn_global_load_lds( \
    (__attribute__((address_space(1))) void*)(gsrc),        \
    (__attribute__((address_space(3))) void*)(ldst), 16, 0, 0)

// ---------------------------------------------------------------------------
// fp32 -> bf16 elementwise cast (8 elems/thread)
// ---------------------------------------------------------------------------
__global__ __launch_bounds__(256) void cast_bf16_k(
    const float* __restrict__ in, u16* __restrict__ out, int n8)
{
    int i = blockIdx.x * 256 + threadIdx.x;
    if (i >= n8) return;
    const float4* p = (const float4*)(in + (size_t)i * 8);
    float4 a = p[0], b = p[1];
    u16x8 o;
    o[0] = f2bf(a.x); o[1] = f2bf(a.y); o[2] = f2bf(a.z); o[3] = f2bf(a.w);
    o[4] = f2bf(b.x); o[5] = f2bf(b.y); o[6] = f2bf(b.z); o[7] = f2bf(b.w);
    *(u16x8*)(out + (size_t)i * 8) = o;
}

// ---------------------------------------------------------------------------
// W[K][N] fp32 -> Wt[N][K] bf16 (32x32 LDS tile, 256 threads)
// ---------------------------------------------------------------------------
__global__ __launch_bounds__(256) void transpose_cast_k(
    const float* __restrict__ W, u16* __restrict__ Wt, int K, int N)
{
    __shared__ float t[32][33];
    const int n0 = blockIdx.x * 32, k0 = blockIdx.y * 32;
    const int tid = threadIdx.x;
    {
        int kr = tid >> 3, nc = (tid & 7) * 4;
        float4 v = *(const float4*)(W + (size_t)(k0 + kr) * N + n0 + nc);
        t[kr][nc] = v.x; t[kr][nc + 1] = v.y; t[kr][nc + 2] = v.z; t[kr][nc + 3] = v.w;
    }
    __syncthreads();
    {
        int nr = tid >> 3, kc = (tid & 7) * 4;
        u16x4 o = { f2bf(t[kc][nr]), f2bf(t[kc + 1][nr]),
                    f2bf(t[kc + 2][nr]), f2bf(t[kc + 3][nr]) };
        *(u16x4*)(Wt + (size_t)(n0 + nr) * K + k0 + kc) = o;
    }
}

// ---------------------------------------------------------------------------
// bf16 MFMA GEMM (m97 structure): C[M,N] = act(A[M,K] @ Bt[N,K]^T + bias)
// 128x128 tile, BK=32, 256 thr (4 waves, 2x2), 4x4 16x16x32 frags/wave.
// ---------------------------------------------------------------------------
template<bool BIAS, bool GELU, bool ACCUM, bool BF16OUT>
__global__ __launch_bounds__(256) void gemm_mfma(
    const u16* __restrict__ A, const u16* __restrict__ Bt,
    const float* __restrict__ bias, void* __restrict__ Cv,
    int M, int N, int K)
{
    __shared__ u16 As[4096];   // 128 rows x 32 k (8 KB)
    __shared__ u16 Bs[4096];
    const int tid = threadIdx.x;
    const int m0 = blockIdx.y * 128, n0 = blockIdx.x * 128;
    const int w = tid >> 6, l = tid & 63;
    const int mw = (w >> 1) * 64, nw = (w & 1) * 64;
    const int lr = l & 15, kg = l >> 4;
    const int swz = kg ^ ((lr >> 1) & 3);    // frag k-granule after swizzle

    f32x4 acc[4][4];
#pragma unroll
    for (int i = 0; i < 4; ++i)
#pragma unroll
        for (int j = 0; j < 4; ++j) acc[i][j] = (f32x4){0.f, 0.f, 0.f, 0.f};

    const int mA0 = tid >> 2;
    const int kg0 = (tid & 3) ^ ((mA0 >> 1) & 3);
    const int mA1 = (256 + tid) >> 2;
    const int kg1 = ((256 + tid) & 3) ^ ((mA1 >> 1) & 3);
    const u16* a0 = A + (size_t)(m0 + mA0) * K + kg0 * 8;
    const u16* a1 = A + (size_t)(m0 + mA1) * K + kg1 * 8;
    const u16* b0 = Bt + (size_t)(n0 + mA0) * K + kg0 * 8;
    const u16* b1 = Bt + (size_t)(n0 + mA1) * K + kg1 * 8;
    u16* lA0 = As + tid * 8;  u16* lA1 = As + (256 + tid) * 8;
    u16* lB0 = Bs + tid * 8;  u16* lB1 = Bs + (256 + tid) * 8;

    for (int k0 = 0; k0 < K; k0 += 32) {
        __syncthreads();
        GLD16(a0 + k0, lA0); GLD16(a1 + k0, lA1);
        GLD16(b0 + k0, lB0); GLD16(b1 + k0, lB1);
        __syncthreads();

        bf16x8 aF[4], bF[4];
#pragma unroll
        for (int mt = 0; mt < 4; ++mt) {
            int row = mw + mt * 16 + lr;
            aF[mt] = *(const bf16x8*)&As[(row * 4 + swz) * 8];
            int rowb = nw + mt * 16 + lr;
            bF[mt] = *(const bf16x8*)&Bs[(rowb * 4 + swz) * 8];
        }
#pragma unroll
        for (int mt = 0; mt < 4; ++mt)
#pragma unroll
            for (int nt = 0; nt < 4; ++nt)
                acc[mt][nt] = __builtin_amdgcn_mfma_f32_16x16x32_bf16(
                    aF[mt], bF[nt], acc[mt][nt], 0, 0, 0);
    }

    const int lq = l >> 4;
#pragma unroll
    for (int mt = 0; mt < 4; ++mt) {
#pragma unroll
        for (int nt = 0; nt < 4; ++nt) {
            int row = m0 + mw + mt * 16 + lq * 4;
            int col = n0 + nw + nt * 16 + lr;
            float bsv = BIAS ? bias[col] : 0.f;
#pragma unroll
            for (int j = 0; j < 4; ++j) {
                float v = acc[mt][nt][j] + bsv;
                if (GELU) v = gelu_f(v);
                size_t idx = (size_t)(row + j) * N + col;
                if (BF16OUT) {
                    ((u16*)Cv)[idx] = f2bf(v);
                } else {
                    float* C = (float*)Cv;
                    if (ACCUM) v += C[idx];
                    C[idx] = v;
                }
            }
        }
    }
}

// ---------------------------------------------------------------------------
// bf16 MFMA flash attention v2 — qkv is bf16.
// Block = 64 q-rows of one (b,h), 4 waves x 16 q-rows.
// K staged via GLD16 with PRE-SWIZZLED global source (rule 21): LDS granule
// p holds src granule (p&7)^((p>>3)&7) of row p>>3, so frag reads use slot
// g^(row&7). V staged linearly via GLD16 into Vrow, then transposed to
// Vt[d][kv-swizzled] in LDS: reads 2-way (free, m136), writes structural.
// Scale 0.125 applied to S post-MFMA (exact; bf16(Q*.125)=bf16(Q)*.125).
// ---------------------------------------------------------------------------
__global__ __launch_bounds__(256) void attn_mfma(
    const u16* __restrict__ qkv, const float* __restrict__ nmda,
    const float* __restrict__ nmda_decay, float* __restrict__ branch)
{
    const int qt = 15 - (int)blockIdx.x;   // heavy q-tiles first
    const int h  = blockIdx.y;
    const int b  = blockIdx.z;
    const int tid = threadIdx.x;
    const int w  = tid >> 6, l = tid & 63;
    const int lr = l & 15, kg = l >> 4;
    const int q0 = qt * 64;

    __shared__ u16 Ks[64 * 64];      // [kv][slot=g^(kv&7)]  8 KB
    __shared__ u16 Vrow[64 * 64];    // [kv][d] linear       8 KB
    __shared__ u16 Vt[64 * 64];      // [d][kv swizzled]     8 KB
    __shared__ u16 Ps[4][16 * 64];   // per-wave [q][kv swz] 8 KB

    // Q fragments: direct bf16 loads
    bf16x8 qf[2];
    {
        const u16* qrow = qkv + (size_t)(b * T_ + q0 + w * 16 + lr) * (3 * D_) + h * 64;
        qf[0] = *(const bf16x8*)(qrow + kg * 8);
        qf[1] = *(const bf16x8*)(qrow + 32 + kg * 8);
    }

    float nshift[4];
#pragma unroll
    for (int nt = 0; nt < 4; ++nt) {
        int d = nt * 16 + lr;
        nshift[nt] = nmda[(size_t)(b * NH_ + h) * 64 + d] * sigm_f(nmda_decay[h * 64 + d]);
    }

    f32x4 O[4];
#pragma unroll
    for (int nt = 0; nt < 4; ++nt) O[nt] = (f32x4){0.f, 0.f, 0.f, 0.f};
    float m_run[4] = {-INFINITY, -INFINITY, -INFINITY, -INFINITY};
    float l_run[4] = {0.f, 0.f, 0.f, 0.f};

    // staging source addresses (per-lane; add kv0*3D each iter)
    const int p0 = tid, p1 = 256 + tid;
    const int kr0 = p0 >> 3, ks0 = p0 & 7;
    const int kr1 = p1 >> 3, ks1 = p1 & 7;
    const u16* kbase = qkv + (size_t)(b * T_) * (3 * D_) + D_ + h * 64;
    const u16* vbase = kbase + D_;
    const u16* ksrc0 = kbase + (size_t)kr0 * (3 * D_) + ((ks0 ^ (kr0 & 7)) << 3);
    const u16* ksrc1 = kbase + (size_t)kr1 * (3 * D_) + ((ks1 ^ (kr1 & 7)) << 3);
    const u16* vsrc0 = vbase + (size_t)kr0 * (3 * D_) + (ks0 << 3);
    const u16* vsrc1 = vbase + (size_t)kr1 * (3 * D_) + (ks1 << 3);

    for (int kt = 0; kt <= qt; ++kt) {
        const size_t off = (size_t)(kt * 64) * (3 * D_);
        __syncthreads();   // prior iter done reading Ks/Vrow/Vt
        GLD16(ksrc0 + off, Ks + p0 * 8);
        GLD16(ksrc1 + off, Ks + p1 * 8);
        GLD16(vsrc0 + off, Vrow + p0 * 8);
        GLD16(vsrc1 + off, Vrow + p1 * 8);
        __syncthreads();   // vmcnt drained before barrier (m97 behavior)

        // ---- Vt build: wave w handles granules {w, w+4}, d = lane
        {
            const int d = l;
#pragma unroll
            for (int pp = 0; pp < 2; ++pp) {
                const int gk = w + pp * 4;
                u16x8 col;
#pragma unroll
                for (int j = 0; j < 8; ++j)
                    col[j] = Vrow[(gk * 8 + j) * 64 + d];
                *(u16x8*)&Vt[d * 64 + ((gk ^ (d & 7)) << 3)] = col;
            }
        }

        // ---- S = Q K^T (unscaled; *0.125 after)
        f32x4 s[4];
#pragma unroll
        for (int nt = 0; nt < 4; ++nt) s[nt] = (f32x4){0.f, 0.f, 0.f, 0.f};
#pragma unroll
        for (int ks = 0; ks < 2; ++ks) {
#pragma unroll
            for (int nt = 0; nt < 4; ++nt) {
                int krow = nt * 16 + lr;
                bf16x8 kf = *(const bf16x8*)&Ks[krow * 64 + (((ks * 4 + kg) ^ (krow & 7)) << 3)];
                s[nt] = __builtin_amdgcn_mfma_f32_16x16x32_bf16(qf[ks], kf, s[nt], 0, 0, 0);
            }
        }
#pragma unroll
        for (int nt = 0; nt < 4; ++nt)
#pragma unroll
            for (int j = 0; j < 4; ++j) s[nt][j] *= 0.125f;

        __syncthreads();   // Vt writes visible to all waves before PV

        if (kt == qt) {
#pragma unroll
            for (int nt = 0; nt < 4; ++nt) {
                int kvp = nt * 16 + lr;
#pragma unroll
                for (int j = 0; j < 4; ++j) {
                    int qp = w * 16 + kg * 4 + j;
                    if (kvp > qp) s[nt][j] = -INFINITY;
                }
            }
        }

        // ---- online softmax (row spread over 16 lanes sharing kg)
        float c4[4];
#pragma unroll
        for (int j = 0; j < 4; ++j) {
            float mx = fmaxf(fmaxf(s[0][j], s[1][j]), fmaxf(s[2][j], s[3][j]));
#pragma unroll
            for (int msk = 1; msk < 16; msk <<= 1) mx = fmaxf(mx, __shfl_xor(mx, msk));
            float mn = fmaxf(m_run[j], mx);
            c4[j] = __expf(m_run[j] - mn);
            m_run[j] = mn;
            float ls = 0.f;
#pragma unroll
            for (int nt = 0; nt < 4; ++nt) {
                float p = __expf(s[nt][j] - mn);
                s[nt][j] = p;
                ls += p;
            }
#pragma unroll
            for (int msk = 1; msk < 16; msk <<= 1) ls += __shfl_xor(ls, msk);
            l_run[j] = l_run[j] * c4[j] + ls;
        }

        // ---- P -> per-wave LDS (bf16, swizzled); same-wave RAW, no barrier
#pragma unroll
        for (int nt = 0; nt < 4; ++nt) {
#pragma unroll
            for (int j = 0; j < 4; ++j) {
                int r = kg * 4 + j;
                int c = nt * 16 + lr;
                Ps[w][r * 64 + (((c >> 3) ^ (r & 7)) << 3) + (c & 7)] = f2bf(s[nt][j]);
            }
        }

        // ---- O rescale + PV
#pragma unroll
        for (int nt = 0; nt < 4; ++nt)
#pragma unroll
            for (int j = 0; j < 4; ++j) O[nt][j] *= c4[j];
#pragma unroll
        for (int ks = 0; ks < 2; ++ks) {
            bf16x8 pa = *(const bf16x8*)&Ps[w][lr * 64 + (((ks * 4 + kg) ^ (lr & 7)) << 3)];
#pragma unroll
            for (int nt = 0; nt < 4; ++nt) {
                int vrow = nt * 16 + lr;
                bf16x8 vf = *(const bf16x8*)&Vt[vrow * 64 + (((ks * 4 + kg) ^ (vrow & 7)) << 3)];
                O[nt] = __builtin_amdgcn_mfma_f32_16x16x32_bf16(pa, vf, O[nt], 0, 0, 0);
            }
        }
    }

    // ---- epilogue: normalize + nmda shift, store fp32
#pragma unroll
    for (int j = 0; j < 4; ++j) {
        float inv = 1.f / l_run[j];
        int qrow = q0 + w * 16 + kg * 4 + j;
        float* orow = branch + (size_t)(b * T_ + qrow) * D_ + h * 64;
#pragma unroll
        for (int nt = 0; nt < 4; ++nt)
            orow[nt * 16 + lr] = O[nt][j] * inv + nshift[nt];
    }
}

// ---------------------------------------------------------------------------
// Causal grouped temporal conv (k=5, pad_left=4) + residual + bias.
// 16 output channels/block, 256 threads, float4 staging.
// ---------------------------------------------------------------------------
__global__ __launch_bounds__(256) void tconv_kernel(
    const float* __restrict__ branch, const float* __restrict__ w,
    const float* __restrict__ bias, float* __restrict__ xcf2)
{
    const int tid = threadIdx.x;
    const int t0 = blockIdx.x * 128;
    const int c0 = blockIdx.y * 16;     // global out-channel base (16/block)
    const int b  = blockIdx.z;
    const int g  = c0 >> 6;
    __shared__ __align__(16) float xl[132][68];
    __shared__ __align__(16) float wl[16][5][64];
    __shared__ float bl[16];

    for (int idx = tid; idx < 132 * 16; idx += 256) {
        int tl = idx >> 4, q = (idx & 15) * 4;
        int tg = t0 - 4 + tl;
        float4 v = (tg >= 0)
            ? *(const float4*)&branch[(size_t)(b * T_ + tg) * D_ + g * 64 + q]
            : make_float4(0.f, 0.f, 0.f, 0.f);
        *(float4*)&xl[tl][q] = v;
    }
    for (int idx = tid; idx < 16 * 320; idx += 256) {
        int cc = idx / 320, r = idx - cc * 320;
        int i = r / 5, k = r - i * 5;
        wl[cc][k][i] = w[(size_t)(c0 + cc) * 320 + r];
    }
    if (tid < 16) bl[tid] = bias[c0 + tid];
    __syncthreads();

    const int t  = tid & 127;
    const int h8 = (tid >> 7) * 8;
    const int cl = (c0 & 63) + h8;

    float acc[8];
    {
        float4 s0 = *(const float4*)&xl[t + 4][cl];
        float4 s1 = *(const float4*)&xl[t + 4][cl + 4];
        acc[0] = s0.x + bl[h8 + 0]; acc[1] = s0.y + bl[h8 + 1];
        acc[2] = s0.z + bl[h8 + 2]; acc[3] = s0.w + bl[h8 + 3];
        acc[4] = s1.x + bl[h8 + 4]; acc[5] = s1.y + bl[h8 + 5];
        acc[6] = s1.z + bl[h8 + 6]; acc[7] = s1.w + bl[h8 + 7];
    }
#pragma unroll
    for (int k = 0; k < 5; ++k) {
        const float* xr = &xl[t + k][0];
#pragma unroll 4
        for (int i4 = 0; i4 < 16; ++i4) {
            float4 xv = *(const float4*)&xr[i4 * 4];
#pragma unroll
            for (int cc = 0; cc < 8; ++cc) {
                float4 w4 = *(const float4*)&wl[h8 + cc][k][i4 * 4];
                acc[cc] += xv.x * w4.x + xv.y * w4.y + xv.z * w4.z + xv.w * w4.w;
            }
        }
    }
    float* op = &xcf2[(size_t)(b * T_ + t0 + t) * D_ + c0 + h8];
    *(float4*)op       = make_float4(acc[0], acc[1], acc[2], acc[3]);
    *(float4*)(op + 4) = make_float4(acc[4], acc[5], acc[6], acc[7]);
}

// ---------------------------------------------------------------------------
// Grouped 1x1 up-proj (64 -> 128 per group) + bias + exact GELU.
// ---------------------------------------------------------------------------
__global__ __launch_bounds__(256) void ffu_kernel(
    const float* __restrict__ xcf2, const float* __restrict__ w,
    const float* __restrict__ bias, float* __restrict__ hid)
{
    const int tid = threadIdx.x;
    const int t0 = blockIdx.x * 64, g = blockIdx.y, b = blockIdx.z;
    __shared__ __align__(16) float al[64][68];
    __shared__ __align__(16) float wlds[64][132];

    for (int idx = tid; idx < 64 * 64; idx += 256) {
        int i = idx & 63, tl = idx >> 6;
        al[i][tl] = xcf2[(size_t)(b * T_ + t0 + tl) * D_ + g * 64 + i];
    }
    for (int idx = tid; idx < 128 * 64; idx += 256) {
        int i = idx & 63, o = idx >> 6;
        wlds[i][o] = w[(size_t)(g * 128 + o) * 64 + i];
    }
    __syncthreads();

    const int ot = (tid & 15) * 8;
    const int tt = (tid >> 4) * 4;
    float acc[4][8];
#pragma unroll
    for (int i = 0; i < 4; ++i)
#pragma unroll
        for (int j = 0; j < 8; ++j) acc[i][j] = 0.f;

#pragma unroll 8
    for (int i = 0; i < 64; ++i) {
        float4 a4 = *(const float4*)&al[i][tt];
        float4 w0 = *(const float4*)&wlds[i][ot];
        float4 w1 = *(const float4*)&wlds[i][ot + 4];
        float av[4] = {a4.x, a4.y, a4.z, a4.w};
        float wv[8] = {w0.x, w0.y, w0.z, w0.w, w1.x, w1.y, w1.z, w1.w};
#pragma unroll
        for (int ti = 0; ti < 4; ++ti)
#pragma unroll
            for (int oi = 0; oi < 8; ++oi)
                acc[ti][oi] = fmaf(av[ti], wv[oi], acc[ti][oi]);
    }

    float4 bb0 = *(const float4*)&bias[g * 128 + ot];
    float4 bb1 = *(const float4*)&bias[g * 128 + ot + 4];
    float bv[8] = {bb0.x, bb0.y, bb0.z, bb0.w, bb1.x, bb1.y, bb1.z, bb1.w};
#pragma unroll
    for (int ti = 0; ti < 4; ++ti) {
        float o_[8];
#pragma unroll
        for (int oi = 0; oi < 8; ++oi) o_[oi] = gelu_f(acc[ti][oi] + bv[oi]);
        float* hp = hid + (size_t)(b * T_ + t0 + tt + ti) * (2 * D_) + g * 128 + ot;
        *(float4*)hp       = make_float4(o_[0], o_[1], o_[2], o_[3]);
        *(float4*)(hp + 4) = make_float4(o_[4], o_[5], o_[6], o_[7]);
    }
}

// ---------------------------------------------------------------------------
// Grouped 1x1 down-proj (128 -> 64) + bias + residual + per-head GroupNorm
// + nmda update at t=T-1. Writes bf16 `normed` directly (GEMM6 input).
// ---------------------------------------------------------------------------
__global__ __launch_bounds__(256) void ffd_gn_kernel(
    const float* __restrict__ hid, const float* __restrict__ w,
    const float* __restrict__ bias, const float* __restrict__ branch,
    const float* __restrict__ gn_w, const float* __restrict__ gn_b,
    const float* __restrict__ nmda, const float* __restrict__ nmda_decay,
    u16* __restrict__ normed, float* __restrict__ out_nmda)
{
    const int tid = threadIdx.x;
    const int t0 = blockIdx.x * 32, g = blockIdx.y, b = blockIdx.z;
    __shared__ __align__(16) float al[128][36];
    __shared__ __align__(16) float wl[128][68];

    for (int idx = tid; idx < 128 * 32; idx += 256) {
        int j = idx & 127, tl = idx >> 7;
        al[j][tl] = hid[(size_t)(b * T_ + t0 + tl) * (2 * D_) + g * 128 + j];
    }
    for (int idx = tid; idx < 64 * 128; idx += 256) {
        int j = idx & 127, c = idx >> 7;
        wl[j][c] = w[(size_t)(g * 64 + c) * 128 + j];
    }
    __syncthreads();

    const int c0 = (tid & 15) * 4;
    const int tt = (tid >> 4) * 2;
    float acc[2][4];
#pragma unroll
    for (int i = 0; i < 2; ++i)
#pragma unroll
        for (int j = 0; j < 4; ++j) acc[i][j] = 0.f;

#pragma unroll 8
    for (int j = 0; j < 128; ++j) {
        float2 a2 = *(const float2*)&al[j][tt];
        float4 w4 = *(const float4*)&wl[j][c0];
        acc[0][0] = fmaf(a2.x, w4.x, acc[0][0]);
        acc[0][1] = fmaf(a2.x, w4.y, acc[0][1]);
        acc[0][2] = fmaf(a2.x, w4.z, acc[0][2]);
        acc[0][3] = fmaf(a2.x, w4.w, acc[0][3]);
        acc[1][0] = fmaf(a2.y, w4.x, acc[1][0]);
        acc[1][1] = fmaf(a2.y, w4.y, acc[1][1]);
        acc[1][2] = fmaf(a2.y, w4.z, acc[1][2]);
        acc[1][3] = fmaf(a2.y, w4.w, acc[1][3]);
    }

    float4 bb = *(const float4*)&bias[g * 64 + c0];
    float4 gw = *(const float4*)&gn_w[g * 64 + c0];
    float4 gb = *(const float4*)&gn_b[g * 64 + c0];

#pragma unroll
    for (int tq = 0; tq < 2; ++tq) {
        const int tg = t0 + tt + tq;
        float4 br = *(const float4*)&branch[(size_t)(b * T_ + tg) * D_ + g * 64 + c0];
        float r0 = br.x + acc[tq][0] + bb.x;
        float r1 = br.y + acc[tq][1] + bb.y;
        float r2 = br.z + acc[tq][2] + bb.z;
        float r3 = br.w + acc[tq][3] + bb.w;
        float sm = r0 + r1 + r2 + r3;
#pragma unroll
        for (int m = 1; m < 16; m <<= 1) sm += __shfl_xor(sm, m);
        float mu = sm * (1.f / 64.f);
        float d0 = r0 - mu, d1 = r1 - mu, d2 = r2 - mu, d3 = r3 - mu;
        float vs = d0 * d0 + d1 * d1 + d2 * d2 + d3 * d3;
#pragma unroll
        for (int m = 1; m < 16; m <<= 1) vs += __shfl_xor(vs, m);
        float is = rsqrtf(vs * (1.f / 64.f) + 1e-5f);
        float n0 = d0 * is * gw.x + gb.x;
        float n1 = d1 * is * gw.y + gb.y;
        float n2 = d2 * is * gw.z + gb.z;
        float n3 = d3 * is * gw.w + gb.w;
        u16x4 o = { f2bf(n0), f2bf(n1), f2bf(n2), f2bf(n3) };
        *(u16x4*)&normed[(size_t)(b * T_ + tg) * D_ + g * 64 + c0] = o;
        if (tg == T_ - 1) {
            float nv[4] = {n0, n1, n2, n3};
#pragma unroll
            for (int cc = 0; cc < 4; ++cc) {
                int dloc = c0 + cc;
                int ni = (b * NH_ + g) * 64 + dloc;
                float t2 = sigm_f(nmda_decay[g * 64 + dloc]);
                out_nmda[ni] = t2 * nmda[ni] + (1.f - t2) * nv[cc];
            }
        }
    }
}

// ---------------------------------------------------------------------------
// LayerNorm over D=1024 per row; writes bf16 directly (GEMM8 input).
// ---------------------------------------------------------------------------
__global__ __launch_bounds__(256) void ln_kernel(
    const float* __restrict__ x, const float* __restrict__ w,
    const float* __restrict__ bo, u16* __restrict__ y)
{
    __shared__ float red[8];
    const int row = blockIdx.x, tid = threadIdx.x;
    const float* xr = x + (size_t)row * D_;
    float4 v = *(const float4*)&xr[tid * 4];
    float s = v.x + v.y + v.z + v.w;
#pragma unroll
    for (int m = 32; m; m >>= 1) s += __shfl_xor(s, m);
    if ((tid & 63) == 0) red[tid >> 6] = s;
    __syncthreads();
    float mu = (red[0] + red[1] + red[2] + red[3]) * (1.f / 1024.f);
    float dx = v.x - mu, dy = v.y - mu, dz = v.z - mu, dw = v.w - mu;
    float q = dx * dx + dy * dy + dz * dz + dw * dw;
#pragma unroll
    for (int m = 32; m; m >>= 1) q += __shfl_xor(q, m);
    if ((tid & 63) == 0) red[4 + (tid >> 6)] = q;
    __syncthreads();
    float var = (red[4] + red[5] + red[6] + red[7]) * (1.f / 1024.f);
    float is = rsqrtf(var + 1e-5f);
    float4 wv = *(const float4*)&w[tid * 4];
    float4 bv = *(const float4*)&bo[tid * 4];
    u16x4 o = { f2bf(dx * is * wv.x + bv.x), f2bf(dy * is * wv.y + bv.y),
                f2bf(dz * is * wv.z + bv.z), f2bf(dw * is * wv.w + bv.w) };
    *(u16x4*)&y[(size_t)row * D_ + tid * 4] = o;
}

// ---------------------------------------------------------------------------
extern "C" void kernel_launch(void* const* d_in, const int* in_sizes, int n_in,
                              void* d_out, int out_size, void* d_ws, size_t ws_size,
                              hipStream_t stream)
{
    const float* x       = (const float*)d_in[0];
    const float* nmda    = (const float*)d_in[1];
    const float* qkv_w   = (const float*)d_in[2];
    const float* nmda_d  = (const float*)d_in[3];
    const float* tconv_w = (const float*)d_in[4];
    const float* tconv_b = (const float*)d_in[5];
    const float* ffu_w   = (const float*)d_in[6];
    const float* ffu_b   = (const float*)d_in[7];
    const float* ffd_w   = (const float*)d_in[8];
    const float* ffd_b   = (const float*)d_in[9];
    const float* gn_w    = (const float*)d_in[10];
    const float* gn_b    = (const float*)d_in[11];
    const float* soma_w  = (const float*)d_in[12];
    const float* ln_w    = (const float*)d_in[13];
    const float* ln_b    = (const float*)d_in[14];
    const float* w1      = (const float*)d_in[15];
    const float* b1      = (const float*)d_in[16];
    const float* w2      = (const float*)d_in[17];
    const float* b2      = (const float*)d_in[18];
    (void)in_sizes; (void)n_in; (void)out_size; (void)ws_size;

    float* outp     = (float*)d_out;
    float* soma     = outp;                               // B*T*D
    float* out_nmda = outp + (size_t)B_ * T_ * D_;        // B*NH*DH

    // ws regions (floats) — total 25,165,824 floats
    float* ws     = (float*)d_ws;
    float* branch = ws;                       // R0: 4M floats
    float* xcf2   = ws + (size_t)4194304;     // R1: 4M
    float* normed = ws + (size_t)8388608;     // R2: 4M (aliased below)
    float* qkvb   = ws + (size_t)12582912;    // R3: 12.58M
    u16*   qkvbf = (u16*)qkvb;  // bf16 qkv (12.58M u16 = 25MB), dead after attn
    float* hid   = qkvb;        // fp32 ff-hidden reuses R3
    u16*   h1bf  = (u16*)qkvb;  // bf16 MLP hidden reuses R3 (hid dead after ffd)

    // bf16 scratch aliased into dead regions by lifetime:
    u16* xbf    = (u16*)normed;                  // G1: x_bf
    u16* wqkvT  = (u16*)normed + 4194304;        // G1: qkv_w^T
    u16* normbf = (u16*)xcf2;                    // G2: normed_bf (ffd output)
    u16* somaT  = (u16*)xcf2 + 4194304;          // G2: soma_w^T
    u16* lnsbf  = (u16*)branch;                  // G3: lns_bf (ln output)
    u16* w1T    = (u16*)branch + 4194304;        // G3: w1^T
    u16* w2T    = (u16*)xcf2;                    // G4: w2^T

    // 0. casts for qkv GEMM
    hipLaunchKernelGGL(cast_bf16_k, dim3(2048), dim3(256), 0, stream, x, xbf, 524288);
    hipLaunchKernelGGL(transpose_cast_k, dim3(96, 32), dim3(256), 0, stream,
                       qkv_w, wqkvT, 1024, 3072);
    // 1. qkv = x @ qkv_w  (bf16 MFMA, bf16 out)
    hipLaunchKernelGGL((gemm_mfma<false, false, false, true>), dim3(24, 32), dim3(256), 0, stream,
                       xbf, wqkvT, nullptr, qkvbf, 4096, 3072, 1024);
    // 2. bf16 MFMA flash attention + nmda shift -> branch (fp32)
    hipLaunchKernelGGL(attn_mfma, dim3(16, NH_, B_), dim3(256), 0, stream,
                       qkvbf, nmda, nmda_d, branch);
    // 3. xcf2 = branch + tconv(branch)
    hipLaunchKernelGGL(tconv_kernel, dim3(8, 64, 4), dim3(256), 0, stream,
                       branch, tconv_w, tconv_b, xcf2);
    // 4. hid = gelu(ffu(xcf2))
    hipLaunchKernelGGL(ffu_kernel, dim3(16, NH_, B_), dim3(256), 0, stream,
                       xcf2, ffu_w, ffu_b, hid);
    // 5. normbf = bf16(GroupNorm(branch + ffd(hid))); nmda update at t=T-1
    hipLaunchKernelGGL(ffd_gn_kernel, dim3(32, NH_, B_), dim3(256), 0, stream,
                       hid, ffd_w, ffd_b, branch, gn_w, gn_b, nmda, nmda_d,
                       normbf, out_nmda);
    // 6. soma = normed @ soma_w (bf16 MFMA, fp32 out -> d_out)
    hipLaunchKernelGGL(transpose_cast_k, dim3(32, 32), dim3(256), 0, stream,
                       soma_w, somaT, 1024, 1024);
    hipLaunchKernelGGL((gemm_mfma<false, false, false, false>), dim3(8, 32), dim3(256), 0, stream,
                       normbf, somaT, nullptr, soma, 4096, 1024, 1024);
    // 7. lnsbf = bf16(LayerNorm(soma))
    hipLaunchKernelGGL(ln_kernel, dim3(B_ * T_), dim3(256), 0, stream,
                       soma, ln_w, ln_b, lnsbf);
    // 8. h1 = gelu(lns @ w1 + b1)  (bf16 out)
    hipLaunchKernelGGL(transpose_cast_k, dim3(96, 32), dim3(256), 0, stream,
                       w1, w1T, 1024, 3072);
    hipLaunchKernelGGL((gemm_mfma<true, true, false, true>), dim3(24, 32), dim3(256), 0, stream,
                       lnsbf, w1T, b1, h1bf, 4096, 3072, 1024);
    // 9. soma += h1 @ w2 + b2
    hipLaunchKernelGGL(transpose_cast_k, dim3(32, 96), dim3(256), 0, stream,
                       w2, w2T, 3072, 1024);
    hipLaunchKernelGGL((gemm_mfma<true, false, true, false>), dim3(8, 32), dim3(256), 0, stream,
                       h1bf, w2T, b2, soma, 4096, 1024, 3072);
}

// Round 12
// 489.714 us; speedup vs baseline: 6.9912x; 1.1198x over previous
//
#include <hip/hip_runtime.h>
#include <math.h>

#define B_  4
#define T_  1024
#define D_  1024
#define NH_ 16
#define DH_ 64
#define SH_ 3072

typedef unsigned short u16;
typedef __attribute__((ext_vector_type(8))) short bf16x8;
typedef __attribute__((ext_vector_type(4))) float f32x4;
typedef __attribute__((ext_vector_type(4))) unsigned short u16x4;
typedef __attribute__((ext_vector_type(8))) unsigned short u16x8;

__device__ __forceinline__ float gelu_f(float x) {
    return 0.5f * x * (1.0f + erff(x * 0.70710678118654752440f));
}
__device__ __forceinline__ float sigm_f(float x) {
    return 1.0f / (1.0f + __expf(-x));
}
__device__ __forceinline__ u16 f2bf(float f) {
    unsigned u = __builtin_bit_cast(unsigned, f);
    return (u16)((u + 0x7FFFu + ((u >> 16) & 1u)) >> 16);
}

// async global->LDS, 16B per lane; LDS dest must be wave-linear (base+lane*16)
#define GLD16(gsrc, ldst) __builtin_amdgcn_global_load_lds( \
    (__attribute__((address_space(1))) void*)(gsrc),        \
    (__attribute__((address_space(3))) void*)(ldst), 16, 0, 0)

// ---------------------------------------------------------------------------
// fp32 -> bf16 elementwise cast (8 elems/thread)
// ---------------------------------------------------------------------------
__global__ __launch_bounds__(256) void cast_bf16_k(
    const float* __restrict__ in, u16* __restrict__ out, int n8)
{
    int i = blockIdx.x * 256 + threadIdx.x;
    if (i >= n8) return;
    const float4* p = (const float4*)(in + (size_t)i * 8);
    float4 a = p[0], b = p[1];
    u16x8 o;
    o[0] = f2bf(a.x); o[1] = f2bf(a.y); o[2] = f2bf(a.z); o[3] = f2bf(a.w);
    o[4] = f2bf(b.x); o[5] = f2bf(b.y); o[6] = f2bf(b.z); o[7] = f2bf(b.w);
    *(u16x8*)(out + (size_t)i * 8) = o;
}

// ---------------------------------------------------------------------------
// W[K][N] fp32 -> Wt[N][K] bf16 (32x32 LDS tile, 256 threads)
// ---------------------------------------------------------------------------
__global__ __launch_bounds__(256) void transpose_cast_k(
    const float* __restrict__ W, u16* __restrict__ Wt, int K, int N)
{
    __shared__ float t[32][33];
    const int n0 = blockIdx.x * 32, k0 = blockIdx.y * 32;
    const int tid = threadIdx.x;
    {
        int kr = tid >> 3, nc = (tid & 7) * 4;
        float4 v = *(const float4*)(W + (size_t)(k0 + kr) * N + n0 + nc);
        t[kr][nc] = v.x; t[kr][nc + 1] = v.y; t[kr][nc + 2] = v.z; t[kr][nc + 3] = v.w;
    }
    __syncthreads();
    {
        int nr = tid >> 3, kc = (tid & 7) * 4;
        u16x4 o = { f2bf(t[kc][nr]), f2bf(t[kc + 1][nr]),
                    f2bf(t[kc + 2][nr]), f2bf(t[kc + 3][nr]) };
        *(u16x4*)(Wt + (size_t)(n0 + nr) * K + k0 + kc) = o;
    }
}

// ---------------------------------------------------------------------------
// tconv weight prep: Wtp[c][k5*64+i] = bf16(w[c][i][k5])  (c=0..1023)
// ---------------------------------------------------------------------------
__global__ __launch_bounds__(256) void tconv_wprep(
    const float* __restrict__ w, u16* __restrict__ Wtp)
{
    int idx = blockIdx.x * 256 + threadIdx.x;   // 0 .. 327679
    int c = idx / 320, r = idx - c * 320;
    int k5 = r >> 6, i = r & 63;
    Wtp[idx] = f2bf(w[c * 320 + i * 5 + k5]);
}

// ---------------------------------------------------------------------------
// bf16 MFMA GEMM (m97 structure): C[M,N] = act(A[M,K] @ Bt[N,K]^T + bias)
// 128x128 tile, BK=32, 256 thr (4 waves, 2x2), 4x4 16x16x32 frags/wave.
// ---------------------------------------------------------------------------
template<bool BIAS, bool GELU, bool ACCUM, bool BF16OUT>
__global__ __launch_bounds__(256) void gemm_mfma(
    const u16* __restrict__ A, const u16* __restrict__ Bt,
    const float* __restrict__ bias, void* __restrict__ Cv,
    int M, int N, int K)
{
    __shared__ u16 As[4096];   // 128 rows x 32 k (8 KB)
    __shared__ u16 Bs[4096];
    const int tid = threadIdx.x;
    const int m0 = blockIdx.y * 128, n0 = blockIdx.x * 128;
    const int w = tid >> 6, l = tid & 63;
    const int mw = (w >> 1) * 64, nw = (w & 1) * 64;
    const int lr = l & 15, kg = l >> 4;
    const int swz = kg ^ ((lr >> 1) & 3);    // frag k-granule after swizzle

    f32x4 acc[4][4];
#pragma unroll
    for (int i = 0; i < 4; ++i)
#pragma unroll
        for (int j = 0; j < 4; ++j) acc[i][j] = (f32x4){0.f, 0.f, 0.f, 0.f};

    const int mA0 = tid >> 2;
    const int kg0 = (tid & 3) ^ ((mA0 >> 1) & 3);
    const int mA1 = (256 + tid) >> 2;
    const int kg1 = ((256 + tid) & 3) ^ ((mA1 >> 1) & 3);
    const u16* a0 = A + (size_t)(m0 + mA0) * K + kg0 * 8;
    const u16* a1 = A + (size_t)(m0 + mA1) * K + kg1 * 8;
    const u16* b0 = Bt + (size_t)(n0 + mA0) * K + kg0 * 8;
    const u16* b1 = Bt + (size_t)(n0 + mA1) * K + kg1 * 8;
    u16* lA0 = As + tid * 8;  u16* lA1 = As + (256 + tid) * 8;
    u16* lB0 = Bs + tid * 8;  u16* lB1 = Bs + (256 + tid) * 8;

    for (int k0 = 0; k0 < K; k0 += 32) {
        __syncthreads();
        GLD16(a0 + k0, lA0); GLD16(a1 + k0, lA1);
        GLD16(b0 + k0, lB0); GLD16(b1 + k0, lB1);
        __syncthreads();

        bf16x8 aF[4], bF[4];
#pragma unroll
        for (int mt = 0; mt < 4; ++mt) {
            int row = mw + mt * 16 + lr;
            aF[mt] = *(const bf16x8*)&As[(row * 4 + swz) * 8];
            int rowb = nw + mt * 16 + lr;
            bF[mt] = *(const bf16x8*)&Bs[(rowb * 4 + swz) * 8];
        }
#pragma unroll
        for (int mt = 0; mt < 4; ++mt)
#pragma unroll
            for (int nt = 0; nt < 4; ++nt)
                acc[mt][nt] = __builtin_amdgcn_mfma_f32_16x16x32_bf16(
                    aF[mt], bF[nt], acc[mt][nt], 0, 0, 0);
    }

    const int lq = l >> 4;
#pragma unroll
    for (int mt = 0; mt < 4; ++mt) {
#pragma unroll
        for (int nt = 0; nt < 4; ++nt) {
            int row = m0 + mw + mt * 16 + lq * 4;
            int col = n0 + nw + nt * 16 + lr;
            float bsv = BIAS ? bias[col] : 0.f;
#pragma unroll
            for (int j = 0; j < 4; ++j) {
                float v = acc[mt][nt][j] + bsv;
                if (GELU) v = gelu_f(v);
                size_t idx = (size_t)(row + j) * N + col;
                if (BF16OUT) {
                    ((u16*)Cv)[idx] = f2bf(v);
                } else {
                    float* C = (float*)Cv;
                    if (ACCUM) v += C[idx];
                    C[idx] = v;
                }
            }
        }
    }
}

// ---------------------------------------------------------------------------
// bf16 MFMA flash attention v2 (unchanged, verified round 11).
// ---------------------------------------------------------------------------
__global__ __launch_bounds__(256) void attn_mfma(
    const u16* __restrict__ qkv, const float* __restrict__ nmda,
    const float* __restrict__ nmda_decay, float* __restrict__ branch)
{
    const int qt = 15 - (int)blockIdx.x;   // heavy q-tiles first
    const int h  = blockIdx.y;
    const int b  = blockIdx.z;
    const int tid = threadIdx.x;
    const int w  = tid >> 6, l = tid & 63;
    const int lr = l & 15, kg = l >> 4;
    const int q0 = qt * 64;

    __shared__ u16 Ks[64 * 64];      // [kv][slot=g^(kv&7)]  8 KB
    __shared__ u16 Vrow[64 * 64];    // [kv][d] linear       8 KB
    __shared__ u16 Vt[64 * 64];      // [d][kv swizzled]     8 KB
    __shared__ u16 Ps[4][16 * 64];   // per-wave [q][kv swz] 8 KB

    bf16x8 qf[2];
    {
        const u16* qrow = qkv + (size_t)(b * T_ + q0 + w * 16 + lr) * (3 * D_) + h * 64;
        qf[0] = *(const bf16x8*)(qrow + kg * 8);
        qf[1] = *(const bf16x8*)(qrow + 32 + kg * 8);
    }

    float nshift[4];
#pragma unroll
    for (int nt = 0; nt < 4; ++nt) {
        int d = nt * 16 + lr;
        nshift[nt] = nmda[(size_t)(b * NH_ + h) * 64 + d] * sigm_f(nmda_decay[h * 64 + d]);
    }

    f32x4 O[4];
#pragma unroll
    for (int nt = 0; nt < 4; ++nt) O[nt] = (f32x4){0.f, 0.f, 0.f, 0.f};
    float m_run[4] = {-INFINITY, -INFINITY, -INFINITY, -INFINITY};
    float l_run[4] = {0.f, 0.f, 0.f, 0.f};

    const int p0 = tid, p1 = 256 + tid;
    const int kr0 = p0 >> 3, ks0 = p0 & 7;
    const int kr1 = p1 >> 3, ks1 = p1 & 7;
    const u16* kbase = qkv + (size_t)(b * T_) * (3 * D_) + D_ + h * 64;
    const u16* vbase = kbase + D_;
    const u16* ksrc0 = kbase + (size_t)kr0 * (3 * D_) + ((ks0 ^ (kr0 & 7)) << 3);
    const u16* ksrc1 = kbase + (size_t)kr1 * (3 * D_) + ((ks1 ^ (kr1 & 7)) << 3);
    const u16* vsrc0 = vbase + (size_t)kr0 * (3 * D_) + (ks0 << 3);
    const u16* vsrc1 = vbase + (size_t)kr1 * (3 * D_) + (ks1 << 3);

    for (int kt = 0; kt <= qt; ++kt) {
        const size_t off = (size_t)(kt * 64) * (3 * D_);
        __syncthreads();
        GLD16(ksrc0 + off, Ks + p0 * 8);
        GLD16(ksrc1 + off, Ks + p1 * 8);
        GLD16(vsrc0 + off, Vrow + p0 * 8);
        GLD16(vsrc1 + off, Vrow + p1 * 8);
        __syncthreads();

        {
            const int d = l;
#pragma unroll
            for (int pp = 0; pp < 2; ++pp) {
                const int gk = w + pp * 4;
                u16x8 col;
#pragma unroll
                for (int j = 0; j < 8; ++j)
                    col[j] = Vrow[(gk * 8 + j) * 64 + d];
                *(u16x8*)&Vt[d * 64 + ((gk ^ (d & 7)) << 3)] = col;
            }
        }

        f32x4 s[4];
#pragma unroll
        for (int nt = 0; nt < 4; ++nt) s[nt] = (f32x4){0.f, 0.f, 0.f, 0.f};
#pragma unroll
        for (int ks = 0; ks < 2; ++ks) {
#pragma unroll
            for (int nt = 0; nt < 4; ++nt) {
                int krow = nt * 16 + lr;
                bf16x8 kf = *(const bf16x8*)&Ks[krow * 64 + (((ks * 4 + kg) ^ (krow & 7)) << 3)];
                s[nt] = __builtin_amdgcn_mfma_f32_16x16x32_bf16(qf[ks], kf, s[nt], 0, 0, 0);
            }
        }
#pragma unroll
        for (int nt = 0; nt < 4; ++nt)
#pragma unroll
            for (int j = 0; j < 4; ++j) s[nt][j] *= 0.125f;

        __syncthreads();

        if (kt == qt) {
#pragma unroll
            for (int nt = 0; nt < 4; ++nt) {
                int kvp = nt * 16 + lr;
#pragma unroll
                for (int j = 0; j < 4; ++j) {
                    int qp = w * 16 + kg * 4 + j;
                    if (kvp > qp) s[nt][j] = -INFINITY;
                }
            }
        }

        float c4[4];
#pragma unroll
        for (int j = 0; j < 4; ++j) {
            float mx = fmaxf(fmaxf(s[0][j], s[1][j]), fmaxf(s[2][j], s[3][j]));
#pragma unroll
            for (int msk = 1; msk < 16; msk <<= 1) mx = fmaxf(mx, __shfl_xor(mx, msk));
            float mn = fmaxf(m_run[j], mx);
            c4[j] = __expf(m_run[j] - mn);
            m_run[j] = mn;
            float ls = 0.f;
#pragma unroll
            for (int nt = 0; nt < 4; ++nt) {
                float p = __expf(s[nt][j] - mn);
                s[nt][j] = p;
                ls += p;
            }
#pragma unroll
            for (int msk = 1; msk < 16; msk <<= 1) ls += __shfl_xor(ls, msk);
            l_run[j] = l_run[j] * c4[j] + ls;
        }

#pragma unroll
        for (int nt = 0; nt < 4; ++nt) {
#pragma unroll
            for (int j = 0; j < 4; ++j) {
                int r = kg * 4 + j;
                int c = nt * 16 + lr;
                Ps[w][r * 64 + (((c >> 3) ^ (r & 7)) << 3) + (c & 7)] = f2bf(s[nt][j]);
            }
        }

#pragma unroll
        for (int nt = 0; nt < 4; ++nt)
#pragma unroll
            for (int j = 0; j < 4; ++j) O[nt][j] *= c4[j];
#pragma unroll
        for (int ks = 0; ks < 2; ++ks) {
            bf16x8 pa = *(const bf16x8*)&Ps[w][lr * 64 + (((ks * 4 + kg) ^ (lr & 7)) << 3)];
#pragma unroll
            for (int nt = 0; nt < 4; ++nt) {
                int vrow = nt * 16 + lr;
                bf16x8 vf = *(const bf16x8*)&Vt[vrow * 64 + (((ks * 4 + kg) ^ (vrow & 7)) << 3)];
                O[nt] = __builtin_amdgcn_mfma_f32_16x16x32_bf16(pa, vf, O[nt], 0, 0, 0);
            }
        }
    }

#pragma unroll
    for (int j = 0; j < 4; ++j) {
        float inv = 1.f / l_run[j];
        int qrow = q0 + w * 16 + kg * 4 + j;
        float* orow = branch + (size_t)(b * T_ + qrow) * D_ + h * 64;
#pragma unroll
        for (int nt = 0; nt < 4; ++nt)
            orow[nt * 16 + lr] = O[nt][j] * inv + nshift[nt];
    }
}

// ---------------------------------------------------------------------------
// MFMA tconv: per (b,g) out[1024][64] = X5[1024][320] @ Wtp_g[320][64]^T
// where X5[t][k5*64+i] = branch[t-4+k5][g*64+i] (no materialization: A-frag
// at k-granule kgr is a shifted-row read, row m + (kgr>>3)).
// Block = (t-tile 128, g, b), 4 waves: wave (w>>1) M-half, (w&1) N-half(32).
// x-tile fp32->bf16 staged once, granule-XOR-swizzled -> A reads 2-way free.
// Weights via GLD16 per K-step with gemm_mfma's involution.
// Epilogue: + bias + fp32 branch residual -> fp32 xcf2.
// ---------------------------------------------------------------------------
__global__ __launch_bounds__(256) void tconv_mfma(
    const float* __restrict__ branch, const u16* __restrict__ Wtp,
    const float* __restrict__ bias, float* __restrict__ xcf2)
{
    const int tid = threadIdx.x;
    const int t0 = blockIdx.x * 128;
    const int g  = blockIdx.y;
    const int b  = blockIdx.z;
    const int w = tid >> 6, l = tid & 63;
    const int lr = l & 15, kg = l >> 4;
    const int mw = (w >> 1) * 64;     // M offset 0/64
    const int nw = (w & 1) * 32;      // N offset 0/32

    __shared__ u16 xbf[132 * 64];     // [row][slot], slot = gr^(row&7)
    __shared__ u16 Bs[64 * 32];       // [c][slot], gemm involution

    // ---- stage x tile (fp32 -> bf16, swizzled)
    for (int idx = tid; idx < 132 * 8; idx += 256) {
        int row = idx >> 3, gr = idx & 7;
        int tg = t0 - 4 + row;
        u16x8 v8 = (u16x8){0, 0, 0, 0, 0, 0, 0, 0};
        if (tg >= 0) {
            const float* src = &branch[(size_t)(b * T_ + tg) * D_ + g * 64 + gr * 8];
            float4 f0 = *(const float4*)src;
            float4 f1 = *(const float4*)(src + 4);
            v8[0] = f2bf(f0.x); v8[1] = f2bf(f0.y); v8[2] = f2bf(f0.z); v8[3] = f2bf(f0.w);
            v8[4] = f2bf(f1.x); v8[5] = f2bf(f1.y); v8[6] = f2bf(f1.z); v8[7] = f2bf(f1.w);
        }
        *(u16x8*)&xbf[row * 64 + ((gr ^ (row & 7)) << 3)] = v8;
    }

    f32x4 acc[4][2];
#pragma unroll
    for (int i = 0; i < 4; ++i)
#pragma unroll
        for (int j = 0; j < 2; ++j) acc[i][j] = (f32x4){0.f, 0.f, 0.f, 0.f};

    // B staging (reuse gemm_mfma involution; 64 rows x 4 granules = 256 thr)
    const int mB  = tid >> 2;
    const int kgb = (tid & 3) ^ ((mB >> 1) & 3);
    const u16* bsrc = Wtp + (size_t)(g * 64 + mB) * 320 + kgb * 8;
    u16* lB = Bs + tid * 8;
    const int swzB = kg ^ ((lr >> 1) & 3);

    for (int k0 = 0; k0 < 320; k0 += 32) {
        __syncthreads();                 // prior iter done reading Bs (+xbf ready)
        GLD16(bsrc + k0, lB);
        __syncthreads();                 // vmcnt drained before barrier

        const int kgr = (k0 >> 3) + kg;  // global k-granule 0..39
        const int k5  = kgr >> 3;        // conv tap 0..4
        const int ig  = kgr & 7;         // in-channel granule

        bf16x8 aF[4];
#pragma unroll
        for (int mt = 0; mt < 4; ++mt) {
            int row = mw + mt * 16 + lr + k5;    // shifted row (X5 trick)
            aF[mt] = *(const bf16x8*)&xbf[row * 64 + ((ig ^ (row & 7)) << 3)];
        }
        bf16x8 bF[2];
#pragma unroll
        for (int nt = 0; nt < 2; ++nt) {
            int rb = nw + nt * 16 + lr;
            bF[nt] = *(const bf16x8*)&Bs[(rb * 4 + swzB) * 8];
        }
#pragma unroll
        for (int mt = 0; mt < 4; ++mt)
#pragma unroll
            for (int nt = 0; nt < 2; ++nt)
                acc[mt][nt] = __builtin_amdgcn_mfma_f32_16x16x32_bf16(
                    aF[mt], bF[nt], acc[mt][nt], 0, 0, 0);
    }

    // ---- epilogue: + bias + fp32 residual -> xcf2
    const int lq = l >> 4;
#pragma unroll
    for (int mt = 0; mt < 4; ++mt) {
#pragma unroll
        for (int nt = 0; nt < 2; ++nt) {
            int trow = t0 + mw + mt * 16 + lq * 4;
            int col  = g * 64 + nw + nt * 16 + lr;
            float bv = bias[col];
#pragma unroll
            for (int j = 0; j < 4; ++j) {
                size_t idx = (size_t)(b * T_ + trow + j) * D_ + col;
                xcf2[idx] = acc[mt][nt][j] + bv + branch[idx];
            }
        }
    }
}

// ---------------------------------------------------------------------------
// Grouped 1x1 up-proj (64 -> 128 per group) + bias + exact GELU.
// ---------------------------------------------------------------------------
__global__ __launch_bounds__(256) void ffu_kernel(
    const float* __restrict__ xcf2, const float* __restrict__ w,
    const float* __restrict__ bias, float* __restrict__ hid)
{
    const int tid = threadIdx.x;
    const int t0 = blockIdx.x * 64, g = blockIdx.y, b = blockIdx.z;
    __shared__ __align__(16) float al[64][68];
    __shared__ __align__(16) float wlds[64][132];

    for (int idx = tid; idx < 64 * 64; idx += 256) {
        int i = idx & 63, tl = idx >> 6;
        al[i][tl] = xcf2[(size_t)(b * T_ + t0 + tl) * D_ + g * 64 + i];
    }
    for (int idx = tid; idx < 128 * 64; idx += 256) {
        int i = idx & 63, o = idx >> 6;
        wlds[i][o] = w[(size_t)(g * 128 + o) * 64 + i];
    }
    __syncthreads();

    const int ot = (tid & 15) * 8;
    const int tt = (tid >> 4) * 4;
    float acc[4][8];
#pragma unroll
    for (int i = 0; i < 4; ++i)
#pragma unroll
        for (int j = 0; j < 8; ++j) acc[i][j] = 0.f;

#pragma unroll 8
    for (int i = 0; i < 64; ++i) {
        float4 a4 = *(const float4*)&al[i][tt];
        float4 w0 = *(const float4*)&wlds[i][ot];
        float4 w1 = *(const float4*)&wlds[i][ot + 4];
        float av[4] = {a4.x, a4.y, a4.z, a4.w};
        float wv[8] = {w0.x, w0.y, w0.z, w0.w, w1.x, w1.y, w1.z, w1.w};
#pragma unroll
        for (int ti = 0; ti < 4; ++ti)
#pragma unroll
            for (int oi = 0; oi < 8; ++oi)
                acc[ti][oi] = fmaf(av[ti], wv[oi], acc[ti][oi]);
    }

    float4 bb0 = *(const float4*)&bias[g * 128 + ot];
    float4 bb1 = *(const float4*)&bias[g * 128 + ot + 4];
    float bv[8] = {bb0.x, bb0.y, bb0.z, bb0.w, bb1.x, bb1.y, bb1.z, bb1.w};
#pragma unroll
    for (int ti = 0; ti < 4; ++ti) {
        float o_[8];
#pragma unroll
        for (int oi = 0; oi < 8; ++oi) o_[oi] = gelu_f(acc[ti][oi] + bv[oi]);
        float* hp = hid + (size_t)(b * T_ + t0 + tt + ti) * (2 * D_) + g * 128 + ot;
        *(float4*)hp       = make_float4(o_[0], o_[1], o_[2], o_[3]);
        *(float4*)(hp + 4) = make_float4(o_[4], o_[5], o_[6], o_[7]);
    }
}

// ---------------------------------------------------------------------------
// Grouped 1x1 down-proj (128 -> 64) + bias + residual + per-head GroupNorm
// + nmda update at t=T-1. Writes bf16 `normed` directly (GEMM6 input).
// ---------------------------------------------------------------------------
__global__ __launch_bounds__(256) void ffd_gn_kernel(
    const float* __restrict__ hid, const float* __restrict__ w,
    const float* __restrict__ bias, const float* __restrict__ branch,
    const float* __restrict__ gn_w, const float* __restrict__ gn_b,
    const float* __restrict__ nmda, const float* __restrict__ nmda_decay,
    u16* __restrict__ normed, float* __restrict__ out_nmda)
{
    const int tid = threadIdx.x;
    const int t0 = blockIdx.x * 32, g = blockIdx.y, b = blockIdx.z;
    __shared__ __align__(16) float al[128][36];
    __shared__ __align__(16) float wl[128][68];

    for (int idx = tid; idx < 128 * 32; idx += 256) {
        int j = idx & 127, tl = idx >> 7;
        al[j][tl] = hid[(size_t)(b * T_ + t0 + tl) * (2 * D_) + g * 128 + j];
    }
    for (int idx = tid; idx < 64 * 128; idx += 256) {
        int j = idx & 127, c = idx >> 7;
        wl[j][c] = w[(size_t)(g * 64 + c) * 128 + j];
    }
    __syncthreads();

    const int c0 = (tid & 15) * 4;
    const int tt = (tid >> 4) * 2;
    float acc[2][4];
#pragma unroll
    for (int i = 0; i < 2; ++i)
#pragma unroll
        for (int j = 0; j < 4; ++j) acc[i][j] = 0.f;

#pragma unroll 8
    for (int j = 0; j < 128; ++j) {
        float2 a2 = *(const float2*)&al[j][tt];
        float4 w4 = *(const float4*)&wl[j][c0];
        acc[0][0] = fmaf(a2.x, w4.x, acc[0][0]);
        acc[0][1] = fmaf(a2.x, w4.y, acc[0][1]);
        acc[0][2] = fmaf(a2.x, w4.z, acc[0][2]);
        acc[0][3] = fmaf(a2.x, w4.w, acc[0][3]);
        acc[1][0] = fmaf(a2.y, w4.x, acc[1][0]);
        acc[1][1] = fmaf(a2.y, w4.y, acc[1][1]);
        acc[1][2] = fmaf(a2.y, w4.z, acc[1][2]);
        acc[1][3] = fmaf(a2.y, w4.w, acc[1][3]);
    }

    float4 bb = *(const float4*)&bias[g * 64 + c0];
    float4 gw = *(const float4*)&gn_w[g * 64 + c0];
    float4 gb = *(const float4*)&gn_b[g * 64 + c0];

#pragma unroll
    for (int tq = 0; tq < 2; ++tq) {
        const int tg = t0 + tt + tq;
        float4 br = *(const float4*)&branch[(size_t)(b * T_ + tg) * D_ + g * 64 + c0];
        float r0 = br.x + acc[tq][0] + bb.x;
        float r1 = br.y + acc[tq][1] + bb.y;
        float r2 = br.z + acc[tq][2] + bb.z;
        float r3 = br.w + acc[tq][3] + bb.w;
        float sm = r0 + r1 + r2 + r3;
#pragma unroll
        for (int m = 1; m < 16; m <<= 1) sm += __shfl_xor(sm, m);
        float mu = sm * (1.f / 64.f);
        float d0 = r0 - mu, d1 = r1 - mu, d2 = r2 - mu, d3 = r3 - mu;
        float vs = d0 * d0 + d1 * d1 + d2 * d2 + d3 * d3;
#pragma unroll
        for (int m = 1; m < 16; m <<= 1) vs += __shfl_xor(vs, m);
        float is = rsqrtf(vs * (1.f / 64.f) + 1e-5f);
        float n0 = d0 * is * gw.x + gb.x;
        float n1 = d1 * is * gw.y + gb.y;
        float n2 = d2 * is * gw.z + gb.z;
        float n3 = d3 * is * gw.w + gb.w;
        u16x4 o = { f2bf(n0), f2bf(n1), f2bf(n2), f2bf(n3) };
        *(u16x4*)&normed[(size_t)(b * T_ + tg) * D_ + g * 64 + c0] = o;
        if (tg == T_ - 1) {
            float nv[4] = {n0, n1, n2, n3};
#pragma unroll
            for (int cc = 0; cc < 4; ++cc) {
                int dloc = c0 + cc;
                int ni = (b * NH_ + g) * 64 + dloc;
                float t2 = sigm_f(nmda_decay[g * 64 + dloc]);
                out_nmda[ni] = t2 * nmda[ni] + (1.f - t2) * nv[cc];
            }
        }
    }
}

// ---------------------------------------------------------------------------
// LayerNorm over D=1024 per row; writes bf16 directly (GEMM8 input).
// ---------------------------------------------------------------------------
__global__ __launch_bounds__(256) void ln_kernel(
    const float* __restrict__ x, const float* __restrict__ w,
    const float* __restrict__ bo, u16* __restrict__ y)
{
    __shared__ float red[8];
    const int row = blockIdx.x, tid = threadIdx.x;
    const float* xr = x + (size_t)row * D_;
    float4 v = *(const float4*)&xr[tid * 4];
    float s = v.x + v.y + v.z + v.w;
#pragma unroll
    for (int m = 32; m; m >>= 1) s += __shfl_xor(s, m);
    if ((tid & 63) == 0) red[tid >> 6] = s;
    __syncthreads();
    float mu = (red[0] + red[1] + red[2] + red[3]) * (1.f / 1024.f);
    float dx = v.x - mu, dy = v.y - mu, dz = v.z - mu, dw = v.w - mu;
    float q = dx * dx + dy * dy + dz * dz + dw * dw;
#pragma unroll
    for (int m = 32; m; m >>= 1) q += __shfl_xor(q, m);
    if ((tid & 63) == 0) red[4 + (tid >> 6)] = q;
    __syncthreads();
    float var = (red[4] + red[5] + red[6] + red[7]) * (1.f / 1024.f);
    float is = rsqrtf(var + 1e-5f);
    float4 wv = *(const float4*)&w[tid * 4];
    float4 bv = *(const float4*)&bo[tid * 4];
    u16x4 o = { f2bf(dx * is * wv.x + bv.x), f2bf(dy * is * wv.y + bv.y),
                f2bf(dz * is * wv.z + bv.z), f2bf(dw * is * wv.w + bv.w) };
    *(u16x4*)&y[(size_t)row * D_ + tid * 4] = o;
}

// ---------------------------------------------------------------------------
extern "C" void kernel_launch(void* const* d_in, const int* in_sizes, int n_in,
                              void* d_out, int out_size, void* d_ws, size_t ws_size,
                              hipStream_t stream)
{
    const float* x       = (const float*)d_in[0];
    const float* nmda    = (const float*)d_in[1];
    const float* qkv_w   = (const float*)d_in[2];
    const float* nmda_d  = (const float*)d_in[3];
    const float* tconv_w = (const float*)d_in[4];
    const float* tconv_b = (const float*)d_in[5];
    const float* ffu_w   = (const float*)d_in[6];
    const float* ffu_b   = (const float*)d_in[7];
    const float* ffd_w   = (const float*)d_in[8];
    const float* ffd_b   = (const float*)d_in[9];
    const float* gn_w    = (const float*)d_in[10];
    const float* gn_b    = (const float*)d_in[11];
    const float* soma_w  = (const float*)d_in[12];
    const float* ln_w    = (const float*)d_in[13];
    const float* ln_b    = (const float*)d_in[14];
    const float* w1      = (const float*)d_in[15];
    const float* b1      = (const float*)d_in[16];
    const float* w2      = (const float*)d_in[17];
    const float* b2      = (const float*)d_in[18];
    (void)in_sizes; (void)n_in; (void)out_size; (void)ws_size;

    float* outp     = (float*)d_out;
    float* soma     = outp;                               // B*T*D
    float* out_nmda = outp + (size_t)B_ * T_ * D_;        // B*NH*DH

    // ws regions (floats) — total 25,165,824 floats
    float* ws     = (float*)d_ws;
    float* branch = ws;                       // R0: 4M floats
    float* xcf2   = ws + (size_t)4194304;     // R1: 4M
    float* normed = ws + (size_t)8388608;     // R2: 4M (aliased below)
    float* qkvb   = ws + (size_t)12582912;    // R3: 12.58M
    u16*   qkvbf = (u16*)qkvb;  // bf16 qkv, dead after attn
    float* hid   = qkvb;        // fp32 ff-hidden reuses R3
    u16*   h1bf  = (u16*)qkvb;  // bf16 MLP hidden reuses R3

    // bf16 scratch aliased into dead regions by lifetime:
    u16* xbf    = (u16*)normed;                  // G1: x_bf (0..4.19M u16)
    u16* wqkvT  = (u16*)normed + 4194304;        // G1: qkv_w^T (4.19M..7.34M)
    u16* Wtp    = (u16*)normed + 7340032;        // tconv weights (327,680 u16)
    u16* normbf = (u16*)xcf2;                    // G2: normed_bf (ffd output)
    u16* somaT  = (u16*)xcf2 + 4194304;          // G2: soma_w^T
    u16* lnsbf  = (u16*)branch;                  // G3: lns_bf (ln output)
    u16* w1T    = (u16*)branch + 4194304;        // G3: w1^T
    u16* w2T    = (u16*)xcf2;                    // G4: w2^T

    // 0. weight preps + casts
    hipLaunchKernelGGL(tconv_wprep, dim3(1280), dim3(256), 0, stream, tconv_w, Wtp);
    hipLaunchKernelGGL(cast_bf16_k, dim3(2048), dim3(256), 0, stream, x, xbf, 524288);
    hipLaunchKernelGGL(transpose_cast_k, dim3(96, 32), dim3(256), 0, stream,
                       qkv_w, wqkvT, 1024, 3072);
    // 1. qkv = x @ qkv_w  (bf16 MFMA, bf16 out)
    hipLaunchKernelGGL((gemm_mfma<false, false, false, true>), dim3(24, 32), dim3(256), 0, stream,
                       xbf, wqkvT, nullptr, qkvbf, 4096, 3072, 1024);
    // 2. bf16 MFMA flash attention + nmda shift -> branch (fp32)
    hipLaunchKernelGGL(attn_mfma, dim3(16, NH_, B_), dim3(256), 0, stream,
                       qkvbf, nmda, nmda_d, branch);
    // 3. xcf2 = branch + tconv(branch)   (MFMA, X5 shifted-row trick)
    hipLaunchKernelGGL(tconv_mfma, dim3(8, NH_, B_), dim3(256), 0, stream,
                       branch, Wtp, tconv_b, xcf2);
    // 4. hid = gelu(ffu(xcf2))
    hipLaunchKernelGGL(ffu_kernel, dim3(16, NH_, B_), dim3(256), 0, stream,
                       xcf2, ffu_w, ffu_b, hid);
    // 5. normbf = bf16(GroupNorm(branch + ffd(hid))); nmda update at t=T-1
    hipLaunchKernelGGL(ffd_gn_kernel, dim3(32, NH_, B_), dim3(256), 0, stream,
                       hid, ffd_w, ffd_b, branch, gn_w, gn_b, nmda, nmda_d,
                       normbf, out_nmda);
    // 6. soma = normed @ soma_w (bf16 MFMA, fp32 out -> d_out)
    hipLaunchKernelGGL(transpose_cast_k, dim3(32, 32), dim3(256), 0, stream,
                       soma_w, somaT, 1024, 1024);
    hipLaunchKernelGGL((gemm_mfma<false, false, false, false>), dim3(8, 32), dim3(256), 0, stream,
                       normbf, somaT, nullptr, soma, 4096, 1024, 1024);
    // 7. lnsbf = bf16(LayerNorm(soma))
    hipLaunchKernelGGL(ln_kernel, dim3(B_ * T_), dim3(256), 0, stream,
                       soma, ln_w, ln_b, lnsbf);
    // 8. h1 = gelu(lns @ w1 + b1)  (bf16 out)
    hipLaunchKernelGGL(transpose_cast_k, dim3(96, 32), dim3(256), 0, stream,
                       w1, w1T, 1024, 3072);
    hipLaunchKernelGGL((gemm_mfma<true, true, false, true>), dim3(24, 32), dim3(256), 0, stream,
                       lnsbf, w1T, b1, h1bf, 4096, 3072, 1024);
    // 9. soma += h1 @ w2 + b2
    hipLaunchKernelGGL(transpose_cast_k, dim3(32, 96), dim3(256), 0, stream,
                       w2, w2T, 3072, 1024);
    hipLaunchKernelGGL((gemm_mfma<true, false, true, false>), dim3(8, 32), dim3(256), 0, stream,
                       h1bf, w2T, b2, soma, 4096, 1024, 3072);
}

// Round 13
// 441.292 us; speedup vs baseline: 7.7583x; 1.1097x over previous
//
#include <hip/hip_runtime.h>
#include <math.h>

#define B_  4
#define T_  1024
#define D_  1024
#define NH_ 16
#define DH_ 64
#define SH_ 3072

typedef unsigned short u16;
typedef __attribute__((ext_vector_type(8))) short bf16x8;
typedef __attribute__((ext_vector_type(4))) float f32x4;
typedef __attribute__((ext_vector_type(4))) unsigned short u16x4;
typedef __attribute__((ext_vector_type(8))) unsigned short u16x8;

__device__ __forceinline__ float gelu_f(float x) {
    return 0.5f * x * (1.0f + erff(x * 0.70710678118654752440f));
}
__device__ __forceinline__ float sigm_f(float x) {
    return 1.0f / (1.0f + __expf(-x));
}
__device__ __forceinline__ u16 f2bf(float f) {
    unsigned u = __builtin_bit_cast(unsigned, f);
    return (u16)((u + 0x7FFFu + ((u >> 16) & 1u)) >> 16);
}

// async global->LDS, 16B per lane; LDS dest must be wave-linear (base+lane*16)
#define GLD16(gsrc, ldst) __builtin_amdgcn_global_load_lds( \
    (__attribute__((address_space(1))) void*)(gsrc),        \
    (__attribute__((address_space(3))) void*)(ldst), 16, 0, 0)

// ---------------------------------------------------------------------------
// fp32 -> bf16 elementwise cast (8 elems/thread)
// ---------------------------------------------------------------------------
__global__ __launch_bounds__(256) void cast_bf16_k(
    const float* __restrict__ in, u16* __restrict__ out, int n8)
{
    int i = blockIdx.x * 256 + threadIdx.x;
    if (i >= n8) return;
    const float4* p = (const float4*)(in + (size_t)i * 8);
    float4 a = p[0], b = p[1];
    u16x8 o;
    o[0] = f2bf(a.x); o[1] = f2bf(a.y); o[2] = f2bf(a.z); o[3] = f2bf(a.w);
    o[4] = f2bf(b.x); o[5] = f2bf(b.y); o[6] = f2bf(b.z); o[7] = f2bf(b.w);
    *(u16x8*)(out + (size_t)i * 8) = o;
}

// ---------------------------------------------------------------------------
// W[K][N] fp32 -> Wt[N][K] bf16 (32x32 LDS tile, 256 threads)
// ---------------------------------------------------------------------------
__global__ __launch_bounds__(256) void transpose_cast_k(
    const float* __restrict__ W, u16* __restrict__ Wt, int K, int N)
{
    __shared__ float t[32][33];
    const int n0 = blockIdx.x * 32, k0 = blockIdx.y * 32;
    const int tid = threadIdx.x;
    {
        int kr = tid >> 3, nc = (tid & 7) * 4;
        float4 v = *(const float4*)(W + (size_t)(k0 + kr) * N + n0 + nc);
        t[kr][nc] = v.x; t[kr][nc + 1] = v.y; t[kr][nc + 2] = v.z; t[kr][nc + 3] = v.w;
    }
    __syncthreads();
    {
        int nr = tid >> 3, kc = (tid & 7) * 4;
        u16x4 o = { f2bf(t[kc][nr]), f2bf(t[kc + 1][nr]),
                    f2bf(t[kc + 2][nr]), f2bf(t[kc + 3][nr]) };
        *(u16x4*)(Wt + (size_t)(n0 + nr) * K + k0 + kc) = o;
    }
}

// ---------------------------------------------------------------------------
// tconv weight prep: Wtp[c][k5*64+i] = bf16(w[c][i][k5])  (c=0..1023)
// ---------------------------------------------------------------------------
__global__ __launch_bounds__(256) void tconv_wprep(
    const float* __restrict__ w, u16* __restrict__ Wtp)
{
    int idx = blockIdx.x * 256 + threadIdx.x;   // 0 .. 327679
    int c = idx / 320, r = idx - c * 320;
    int k5 = r >> 6, i = r & 63;
    Wtp[idx] = f2bf(w[c * 320 + i * 5 + k5]);
}

// ---------------------------------------------------------------------------
// bf16 MFMA GEMM v2: C[M,N] = act(A[M,K] @ Bt[N,K]^T + bias)
// BM=128, BN=32*NF (128 or 64), BK=64. 256 thr (4 waves, 2x2).
// LDS involution (HW-verified in attn Ks): row r granule slot s holds source
// granule s^(r&7); frag read for granule g uses slot g^(r&7). BK=64 halves
// barrier count vs BK=32 (32 MFMA between barrier pairs at NF=4).
// NF=2 variant -> grid 2x larger for N=1024 GEMMs (2 blocks/CU, m114 overlap).
// ---------------------------------------------------------------------------
template<int NF, bool BIAS, bool GELU, bool ACCUM, bool BF16OUT>
__global__ __launch_bounds__(256) void gemm_mfma(
    const u16* __restrict__ A, const u16* __restrict__ Bt,
    const float* __restrict__ bias, void* __restrict__ Cv,
    int M, int N, int K)
{
    constexpr int BN = 32 * NF;
    __shared__ u16 As[128 * 64];     // 16 KB
    __shared__ u16 Bs[BN * 64];      // 16 or 8 KB
    const int tid = threadIdx.x;
    const int m0 = blockIdx.y * 128, n0 = blockIdx.x * BN;
    const int w = tid >> 6, l = tid & 63;
    const int mw = (w >> 1) * 64, nw = (w & 1) * (NF * 16);
    const int lr = l & 15, kg = l >> 4;

    f32x4 acc[4][NF];
#pragma unroll
    for (int i = 0; i < 4; ++i)
#pragma unroll
        for (int j = 0; j < NF; ++j) acc[i][j] = (f32x4){0.f, 0.f, 0.f, 0.f};

    // staging addresses: granule p -> row p>>3, slot p&7, src granule slot^(row&7)
    const u16* aSrc[4]; u16* lA[4];
#pragma unroll
    for (int i = 0; i < 4; ++i) {
        int p = i * 256 + tid, row = p >> 3, sg = (p & 7) ^ (row & 7);
        aSrc[i] = A + (size_t)(m0 + row) * K + sg * 8;
        lA[i] = As + p * 8;
    }
    const u16* bSrc[NF]; u16* lB[NF];
#pragma unroll
    for (int i = 0; i < NF; ++i) {
        int p = i * 256 + tid, row = p >> 3, sg = (p & 7) ^ (row & 7);
        bSrc[i] = Bt + (size_t)(n0 + row) * K + sg * 8;
        lB[i] = Bs + p * 8;
    }

    for (int k0 = 0; k0 < K; k0 += 64) {
        __syncthreads();
#pragma unroll
        for (int i = 0; i < 4; ++i) GLD16(aSrc[i] + k0, lA[i]);
#pragma unroll
        for (int i = 0; i < NF; ++i) GLD16(bSrc[i] + k0, lB[i]);
        __syncthreads();   // vmcnt drained before barrier (m97 behavior)

#pragma unroll
        for (int ks = 0; ks < 2; ++ks) {
            const int g = ks * 4 + kg;
            bf16x8 aF[4], bF[NF];
#pragma unroll
            for (int mt = 0; mt < 4; ++mt) {
                int row = mw + mt * 16 + lr;
                aF[mt] = *(const bf16x8*)&As[row * 64 + ((g ^ (row & 7)) << 3)];
            }
#pragma unroll
            for (int nt = 0; nt < NF; ++nt) {
                int rb = nw + nt * 16 + lr;
                bF[nt] = *(const bf16x8*)&Bs[rb * 64 + ((g ^ (rb & 7)) << 3)];
            }
#pragma unroll
            for (int mt = 0; mt < 4; ++mt)
#pragma unroll
                for (int nt = 0; nt < NF; ++nt)
                    acc[mt][nt] = __builtin_amdgcn_mfma_f32_16x16x32_bf16(
                        aF[mt], bF[nt], acc[mt][nt], 0, 0, 0);
        }
    }

    // epilogue: lane l reg j -> row=(l>>4)*4+j, col=l&15 (m89/m91 layout)
    const int lq = l >> 4;
#pragma unroll
    for (int mt = 0; mt < 4; ++mt) {
#pragma unroll
        for (int nt = 0; nt < NF; ++nt) {
            int row = m0 + mw + mt * 16 + lq * 4;
            int col = n0 + nw + nt * 16 + lr;
            float bsv = BIAS ? bias[col] : 0.f;
#pragma unroll
            for (int j = 0; j < 4; ++j) {
                float v = acc[mt][nt][j] + bsv;
                if (GELU) v = gelu_f(v);
                size_t idx = (size_t)(row + j) * N + col;
                if (BF16OUT) {
                    ((u16*)Cv)[idx] = f2bf(v);
                } else {
                    float* C = (float*)Cv;
                    if (ACCUM) v += C[idx];
                    C[idx] = v;
                }
            }
        }
    }
}

// ---------------------------------------------------------------------------
// bf16 MFMA flash attention v2 (unchanged, verified round 11).
// ---------------------------------------------------------------------------
__global__ __launch_bounds__(256) void attn_mfma(
    const u16* __restrict__ qkv, const float* __restrict__ nmda,
    const float* __restrict__ nmda_decay, float* __restrict__ branch)
{
    const int qt = 15 - (int)blockIdx.x;   // heavy q-tiles first
    const int h  = blockIdx.y;
    const int b  = blockIdx.z;
    const int tid = threadIdx.x;
    const int w  = tid >> 6, l = tid & 63;
    const int lr = l & 15, kg = l >> 4;
    const int q0 = qt * 64;

    __shared__ u16 Ks[64 * 64];      // [kv][slot=g^(kv&7)]  8 KB
    __shared__ u16 Vrow[64 * 64];    // [kv][d] linear       8 KB
    __shared__ u16 Vt[64 * 64];      // [d][kv swizzled]     8 KB
    __shared__ u16 Ps[4][16 * 64];   // per-wave [q][kv swz] 8 KB

    bf16x8 qf[2];
    {
        const u16* qrow = qkv + (size_t)(b * T_ + q0 + w * 16 + lr) * (3 * D_) + h * 64;
        qf[0] = *(const bf16x8*)(qrow + kg * 8);
        qf[1] = *(const bf16x8*)(qrow + 32 + kg * 8);
    }

    float nshift[4];
#pragma unroll
    for (int nt = 0; nt < 4; ++nt) {
        int d = nt * 16 + lr;
        nshift[nt] = nmda[(size_t)(b * NH_ + h) * 64 + d] * sigm_f(nmda_decay[h * 64 + d]);
    }

    f32x4 O[4];
#pragma unroll
    for (int nt = 0; nt < 4; ++nt) O[nt] = (f32x4){0.f, 0.f, 0.f, 0.f};
    float m_run[4] = {-INFINITY, -INFINITY, -INFINITY, -INFINITY};
    float l_run[4] = {0.f, 0.f, 0.f, 0.f};

    const int p0 = tid, p1 = 256 + tid;
    const int kr0 = p0 >> 3, ks0 = p0 & 7;
    const int kr1 = p1 >> 3, ks1 = p1 & 7;
    const u16* kbase = qkv + (size_t)(b * T_) * (3 * D_) + D_ + h * 64;
    const u16* vbase = kbase + D_;
    const u16* ksrc0 = kbase + (size_t)kr0 * (3 * D_) + ((ks0 ^ (kr0 & 7)) << 3);
    const u16* ksrc1 = kbase + (size_t)kr1 * (3 * D_) + ((ks1 ^ (kr1 & 7)) << 3);
    const u16* vsrc0 = vbase + (size_t)kr0 * (3 * D_) + (ks0 << 3);
    const u16* vsrc1 = vbase + (size_t)kr1 * (3 * D_) + (ks1 << 3);

    for (int kt = 0; kt <= qt; ++kt) {
        const size_t off = (size_t)(kt * 64) * (3 * D_);
        __syncthreads();
        GLD16(ksrc0 + off, Ks + p0 * 8);
        GLD16(ksrc1 + off, Ks + p1 * 8);
        GLD16(vsrc0 + off, Vrow + p0 * 8);
        GLD16(vsrc1 + off, Vrow + p1 * 8);
        __syncthreads();

        {
            const int d = l;
#pragma unroll
            for (int pp = 0; pp < 2; ++pp) {
                const int gk = w + pp * 4;
                u16x8 col;
#pragma unroll
                for (int j = 0; j < 8; ++j)
                    col[j] = Vrow[(gk * 8 + j) * 64 + d];
                *(u16x8*)&Vt[d * 64 + ((gk ^ (d & 7)) << 3)] = col;
            }
        }

        f32x4 s[4];
#pragma unroll
        for (int nt = 0; nt < 4; ++nt) s[nt] = (f32x4){0.f, 0.f, 0.f, 0.f};
#pragma unroll
        for (int ks = 0; ks < 2; ++ks) {
#pragma unroll
            for (int nt = 0; nt < 4; ++nt) {
                int krow = nt * 16 + lr;
                bf16x8 kf = *(const bf16x8*)&Ks[krow * 64 + (((ks * 4 + kg) ^ (krow & 7)) << 3)];
                s[nt] = __builtin_amdgcn_mfma_f32_16x16x32_bf16(qf[ks], kf, s[nt], 0, 0, 0);
            }
        }
#pragma unroll
        for (int nt = 0; nt < 4; ++nt)
#pragma unroll
            for (int j = 0; j < 4; ++j) s[nt][j] *= 0.125f;

        __syncthreads();

        if (kt == qt) {
#pragma unroll
            for (int nt = 0; nt < 4; ++nt) {
                int kvp = nt * 16 + lr;
#pragma unroll
                for (int j = 0; j < 4; ++j) {
                    int qp = w * 16 + kg * 4 + j;
                    if (kvp > qp) s[nt][j] = -INFINITY;
                }
            }
        }

        float c4[4];
#pragma unroll
        for (int j = 0; j < 4; ++j) {
            float mx = fmaxf(fmaxf(s[0][j], s[1][j]), fmaxf(s[2][j], s[3][j]));
#pragma unroll
            for (int msk = 1; msk < 16; msk <<= 1) mx = fmaxf(mx, __shfl_xor(mx, msk));
            float mn = fmaxf(m_run[j], mx);
            c4[j] = __expf(m_run[j] - mn);
            m_run[j] = mn;
            float ls = 0.f;
#pragma unroll
            for (int nt = 0; nt < 4; ++nt) {
                float p = __expf(s[nt][j] - mn);
                s[nt][j] = p;
                ls += p;
            }
#pragma unroll
            for (int msk = 1; msk < 16; msk <<= 1) ls += __shfl_xor(ls, msk);
            l_run[j] = l_run[j] * c4[j] + ls;
        }

#pragma unroll
        for (int nt = 0; nt < 4; ++nt) {
#pragma unroll
            for (int j = 0; j < 4; ++j) {
                int r = kg * 4 + j;
                int c = nt * 16 + lr;
                Ps[w][r * 64 + (((c >> 3) ^ (r & 7)) << 3) + (c & 7)] = f2bf(s[nt][j]);
            }
        }

#pragma unroll
        for (int nt = 0; nt < 4; ++nt)
#pragma unroll
            for (int j = 0; j < 4; ++j) O[nt][j] *= c4[j];
#pragma unroll
        for (int ks = 0; ks < 2; ++ks) {
            bf16x8 pa = *(const bf16x8*)&Ps[w][lr * 64 + (((ks * 4 + kg) ^ (lr & 7)) << 3)];
#pragma unroll
            for (int nt = 0; nt < 4; ++nt) {
                int vrow = nt * 16 + lr;
                bf16x8 vf = *(const bf16x8*)&Vt[vrow * 64 + (((ks * 4 + kg) ^ (vrow & 7)) << 3)];
                O[nt] = __builtin_amdgcn_mfma_f32_16x16x32_bf16(pa, vf, O[nt], 0, 0, 0);
            }
        }
    }

#pragma unroll
    for (int j = 0; j < 4; ++j) {
        float inv = 1.f / l_run[j];
        int qrow = q0 + w * 16 + kg * 4 + j;
        float* orow = branch + (size_t)(b * T_ + qrow) * D_ + h * 64;
#pragma unroll
        for (int nt = 0; nt < 4; ++nt)
            orow[nt * 16 + lr] = O[nt][j] * inv + nshift[nt];
    }
}

// ---------------------------------------------------------------------------
// MFMA tconv (unchanged, verified round 12).
// ---------------------------------------------------------------------------
__global__ __launch_bounds__(256) void tconv_mfma(
    const float* __restrict__ branch, const u16* __restrict__ Wtp,
    const float* __restrict__ bias, float* __restrict__ xcf2)
{
    const int tid = threadIdx.x;
    const int t0 = blockIdx.x * 128;
    const int g  = blockIdx.y;
    const int b  = blockIdx.z;
    const int w = tid >> 6, l = tid & 63;
    const int lr = l & 15, kg = l >> 4;
    const int mw = (w >> 1) * 64;
    const int nw = (w & 1) * 32;

    __shared__ u16 xbf[132 * 64];
    __shared__ u16 Bs[64 * 32];

    for (int idx = tid; idx < 132 * 8; idx += 256) {
        int row = idx >> 3, gr = idx & 7;
        int tg = t0 - 4 + row;
        u16x8 v8 = (u16x8){0, 0, 0, 0, 0, 0, 0, 0};
        if (tg >= 0) {
            const float* src = &branch[(size_t)(b * T_ + tg) * D_ + g * 64 + gr * 8];
            float4 f0 = *(const float4*)src;
            float4 f1 = *(const float4*)(src + 4);
            v8[0] = f2bf(f0.x); v8[1] = f2bf(f0.y); v8[2] = f2bf(f0.z); v8[3] = f2bf(f0.w);
            v8[4] = f2bf(f1.x); v8[5] = f2bf(f1.y); v8[6] = f2bf(f1.z); v8[7] = f2bf(f1.w);
        }
        *(u16x8*)&xbf[row * 64 + ((gr ^ (row & 7)) << 3)] = v8;
    }

    f32x4 acc[4][2];
#pragma unroll
    for (int i = 0; i < 4; ++i)
#pragma unroll
        for (int j = 0; j < 2; ++j) acc[i][j] = (f32x4){0.f, 0.f, 0.f, 0.f};

    const int mB  = tid >> 2;
    const int kgb = (tid & 3) ^ ((mB >> 1) & 3);
    const u16* bsrc = Wtp + (size_t)(g * 64 + mB) * 320 + kgb * 8;
    u16* lB = Bs + tid * 8;
    const int swzB = kg ^ ((lr >> 1) & 3);

    for (int k0 = 0; k0 < 320; k0 += 32) {
        __syncthreads();
        GLD16(bsrc + k0, lB);
        __syncthreads();

        const int kgr = (k0 >> 3) + kg;
        const int k5  = kgr >> 3;
        const int ig  = kgr & 7;

        bf16x8 aF[4];
#pragma unroll
        for (int mt = 0; mt < 4; ++mt) {
            int row = mw + mt * 16 + lr + k5;
            aF[mt] = *(const bf16x8*)&xbf[row * 64 + ((ig ^ (row & 7)) << 3)];
        }
        bf16x8 bF[2];
#pragma unroll
        for (int nt = 0; nt < 2; ++nt) {
            int rb = nw + nt * 16 + lr;
            bF[nt] = *(const bf16x8*)&Bs[(rb * 4 + swzB) * 8];
        }
#pragma unroll
        for (int mt = 0; mt < 4; ++mt)
#pragma unroll
            for (int nt = 0; nt < 2; ++nt)
                acc[mt][nt] = __builtin_amdgcn_mfma_f32_16x16x32_bf16(
                    aF[mt], bF[nt], acc[mt][nt], 0, 0, 0);
    }

    const int lq = l >> 4;
#pragma unroll
    for (int mt = 0; mt < 4; ++mt) {
#pragma unroll
        for (int nt = 0; nt < 2; ++nt) {
            int trow = t0 + mw + mt * 16 + lq * 4;
            int col  = g * 64 + nw + nt * 16 + lr;
            float bv = bias[col];
#pragma unroll
            for (int j = 0; j < 4; ++j) {
                size_t idx = (size_t)(b * T_ + trow + j) * D_ + col;
                xcf2[idx] = acc[mt][nt][j] + bv + branch[idx];
            }
        }
    }
}

// ---------------------------------------------------------------------------
// Grouped 1x1 up-proj (64 -> 128 per group) + bias + exact GELU.
// ---------------------------------------------------------------------------
__global__ __launch_bounds__(256) void ffu_kernel(
    const float* __restrict__ xcf2, const float* __restrict__ w,
    const float* __restrict__ bias, float* __restrict__ hid)
{
    const int tid = threadIdx.x;
    const int t0 = blockIdx.x * 64, g = blockIdx.y, b = blockIdx.z;
    __shared__ __align__(16) float al[64][68];
    __shared__ __align__(16) float wlds[64][132];

    for (int idx = tid; idx < 64 * 64; idx += 256) {
        int i = idx & 63, tl = idx >> 6;
        al[i][tl] = xcf2[(size_t)(b * T_ + t0 + tl) * D_ + g * 64 + i];
    }
    for (int idx = tid; idx < 128 * 64; idx += 256) {
        int i = idx & 63, o = idx >> 6;
        wlds[i][o] = w[(size_t)(g * 128 + o) * 64 + i];
    }
    __syncthreads();

    const int ot = (tid & 15) * 8;
    const int tt = (tid >> 4) * 4;
    float acc[4][8];
#pragma unroll
    for (int i = 0; i < 4; ++i)
#pragma unroll
        for (int j = 0; j < 8; ++j) acc[i][j] = 0.f;

#pragma unroll 8
    for (int i = 0; i < 64; ++i) {
        float4 a4 = *(const float4*)&al[i][tt];
        float4 w0 = *(const float4*)&wlds[i][ot];
        float4 w1 = *(const float4*)&wlds[i][ot + 4];
        float av[4] = {a4.x, a4.y, a4.z, a4.w};
        float wv[8] = {w0.x, w0.y, w0.z, w0.w, w1.x, w1.y, w1.z, w1.w};
#pragma unroll
        for (int ti = 0; ti < 4; ++ti)
#pragma unroll
            for (int oi = 0; oi < 8; ++oi)
                acc[ti][oi] = fmaf(av[ti], wv[oi], acc[ti][oi]);
    }

    float4 bb0 = *(const float4*)&bias[g * 128 + ot];
    float4 bb1 = *(const float4*)&bias[g * 128 + ot + 4];
    float bv[8] = {bb0.x, bb0.y, bb0.z, bb0.w, bb1.x, bb1.y, bb1.z, bb1.w};
#pragma unroll
    for (int ti = 0; ti < 4; ++ti) {
        float o_[8];
#pragma unroll
        for (int oi = 0; oi < 8; ++oi) o_[oi] = gelu_f(acc[ti][oi] + bv[oi]);
        float* hp = hid + (size_t)(b * T_ + t0 + tt + ti) * (2 * D_) + g * 128 + ot;
        *(float4*)hp       = make_float4(o_[0], o_[1], o_[2], o_[3]);
        *(float4*)(hp + 4) = make_float4(o_[4], o_[5], o_[6], o_[7]);
    }
}

// ---------------------------------------------------------------------------
// Grouped 1x1 down-proj (128 -> 64) + bias + residual + per-head GroupNorm
// + nmda update at t=T-1. Writes bf16 `normed` directly (GEMM6 input).
// ---------------------------------------------------------------------------
__global__ __launch_bounds__(256) void ffd_gn_kernel(
    const float* __restrict__ hid, const float* __restrict__ w,
    const float* __restrict__ bias, const float* __restrict__ branch,
    const float* __restrict__ gn_w, const float* __restrict__ gn_b,
    const float* __restrict__ nmda, const float* __restrict__ nmda_decay,
    u16* __restrict__ normed, float* __restrict__ out_nmda)
{
    const int tid = threadIdx.x;
    const int t0 = blockIdx.x * 32, g = blockIdx.y, b = blockIdx.z;
    __shared__ __align__(16) float al[128][36];
    __shared__ __align__(16) float wl[128][68];

    for (int idx = tid; idx < 128 * 32; idx += 256) {
        int j = idx & 127, tl = idx >> 7;
        al[j][tl] = hid[(size_t)(b * T_ + t0 + tl) * (2 * D_) + g * 128 + j];
    }
    for (int idx = tid; idx < 64 * 128; idx += 256) {
        int j = idx & 127, c = idx >> 7;
        wl[j][c] = w[(size_t)(g * 64 + c) * 128 + j];
    }
    __syncthreads();

    const int c0 = (tid & 15) * 4;
    const int tt = (tid >> 4) * 2;
    float acc[2][4];
#pragma unroll
    for (int i = 0; i < 2; ++i)
#pragma unroll
        for (int j = 0; j < 4; ++j) acc[i][j] = 0.f;

#pragma unroll 8
    for (int j = 0; j < 128; ++j) {
        float2 a2 = *(const float2*)&al[j][tt];
        float4 w4 = *(const float4*)&wl[j][c0];
        acc[0][0] = fmaf(a2.x, w4.x, acc[0][0]);
        acc[0][1] = fmaf(a2.x, w4.y, acc[0][1]);
        acc[0][2] = fmaf(a2.x, w4.z, acc[0][2]);
        acc[0][3] = fmaf(a2.x, w4.w, acc[0][3]);
        acc[1][0] = fmaf(a2.y, w4.x, acc[1][0]);
        acc[1][1] = fmaf(a2.y, w4.y, acc[1][1]);
        acc[1][2] = fmaf(a2.y, w4.z, acc[1][2]);
        acc[1][3] = fmaf(a2.y, w4.w, acc[1][3]);
    }

    float4 bb = *(const float4*)&bias[g * 64 + c0];
    float4 gw = *(const float4*)&gn_w[g * 64 + c0];
    float4 gb = *(const float4*)&gn_b[g * 64 + c0];

#pragma unroll
    for (int tq = 0; tq < 2; ++tq) {
        const int tg = t0 + tt + tq;
        float4 br = *(const float4*)&branch[(size_t)(b * T_ + tg) * D_ + g * 64 + c0];
        float r0 = br.x + acc[tq][0] + bb.x;
        float r1 = br.y + acc[tq][1] + bb.y;
        float r2 = br.z + acc[tq][2] + bb.z;
        float r3 = br.w + acc[tq][3] + bb.w;
        float sm = r0 + r1 + r2 + r3;
#pragma unroll
        for (int m = 1; m < 16; m <<= 1) sm += __shfl_xor(sm, m);
        float mu = sm * (1.f / 64.f);
        float d0 = r0 - mu, d1 = r1 - mu, d2 = r2 - mu, d3 = r3 - mu;
        float vs = d0 * d0 + d1 * d1 + d2 * d2 + d3 * d3;
#pragma unroll
        for (int m = 1; m < 16; m <<= 1) vs += __shfl_xor(vs, m);
        float is = rsqrtf(vs * (1.f / 64.f) + 1e-5f);
        float n0 = d0 * is * gw.x + gb.x;
        float n1 = d1 * is * gw.y + gb.y;
        float n2 = d2 * is * gw.z + gb.z;
        float n3 = d3 * is * gw.w + gb.w;
        u16x4 o = { f2bf(n0), f2bf(n1), f2bf(n2), f2bf(n3) };
        *(u16x4*)&normed[(size_t)(b * T_ + tg) * D_ + g * 64 + c0] = o;
        if (tg == T_ - 1) {
            float nv[4] = {n0, n1, n2, n3};
#pragma unroll
            for (int cc = 0; cc < 4; ++cc) {
                int dloc = c0 + cc;
                int ni = (b * NH_ + g) * 64 + dloc;
                float t2 = sigm_f(nmda_decay[g * 64 + dloc]);
                out_nmda[ni] = t2 * nmda[ni] + (1.f - t2) * nv[cc];
            }
        }
    }
}

// ---------------------------------------------------------------------------
// LayerNorm over D=1024 per row; writes bf16 directly (GEMM8 input).
// ---------------------------------------------------------------------------
__global__ __launch_bounds__(256) void ln_kernel(
    const float* __restrict__ x, const float* __restrict__ w,
    const float* __restrict__ bo, u16* __restrict__ y)
{
    __shared__ float red[8];
    const int row = blockIdx.x, tid = threadIdx.x;
    const float* xr = x + (size_t)row * D_;
    float4 v = *(const float4*)&xr[tid * 4];
    float s = v.x + v.y + v.z + v.w;
#pragma unroll
    for (int m = 32; m; m >>= 1) s += __shfl_xor(s, m);
    if ((tid & 63) == 0) red[tid >> 6] = s;
    __syncthreads();
    float mu = (red[0] + red[1] + red[2] + red[3]) * (1.f / 1024.f);
    float dx = v.x - mu, dy = v.y - mu, dz = v.z - mu, dw = v.w - mu;
    float q = dx * dx + dy * dy + dz * dz + dw * dw;
#pragma unroll
    for (int m = 32; m; m >>= 1) q += __shfl_xor(q, m);
    if ((tid & 63) == 0) red[4 + (tid >> 6)] = q;
    __syncthreads();
    float var = (red[4] + red[5] + red[6] + red[7]) * (1.f / 1024.f);
    float is = rsqrtf(var + 1e-5f);
    float4 wv = *(const float4*)&w[tid * 4];
    float4 bv = *(const float4*)&bo[tid * 4];
    u16x4 o = { f2bf(dx * is * wv.x + bv.x), f2bf(dy * is * wv.y + bv.y),
                f2bf(dz * is * wv.z + bv.z), f2bf(dw * is * wv.w + bv.w) };
    *(u16x4*)&y[(size_t)row * D_ + tid * 4] = o;
}

// ---------------------------------------------------------------------------
extern "C" void kernel_launch(void* const* d_in, const int* in_sizes, int n_in,
                              void* d_out, int out_size, void* d_ws, size_t ws_size,
                              hipStream_t stream)
{
    const float* x       = (const float*)d_in[0];
    const float* nmda    = (const float*)d_in[1];
    const float* qkv_w   = (const float*)d_in[2];
    const float* nmda_d  = (const float*)d_in[3];
    const float* tconv_w = (const float*)d_in[4];
    const float* tconv_b = (const float*)d_in[5];
    const float* ffu_w   = (const float*)d_in[6];
    const float* ffu_b   = (const float*)d_in[7];
    const float* ffd_w   = (const float*)d_in[8];
    const float* ffd_b   = (const float*)d_in[9];
    const float* gn_w    = (const float*)d_in[10];
    const float* gn_b    = (const float*)d_in[11];
    const float* soma_w  = (const float*)d_in[12];
    const float* ln_w    = (const float*)d_in[13];
    const float* ln_b    = (const float*)d_in[14];
    const float* w1      = (const float*)d_in[15];
    const float* b1      = (const float*)d_in[16];
    const float* w2      = (const float*)d_in[17];
    const float* b2      = (const float*)d_in[18];
    (void)in_sizes; (void)n_in; (void)out_size; (void)ws_size;

    float* outp     = (float*)d_out;
    float* soma     = outp;                               // B*T*D
    float* out_nmda = outp + (size_t)B_ * T_ * D_;        // B*NH*DH

    // ws regions (floats) — total 25,165,824 floats
    float* ws     = (float*)d_ws;
    float* branch = ws;                       // R0: 4M floats
    float* xcf2   = ws + (size_t)4194304;     // R1: 4M
    float* normed = ws + (size_t)8388608;     // R2: 4M (aliased below)
    float* qkvb   = ws + (size_t)12582912;    // R3: 12.58M
    u16*   qkvbf = (u16*)qkvb;  // bf16 qkv, dead after attn
    float* hid   = qkvb;        // fp32 ff-hidden reuses R3
    u16*   h1bf  = (u16*)qkvb;  // bf16 MLP hidden reuses R3

    // bf16 scratch aliased into dead regions by lifetime:
    u16* xbf    = (u16*)normed;                  // G1: x_bf
    u16* wqkvT  = (u16*)normed + 4194304;        // G1: qkv_w^T
    u16* Wtp    = (u16*)normed + 7340032;        // tconv weights (327,680 u16)
    u16* normbf = (u16*)xcf2;                    // G2: normed_bf (ffd output)
    u16* somaT  = (u16*)xcf2 + 4194304;          // G2: soma_w^T
    u16* lnsbf  = (u16*)branch;                  // G3: lns_bf (ln output)
    u16* w1T    = (u16*)branch + 4194304;        // G3: w1^T
    u16* w2T    = (u16*)xcf2;                    // G4: w2^T

    // 0. weight preps + casts
    hipLaunchKernelGGL(tconv_wprep, dim3(1280), dim3(256), 0, stream, tconv_w, Wtp);
    hipLaunchKernelGGL(cast_bf16_k, dim3(2048), dim3(256), 0, stream, x, xbf, 524288);
    hipLaunchKernelGGL(transpose_cast_k, dim3(96, 32), dim3(256), 0, stream,
                       qkv_w, wqkvT, 1024, 3072);
    // 1. qkv = x @ qkv_w  (bf16 MFMA, bf16 out; BN=128, BK=64)
    hipLaunchKernelGGL((gemm_mfma<4, false, false, false, true>), dim3(24, 32), dim3(256), 0, stream,
                       xbf, wqkvT, nullptr, qkvbf, 4096, 3072, 1024);
    // 2. bf16 MFMA flash attention + nmda shift -> branch (fp32)
    hipLaunchKernelGGL(attn_mfma, dim3(16, NH_, B_), dim3(256), 0, stream,
                       qkvbf, nmda, nmda_d, branch);
    // 3. xcf2 = branch + tconv(branch)
    hipLaunchKernelGGL(tconv_mfma, dim3(8, NH_, B_), dim3(256), 0, stream,
                       branch, Wtp, tconv_b, xcf2);
    // 4. hid = gelu(ffu(xcf2))
    hipLaunchKernelGGL(ffu_kernel, dim3(16, NH_, B_), dim3(256), 0, stream,
                       xcf2, ffu_w, ffu_b, hid);
    // 5. normbf = bf16(GroupNorm(branch + ffd(hid))); nmda update at t=T-1
    hipLaunchKernelGGL(ffd_gn_kernel, dim3(32, NH_, B_), dim3(256), 0, stream,
                       hid, ffd_w, ffd_b, branch, gn_w, gn_b, nmda, nmda_d,
                       normbf, out_nmda);
    // 6. soma = normed @ soma_w (BN=64 -> 512 blocks = 2/CU)
    hipLaunchKernelGGL(transpose_cast_k, dim3(32, 32), dim3(256), 0, stream,
                       soma_w, somaT, 1024, 1024);
    hipLaunchKernelGGL((gemm_mfma<2, false, false, false, false>), dim3(16, 32), dim3(256), 0, stream,
                       normbf, somaT, nullptr, soma, 4096, 1024, 1024);
    // 7. lnsbf = bf16(LayerNorm(soma))
    hipLaunchKernelGGL(ln_kernel, dim3(B_ * T_), dim3(256), 0, stream,
                       soma, ln_w, ln_b, lnsbf);
    // 8. h1 = gelu(lns @ w1 + b1)  (bf16 out; BN=128, BK=64)
    hipLaunchKernelGGL(transpose_cast_k, dim3(96, 32), dim3(256), 0, stream,
                       w1, w1T, 1024, 3072);
    hipLaunchKernelGGL((gemm_mfma<4, true, true, false, true>), dim3(24, 32), dim3(256), 0, stream,
                       lnsbf, w1T, b1, h1bf, 4096, 3072, 1024);
    // 9. soma += h1 @ w2 + b2  (BN=64 -> 512 blocks = 2/CU)
    hipLaunchKernelGGL(transpose_cast_k, dim3(32, 96), dim3(256), 0, stream,
                       w2, w2T, 3072, 1024);
    hipLaunchKernelGGL((gemm_mfma<2, true, false, true, false>), dim3(16, 32), dim3(256), 0, stream,
                       h1bf, w2T, b2, soma, 4096, 1024, 3072);
}